// Round 5
// baseline (981.167 us; speedup 1.0000x reference)
//
#include <hip/hip_runtime.h>
#include <cstdint>
#include <cstddef>

// Problem constants
#define BB   4
#define TT   1024
#define CC   1024
#define HH   16
#define HSS  64
#define NNtok 4096            // B*T
#define EPSGN 0.00064f

typedef unsigned short bf16u;
typedef __attribute__((ext_vector_type(8))) short short8;
typedef __attribute__((ext_vector_type(4))) float f32x4;
#define SLOT 4194304ull       // elements per 8MiB bf16 slot (= NNtok*CC)

__device__ __forceinline__ float bf2f(bf16u u){
  union { unsigned int i; float f; } cv; cv.i = ((unsigned int)u) << 16; return cv.f;
}
__device__ __forceinline__ unsigned short f2bfbits(unsigned int x){
  return (unsigned short)((x + 0x7fffu + ((x >> 16) & 1u)) >> 16);   // RNE
}
__device__ __forceinline__ bf16u f2bf(float f){
  union { float f; unsigned int i; } cv; cv.f = f;
  return f2bfbits(cv.i);
}
__device__ __forceinline__ void ld4bf(const bf16u* p, float* o){
  ushort4 u = *reinterpret_cast<const ushort4*>(p);
  o[0]=bf2f(u.x); o[1]=bf2f(u.y); o[2]=bf2f(u.z); o[3]=bf2f(u.w);
}
__device__ __forceinline__ void st4bf(bf16u* p, const float* v){
  ushort4 u; u.x=f2bf(v[0]); u.y=f2bf(v[1]); u.z=f2bf(v[2]); u.w=f2bf(v[3]);
  *reinterpret_cast<ushort4*>(p) = u;
}
__device__ __forceinline__ unsigned short f2h(float f){
  union { _Float16 h; unsigned short s; } c; c.h = (_Float16)f; return c.s;
}
__device__ __forceinline__ void st4h(bf16u* p, const float* v){
  ushort4 u; u.x=f2h(v[0]); u.y=f2h(v[1]); u.z=f2h(v[2]); u.w=f2h(v[3]);
  *reinterpret_cast<ushort4*>(p) = u;
}
__device__ __forceinline__ void ld4f(const float* p, float* o){
  float4 v = *reinterpret_cast<const float4*>(p);
  o[0]=v.x; o[1]=v.y; o[2]=v.z; o[3]=v.w;
}
__device__ __forceinline__ float sigm(float x){ return 1.f / (1.f + expf(-x)); }

// unpack helpers
__device__ __forceinline__ float bflo(unsigned int u){
  union { unsigned int i; float f; } c; c.i = u << 16; return c.f;
}
__device__ __forceinline__ float bfhi(unsigned int u){
  union { unsigned int i; float f; } c; c.i = u & 0xffff0000u; return c.f;
}
__device__ __forceinline__ float hlo(unsigned int u){
  union { unsigned short s; _Float16 h; } c; c.s = (unsigned short)(u & 0xffffu); return (float)c.h;
}
__device__ __forceinline__ float hhi(unsigned int u){
  union { unsigned short s; _Float16 h; } c; c.s = (unsigned short)(u >> 16); return (float)c.h;
}
__device__ __forceinline__ float hval(unsigned short s){
  union { unsigned short s; _Float16 h; } c; c.s = s; return (float)c.h;
}

// 16-lane sum via DPP (groups must be 16-lane aligned). 4 plain-VALU adds,
// no ds ops / lgkmcnt waits on the critical path.
template<int CTRL>
__device__ __forceinline__ float dpp_add(float v){
  union { float f; int i; } a, b;
  a.f = v;
  b.i = __builtin_amdgcn_update_dpp(a.i, a.i, CTRL, 0xF, 0xF, false);
  return v + b.f;
}
__device__ __forceinline__ float red16(float v){
  v = dpp_add<0xB1>(v);    // quad_perm [1,0,3,2]  (xor 1)
  v = dpp_add<0x4E>(v);    // quad_perm [2,3,0,1]  (xor 2)
  v = dpp_add<0x124>(v);   // row_ror:4
  v = dpp_add<0x128>(v);   // row_ror:8
  return v;
}

// ---------------------------------------------------------------------------
// mix = x + (x[t-1]-x[t])*time_maa_x  (x[-1]=0), stored bf16
// ---------------------------------------------------------------------------
__global__ __launch_bounds__(256) void k_prep(const float* __restrict__ x,
                                              const float* __restrict__ tmx,
                                              bf16u* __restrict__ MIX){
  int e = (blockIdx.x * 256 + threadIdx.x) * 4;
  int n = e >> 10;
  int c = e & (CC - 1);
  int t = n & (TT - 1);
  float xf[4]; ld4f(x + e, xf);
  float pf[4] = {0.f, 0.f, 0.f, 0.f};
  if (t > 0) ld4f(x + e - CC, pf);
  float tm[4]; ld4f(tmx + c, tm);
  float mv[4];
  #pragma unroll
  for (int i = 0; i < 4; ++i) mv[i] = xf[i] + (pf[i] - xf[i]) * tm[i];
  st4bf(MIX + e, mv);
}

// ---------------------------------------------------------------------------
// MFMA NT GEMM: OUT[M,Nd] = X[M,K](bf16) @ W[Nd,K]^T, W as up to 3 row-blocks
// (f32). tanh on cols < act_n. OB: bf16 out else f32. 128x128, BK=32.
// ---------------------------------------------------------------------------
template<bool OB>
__global__ __launch_bounds__(256) void k_gemm_mfma(const bf16u* __restrict__ X,
                                                   const float* __restrict__ Wa,
                                                   const float* __restrict__ Wb,
                                                   const float* __restrict__ Wc,
                                                   int na, int nab,
                                                   void* __restrict__ OUTv,
                                                   int Nd, int Kd, int act_n){
  __shared__ short As[128 * 40];
  __shared__ short Bs[128 * 40];
  const int tid  = threadIdx.x;
  const int lane = tid & 63;
  const int wv   = tid >> 6;
  const int wm   = wv >> 1, wn = wv & 1;
  const int bn0  = blockIdx.x * 128;
  const int bm0  = blockIdx.y * 128;
  const int l15  = lane & 15;
  const int quad = lane >> 4;

  f32x4 acc[4][4];
  #pragma unroll
  for (int mi = 0; mi < 4; ++mi)
    #pragma unroll
    for (int ni = 0; ni < 4; ++ni)
      #pragma unroll
      for (int rg = 0; rg < 4; ++rg) acc[mi][ni][rg] = 0.f;

  const int r    = tid >> 1;
  const int half = (tid & 1) * 16;

  int rr = bn0 + r;
  const float* wsrc = nullptr;
  if (rr < na)        wsrc = Wa + (size_t)rr * Kd;
  else if (rr < nab)  wsrc = Wb + (size_t)(rr - na) * Kd;
  else if (rr < Nd)   wsrc = Wc + (size_t)(rr - nab) * Kd;
  const bf16u* xsrc = X + (size_t)(bm0 + r) * Kd;

  for (int k0 = 0; k0 < Kd; k0 += 32){
    uint4 xa = *(const uint4*)(xsrc + k0 + half);
    uint4 xb = *(const uint4*)(xsrc + k0 + half + 8);
    uint4 w0 = make_uint4(0,0,0,0), w1 = w0, w2 = w0, w3 = w0;
    if (wsrc){
      w0 = *(const uint4*)(wsrc + k0 + half);
      w1 = *(const uint4*)(wsrc + k0 + half + 4);
      w2 = *(const uint4*)(wsrc + k0 + half + 8);
      w3 = *(const uint4*)(wsrc + k0 + half + 12);
    }
    union { unsigned short s[8]; uint4 v; } p0, p1;
    p0.s[0]=f2bfbits(w0.x); p0.s[1]=f2bfbits(w0.y); p0.s[2]=f2bfbits(w0.z); p0.s[3]=f2bfbits(w0.w);
    p0.s[4]=f2bfbits(w1.x); p0.s[5]=f2bfbits(w1.y); p0.s[6]=f2bfbits(w1.z); p0.s[7]=f2bfbits(w1.w);
    p1.s[0]=f2bfbits(w2.x); p1.s[1]=f2bfbits(w2.y); p1.s[2]=f2bfbits(w2.z); p1.s[3]=f2bfbits(w2.w);
    p1.s[4]=f2bfbits(w3.x); p1.s[5]=f2bfbits(w3.y); p1.s[6]=f2bfbits(w3.z); p1.s[7]=f2bfbits(w3.w);

    *(uint4*)&As[r * 40 + half]     = xa;
    *(uint4*)&As[r * 40 + half + 8] = xb;
    *(uint4*)&Bs[r * 40 + half]     = p0.v;
    *(uint4*)&Bs[r * 40 + half + 8] = p1.v;
    __syncthreads();

    short8 af[4], bfg[4];
    #pragma unroll
    for (int mi = 0; mi < 4; ++mi)
      af[mi] = *(const short8*)&As[(wm*64 + mi*16 + l15) * 40 + quad*8];
    #pragma unroll
    for (int ni = 0; ni < 4; ++ni)
      bfg[ni] = *(const short8*)&Bs[(wn*64 + ni*16 + l15) * 40 + quad*8];
    #pragma unroll
    for (int mi = 0; mi < 4; ++mi)
      #pragma unroll
      for (int ni = 0; ni < 4; ++ni)
        acc[mi][ni] = __builtin_amdgcn_mfma_f32_16x16x32_bf16(af[mi], bfg[ni], acc[mi][ni], 0, 0, 0);
    __syncthreads();
  }

  #pragma unroll
  for (int mi = 0; mi < 4; ++mi){
    #pragma unroll
    for (int ni = 0; ni < 4; ++ni){
      int col = bn0 + wn*64 + ni*16 + l15;
      if (col >= Nd) continue;
      #pragma unroll
      for (int rg = 0; rg < 4; ++rg){
        int row = bm0 + wm*64 + mi*16 + quad*4 + rg;
        float v = acc[mi][ni][rg];
        if (col < act_n) v = tanhf(v);
        if (OB) ((bf16u*)OUTv)[(size_t)row * Nd + col] = f2bf(v);
        else    ((float*)OUTv)[(size_t)row * Nd + col] = v;
      }
    }
  }
}

// ---------------------------------------------------------------------------
// MFMA NN GEMM: OUT[M, CC] = A[M, KD](bf16, row stride lda) @ B[KD, CC](f32).
// EP=0: plain bf16 store. EP=1: token-shift epilogue.
// ---------------------------------------------------------------------------
template<int KD, int EP>
__global__ __launch_bounds__(256) void k_gemm_nn(const bf16u* __restrict__ A, int lda,
                                                 const float* __restrict__ B,
                                                 bf16u* __restrict__ OUT,
                                                 const float* __restrict__ x,
                                                 const float* __restrict__ tma_g){
  __shared__ short As[128 * (KD + 8)];
  __shared__ short Bs[128 * (KD + 8)];
  const int tid  = threadIdx.x;
  const int lane = tid & 63;
  const int wv   = tid >> 6;
  const int wm   = wv >> 1, wn = wv & 1;
  const int bn0  = blockIdx.x * 128;
  const int bm0  = blockIdx.y * 128;
  const int l15  = lane & 15;
  const int quad = lane >> 4;

  for (int idx = tid; idx < 128 * (KD / 8); idx += 256){
    int r  = idx / (KD / 8);
    int kc = (idx % (KD / 8)) * 8;
    *(uint4*)&As[r * (KD + 8) + kc] =
        *(const uint4*)(A + (size_t)(bm0 + r) * lda + kc);
  }
  for (int idx = tid; idx < KD * 128; idx += 256){
    int k = idx >> 7, c = idx & 127;
    Bs[c * (KD + 8) + k] = (short)f2bf(B[(size_t)k * CC + bn0 + c]);
  }
  __syncthreads();

  f32x4 acc[4][4];
  #pragma unroll
  for (int mi = 0; mi < 4; ++mi)
    #pragma unroll
    for (int ni = 0; ni < 4; ++ni)
      #pragma unroll
      for (int rg = 0; rg < 4; ++rg) acc[mi][ni][rg] = 0.f;

  #pragma unroll
  for (int kk = 0; kk < KD; kk += 32){
    short8 af[4], bfg[4];
    #pragma unroll
    for (int mi = 0; mi < 4; ++mi)
      af[mi] = *(const short8*)&As[(wm*64 + mi*16 + l15) * (KD + 8) + kk + quad*8];
    #pragma unroll
    for (int ni = 0; ni < 4; ++ni)
      bfg[ni] = *(const short8*)&Bs[(wn*64 + ni*16 + l15) * (KD + 8) + kk + quad*8];
    #pragma unroll
    for (int mi = 0; mi < 4; ++mi)
      #pragma unroll
      for (int ni = 0; ni < 4; ++ni)
        acc[mi][ni] = __builtin_amdgcn_mfma_f32_16x16x32_bf16(af[mi], bfg[ni], acc[mi][ni], 0, 0, 0);
  }

  #pragma unroll
  for (int mi = 0; mi < 4; ++mi){
    #pragma unroll
    for (int ni = 0; ni < 4; ++ni){
      int col = bn0 + wn*64 + ni*16 + l15;
      float tm = (EP == 1) ? tma_g[col] : 0.f;
      #pragma unroll
      for (int rg = 0; rg < 4; ++rg){
        int row = bm0 + wm*64 + mi*16 + quad*4 + rg;
        float v = acc[mi][ni][rg];
        if (EP == 1){
          float xv = x[(size_t)row * CC + col];
          float xp = ((row & (TT - 1)) == 0) ? 0.f : x[(size_t)row * CC + col - CC];
          v = xv + (xp - xv) * (v + tm);
        }
        OUT[(size_t)row * CC + col] = f2bf(v);
      }
    }
  }
}

// ---------------------------------------------------------------------------
// Fused elementwise, tiled 4 tokens/block. UX stores -u = -exp(w) as f16
// (self-normalizing; validated round 4, absmax 2.6e-3).
// ---------------------------------------------------------------------------
__global__ __launch_bounds__(256) void k_elem(bf16u* __restrict__ K0,
    const bf16u* __restrict__ P1, const bf16u* __restrict__ P2,
    const bf16u* __restrict__ W2A,
    const float* __restrict__ kw2, const float* __restrict__ aw2,
    const float* __restrict__ maw2, const float* __restrict__ mkw2,
    const float* __restrict__ td,  const float* __restrict__ taa,
    const float* __restrict__ tma, const float* __restrict__ tmk,
    bf16u* __restrict__ KKN, bf16u* __restrict__ Bb, bf16u* __restrict__ UX){
  int n0 = blockIdx.x * 4, tid = threadIdx.x;
  __shared__ float at_l[4][16], mat_l[4][16], kt_l[4][16], mkt_l[4][16];
  {
    int grp = tid >> 6, q = tid & 63, tt = q >> 4, j = q & 15;
    if (grp == 0)      at_l[tt][j]  = bf2f(P1[(size_t)(n0+tt)*96 + 64 + j]);
    else if (grp == 1) mat_l[tt][j] = bf2f(P1[(size_t)(n0+tt)*96 + 80 + j]);
    else if (grp == 2) kt_l[tt][j]  = bf2f(P2[(size_t)(n0+tt)*32 + j]);
    else               mkt_l[tt][j] = bf2f(P2[(size_t)(n0+tt)*32 + 16 + j]);
  }
  __syncthreads();
  int c = tid * 4;

  float kkk[4][4], aa[4][4], mam[4][4], mkm[4][4];
  #pragma unroll
  for (int tt = 0; tt < 4; ++tt)
    #pragma unroll
    for (int i = 0; i < 4; ++i){ kkk[tt][i]=0; aa[tt][i]=0; mam[tt][i]=0; mkm[tt][i]=0; }

  #pragma unroll 4
  for (int j = 0; j < 16; ++j){
    float wk[4], wa[4], wm[4], wq[4];
    ld4f(kw2  + (size_t)j*CC + c, wk);
    ld4f(aw2  + (size_t)j*CC + c, wa);
    ld4f(maw2 + (size_t)j*CC + c, wm);
    ld4f(mkw2 + (size_t)j*CC + c, wq);
    #pragma unroll
    for (int tt = 0; tt < 4; ++tt){
      float s1 = kt_l[tt][j], s2 = at_l[tt][j], s3 = mat_l[tt][j], s4 = mkt_l[tt][j];
      #pragma unroll
      for (int i = 0; i < 4; ++i){
        kkk[tt][i] += s1 * wk[i];
        aa[tt][i]  += s2 * wa[i];
        mam[tt][i] += s3 * wm[i];
        mkm[tt][i] += s4 * wq[i];
      }
    }
  }

  float td4[4], taa4[4], tma4[4], tmk4[4];
  ld4f(td + c, td4); ld4f(taa + c, taa4); ld4f(tma + c, tma4); ld4f(tmk + c, tmk4);

  for (int tt = 0; tt < 4; ++tt){
    size_t e = (size_t)(n0 + tt) * CC + c;
    float k0a[4]; ld4bf(K0 + e, k0a);
    float w2a[4]; ld4bf(W2A + e, w2a);

    float kkv[4];
    float ssq = 0.f;
    #pragma unroll
    for (int i = 0; i < 4; ++i){ kkv[i] = k0a[i] + kkk[tt][i]; ssq += kkv[i]*kkv[i]; }
    ssq = red16(ssq);
    float rinv = 1.f / fmaxf(sqrtf(ssq), 1e-12f);

    float kkn[4], outb[4], outkf[4], outw[4];
    #pragma unroll
    for (int i = 0; i < 4; ++i){
      float z  = td4[i] + w2a[i];
      float nz = -z;
      float sp = (nz > 15.f) ? nz : log1pf(expf(nz));
      float w  = -sp - 0.5f;               // <= -0.5
      float av  = sigm(taa4[i] + aa[tt][i]);
      float mav = sigm(tma4[i] + mam[tt][i]);
      float mkv = sigm(tmk4[i] + mkm[tt][i]);
      kkn[i]  = kkv[i] * rinv;
      outb[i] = -kkn[i] * av;
      outkf[i]= k0a[i] * (mav + av * (1.f - mav)) * expf(w * mkv);
      outw[i] = -expf(w);                  // -u in [-0.607, 0), stored f16
    }
    st4bf(KKN + e, kkn);
    st4bf(Bb  + e, outb);
    st4bf(K0  + e, outkf);
    st4h (UX  + e, outw);
  }
}

// ---------------------------------------------------------------------------
// Pair pre-pass: exploiting linearity, sa_{t+1} = S_{t-1}·u_t + d_t·v_t with
//   u_t = w_t∘a_{t+1} + (b_t·a_{t+1})·a_t   (even t; stored over KKN row t+1,
//                                            which k_rec never reads as "a")
//   d_t = kf_t·a_{t+1}                      (f32 scalar per (token,head))
// Lets k_rec compute BOTH reductions of a 2-step macro from the same S_{t-1},
// pipelining the two DPP chains. All reads happen into registers before the
// in-place overwrite; pairs never straddle block or batch boundaries.
// ---------------------------------------------------------------------------
__global__ __launch_bounds__(256) void k_pre2(bf16u* __restrict__ KKN,
                                              const bf16u* __restrict__ Bb,
                                              const bf16u* __restrict__ KF,
                                              const bf16u* __restrict__ UX,
                                              float* __restrict__ Dsc){
  int m  = blockIdx.x;            // pair index 0..2047 (global tokens 2m,2m+1)
  int te = m * 2;
  int tid = threadIdx.x;
  int h  = tid >> 4;
  int lg = tid & 15;
  int c  = h * HSS + lg * 4;
  size_t eE = (size_t)te * CC + c;
  size_t eO = eE + CC;
  float aE[4], aO[4], bE[4], kE[4];
  ld4bf(KKN + eE, aE); ld4bf(KKN + eO, aO);
  ld4bf(Bb + eE, bE);  ld4bf(KF + eE, kE);
  ushort4 uu = *(const ushort4*)(UX + eE);
  float w0 = __expf(hval(uu.x)), w1 = __expf(hval(uu.y));
  float w2 = __expf(hval(uu.z)), w3 = __expf(hval(uu.w));
  float cp = (bE[0]*aO[0] + bE[1]*aO[1]) + (bE[2]*aO[2] + bE[3]*aO[3]);
  float dp = (kE[0]*aO[0] + kE[1]*aO[1]) + (kE[2]*aO[2] + kE[3]*aO[3]);
  cp = red16(cp);
  dp = red16(dp);
  float u[4] = { w0*aO[0] + cp*aE[0], w1*aO[1] + cp*aE[1],
                 w2*aO[2] + cp*aE[2], w3*aO[3] + cp*aE[3] };
  st4bf(KKN + eO, u);
  if (lg == 0) Dsc[(size_t)te * HH + h] = dp;
}

// ---------------------------------------------------------------------------
// Recurrence v10: back to the instruction-lean 16-lane/row, 4-col/lane
// geometry (round-0's 404us host), plus 2-step fusion: both sa reductions of
// a token pair are issued back-to-back from the same S (independent DPP
// chains pipeline -> loop-carried reduction latency per token halves).
// 4 pair-slots = 8-step load lookahead. XCD clustering kept (FETCH 98->25MB
// in r4). Decay stored as -u (f16); w_t = __expf in-loop (validated).
// ---------------------------------------------------------------------------
__global__ __launch_bounds__(256) void k_rec(const bf16u* __restrict__ Q,
                                             const bf16u* __restrict__ WT,
                                             const bf16u* __restrict__ KFt,
                                             const bf16u* __restrict__ Vt,
                                             const bf16u* __restrict__ Aa,
                                             const bf16u* __restrict__ Bv,
                                             const float* __restrict__ Dsc,
                                             bf16u* __restrict__ Y){
  const int p  = blockIdx.x;                 // 0..255
  const int g  = (p & 7) | ((p >> 5) << 3);  // (b,h) group 0..63, XCD-clustered
  const int rg = (p >> 3) & 3;               // row quartet within the head
  const int b  = g >> 4;
  const int h  = g & 15;
  const int tid = threadIdx.x;
  const int cg  = tid & 15;                  // 16 lanes per row
  const int i   = rg * 16 + (tid >> 4);      // state row 0..63
  const size_t base0 = (size_t)(b * TT) * CC + h * HSS;
  const size_t colb  = base0 + cg * 4;
  const size_t rowb  = base0 + i;
  const size_t dbase = (size_t)(b * TT) * HH + h;

  float S0 = 0.f, S1 = 0.f, S2 = 0.f, S3 = 0.f;
  float ypEA, ypOA, ypEB, ypOB, ypEC, ypOC, ypED, ypOD;

  uint2 qEA,qOA,kEA,kOA,aEA,uOA,bEA,bOA,wEA,wOA; unsigned short vEA,vOA; float dA;
  uint2 qEB,qOB,kEB,kOB,aEB,uOB,bEB,bOB,wEB,wOB; unsigned short vEB,vOB; float dB;
  uint2 qEC,qOC,kEC,kOC,aEC,uOC,bEC,bOC,wEC,wOC; unsigned short vEC,vOC; float dC;
  uint2 qED,qOD,kED,kOD,aED,uOD,bED,bOD,wED,wOD; unsigned short vED,vOD; float dD;

#define PL(S, T_) do{ \
    size_t cE_ = colb + (size_t)(T_) * CC, cO_ = cE_ + CC; \
    qE##S = *(const uint2*)(Q   + cE_); qO##S = *(const uint2*)(Q   + cO_); \
    kE##S = *(const uint2*)(KFt + cE_); kO##S = *(const uint2*)(KFt + cO_); \
    aE##S = *(const uint2*)(Aa  + cE_); uO##S = *(const uint2*)(Aa  + cO_); \
    bE##S = *(const uint2*)(Bv  + cE_); bO##S = *(const uint2*)(Bv  + cO_); \
    wE##S = *(const uint2*)(WT  + cE_); wO##S = *(const uint2*)(WT  + cO_); \
    vE##S = Vt[rowb + (size_t)(T_) * CC]; \
    vO##S = Vt[rowb + (size_t)(T_ + 1) * CC]; \
    d##S  = Dsc[dbase + (size_t)(T_) * HH]; \
  }while(0)

#define PSTEP(S) do{ \
    float a0=bflo(aE##S.x), a1=bfhi(aE##S.x), a2=bflo(aE##S.y), a3=bfhi(aE##S.y); \
    float u0=bflo(uO##S.x), u1=bfhi(uO##S.x), u2=bflo(uO##S.y), u3=bfhi(uO##S.y); \
    float pE_ = (S0*a0 + S1*a1) + (S2*a2 + S3*a3); \
    float pO_ = (S0*u0 + S1*u1) + (S2*u2 + S3*u3); \
    float saE = red16(pE_); \
    float saO = red16(pO_); \
    float vEf = bf2f(vE##S), vOf = bf2f(vO##S); \
    saO = fmaf(d##S, vEf, saO); \
    float k0=bflo(kE##S.x), k1=bfhi(kE##S.x), k2=bflo(kE##S.y), k3=bfhi(kE##S.y); \
    float b0=bflo(bE##S.x), b1=bfhi(bE##S.x), b2=bflo(bE##S.y), b3=bfhi(bE##S.y); \
    float w0=__expf(hlo(wE##S.x)), w1=__expf(hhi(wE##S.x)); \
    float w2=__expf(hlo(wE##S.y)), w3=__expf(hhi(wE##S.y)); \
    S0 = fmaf(S0, w0, fmaf(saE, b0, vEf * k0)); \
    S1 = fmaf(S1, w1, fmaf(saE, b1, vEf * k1)); \
    S2 = fmaf(S2, w2, fmaf(saE, b2, vEf * k2)); \
    S3 = fmaf(S3, w3, fmaf(saE, b3, vEf * k3)); \
    float q0=bflo(qE##S.x), q1=bfhi(qE##S.x), q2=bflo(qE##S.y), q3=bfhi(qE##S.y); \
    ypE##S = (S0*q0 + S1*q1) + (S2*q2 + S3*q3); \
    float ko0=bflo(kO##S.x), ko1=bfhi(kO##S.x), ko2=bflo(kO##S.y), ko3=bfhi(kO##S.y); \
    float bo0=bflo(bO##S.x), bo1=bfhi(bO##S.x), bo2=bflo(bO##S.y), bo3=bfhi(bO##S.y); \
    float wo0=__expf(hlo(wO##S.x)), wo1=__expf(hhi(wO##S.x)); \
    float wo2=__expf(hlo(wO##S.y)), wo3=__expf(hhi(wO##S.y)); \
    S0 = fmaf(S0, wo0, fmaf(saO, bo0, vOf * ko0)); \
    S1 = fmaf(S1, wo1, fmaf(saO, bo1, vOf * ko1)); \
    S2 = fmaf(S2, wo2, fmaf(saO, bo2, vOf * ko2)); \
    S3 = fmaf(S3, wo3, fmaf(saO, bo3, vOf * ko3)); \
    float qo0=bflo(qO##S.x), qo1=bfhi(qO##S.x), qo2=bflo(qO##S.y), qo3=bfhi(qO##S.y); \
    ypO##S = (S0*qo0 + S1*qo1) + (S2*qo2 + S3*qo3); \
  }while(0)

#define PF(S, T_) do{ \
    float yE_ = red16(ypE##S); \
    float yO_ = red16(ypO##S); \
    if (cg == 0){ \
      Y[rowb + (size_t)(T_) * CC]     = f2bf(yE_); \
      Y[rowb + (size_t)(T_ + 1) * CC] = f2bf(yO_); \
    } \
  }while(0)

  PL(A, 0); PL(B, 2); PL(C, 4); PL(D, 6);
  for (int t = 0; t < TT; t += 8){
    PSTEP(A);
    if (t) PF(D, t - 2);
    if (t + 8  < TT) PL(A, t + 8);
    PSTEP(B);
    PF(A, t);
    if (t + 10 < TT) PL(B, t + 10);
    PSTEP(C);
    PF(B, t + 2);
    if (t + 12 < TT) PL(C, t + 12);
    PSTEP(D);
    PF(C, t + 4);
    if (t + 14 < TT) PL(D, t + 14);
  }
  PF(D, TT - 2);
#undef PL
#undef PSTEP
#undef PF
}

// ---------------------------------------------------------------------------
// Post: GroupNorm + bonus (r.k*faaaa)v + precomputed gate GV -> YG (bf16)
// ---------------------------------------------------------------------------
__global__ __launch_bounds__(256) void k_post(const bf16u* __restrict__ Y,
                                              const bf16u* __restrict__ R,
                                              const bf16u* __restrict__ KFt,
                                              const bf16u* __restrict__ Vt,
                                              const bf16u* __restrict__ GV,
                                              const float* __restrict__ lnw,
                                              const float* __restrict__ lnb,
                                              const float* __restrict__ faaaa,
                                              bf16u* __restrict__ YG){
  int n = blockIdx.x, tid = threadIdx.x;
  int c = tid * 4;
  size_t e = (size_t)n * CC + c;

  float ya[4]; ld4bf(Y + e, ya);
  float s = ya[0] + ya[1] + ya[2] + ya[3];
  s = red16(s);
  float mu = s * (1.f / 64.f);
  float d[4], vs = 0.f;
  #pragma unroll
  for (int i = 0; i < 4; ++i){ d[i] = ya[i] - mu; vs += d[i] * d[i]; }
  vs = red16(vs);
  float rstd = rsqrtf(vs * (1.f / 64.f) + EPSGN);

  float r4[4], k4[4], va[4], fa4[4];
  ld4bf(R + e, r4); ld4bf(KFt + e, k4); ld4bf(Vt + e, va);
  ld4f(faaaa + c, fa4);
  float rk = r4[0]*k4[0]*fa4[0] + r4[1]*k4[1]*fa4[1] + r4[2]*k4[2]*fa4[2] + r4[3]*k4[3]*fa4[3];
  rk = red16(rk);

  float lw4[4], lb4[4];
  ld4f(lnw + c, lw4); ld4f(lnb + c, lb4);
  float g[4]; ld4bf(GV + e, g);
  float o[4];
  #pragma unroll
  for (int i = 0; i < 4; ++i){
    float yn = d[i] * rstd * lw4[i] + lb4[i] + rk * va[i];
    o[i] = yn * g[i];
  }
  st4bf(YG + e, o);
}

// ---------------------------------------------------------------------------
extern "C" void kernel_launch(void* const* d_in, const int* in_sizes, int n_in,
                              void* d_out, int out_size, void* d_ws, size_t ws_size,
                              hipStream_t stream){
  (void)in_sizes; (void)n_in; (void)out_size; (void)ws_size;
  const float* x        = (const float*)d_in[0];
  const float* tmx      = (const float*)d_in[1];
  const float* tmaa     = (const float*)d_in[2];
  const float* maa_w1   = (const float*)d_in[3];
  const float* maa_w2   = (const float*)d_in[4];
  const float* decay_w1 = (const float*)d_in[5];
  const float* decay_w2 = (const float*)d_in[6];
  const float* aaa_w1   = (const float*)d_in[7];
  const float* aaa_w2   = (const float*)d_in[8];
  const float* kkk_w1   = (const float*)d_in[9];
  const float* kkk_w2   = (const float*)d_in[10];
  const float* gate_w1  = (const float*)d_in[11];
  const float* gate_w2  = (const float*)d_in[12];
  const float* ma_w1    = (const float*)d_in[13];
  const float* ma_w2    = (const float*)d_in[14];
  const float* mk_w1    = (const float*)d_in[15];
  const float* mk_w2    = (const float*)d_in[16];
  const float* t_decay  = (const float*)d_in[17];
  const float* t_faaaa  = (const float*)d_in[18];
  const float* t_aaaaa  = (const float*)d_in[19];
  const float* t_misc_a = (const float*)d_in[20];
  const float* t_misc_k = (const float*)d_in[21];
  const float* Wr       = (const float*)d_in[22];
  const float* Wk       = (const float*)d_in[23];
  const float* Wv       = (const float*)d_in[24];
  const float* Wo       = (const float*)d_in[25];
  const float* ln_w     = (const float*)d_in[26];
  const float* ln_b     = (const float*)d_in[27];

  // Slot map (8MiB bf16 each), 56 MiB + ~3.3 MiB smalls:
  // S0: MIX -> X0 -> KKN(+u odd rows) -> YG | S1: X1 -> Bb -> GV
  // S2: X2 -> UX(-u f16) | S3: X3 -> W2A -> Yb | S4: R | S5: K0 -> KF | S6: V
  bf16u* bw  = (bf16u*)d_ws;
  bf16u* MIX = bw + 0*SLOT;
  bf16u* X0  = bw + 0*SLOT;
  bf16u* KKN = bw + 0*SLOT;
  bf16u* YG  = bw + 0*SLOT;
  bf16u* X1  = bw + 1*SLOT;
  bf16u* Bb  = bw + 1*SLOT;
  bf16u* GV  = bw + 1*SLOT;
  bf16u* X2  = bw + 2*SLOT;
  bf16u* UX  = bw + 2*SLOT;
  bf16u* X3  = bw + 3*SLOT;
  bf16u* W2A = bw + 3*SLOT;
  bf16u* Yb  = bw + 3*SLOT;
  bf16u* R   = bw + 4*SLOT;
  bf16u* K0  = bw + 5*SLOT;   // becomes KF
  bf16u* V   = bw + 6*SLOT;
  char*  wsb = (char*)d_ws;
  bf16u* LO  = (bf16u*)(wsb + (56ull<<20));   // [N,128] bf16, 1 MiB
  bf16u* GT  = (bf16u*)(wsb + (57ull<<20));   // [N,128] bf16, 1 MiB
  bf16u* P1  = (bf16u*)(wsb + (58ull<<20));   // [N,96]  bf16 (dt|at|ma)
  bf16u* P2  = (bf16u*)(wsb + (58ull<<20) + (768ull<<10)); // [N,32] bf16
  float* Dsc = (float*)(wsb + (59ull<<20));   // [N,16]  f32 pair-dots, 256 KiB

  // 1. mix
  k_prep<<<4096, 256, 0, stream>>>(x, tmx, MIX);
  // 2. lo = tanh(mix @ maa_w1^T) [N,128] bf16
  k_gemm_mfma<true><<<dim3(1,32),256,0,stream>>>(MIX, maa_w1, maa_w1, maa_w1,
                                                 128, 128, LO, 128, CC, 128);
  // 3. xm[g] = x + xx*(lo_g @ maa_w2_g + tmaa_g)   (NN GEMM + fused epilogue)
  bf16u* XMs[4] = {X0, X1, X2, X3};
  for (int g = 0; g < 4; ++g)
    k_gemm_nn<32,1><<<dim3(8,32),256,0,stream>>>(LO + g*32, 128,
                                                 maa_w2 + (size_t)g*32*CC,
                                                 XMs[g], x, tmaa + (size_t)g*CC);
  // 4. big projections (bf16 out)
  k_gemm_mfma<true><<<dim3(8,32),256,0,stream>>>(X0, Wr, Wr, Wr, CC, CC, R,  CC, CC, 0);
  k_gemm_mfma<true><<<dim3(8,32),256,0,stream>>>(X2, Wk, Wk, Wk, CC, CC, K0, CC, CC, 0);
  k_gemm_mfma<true><<<dim3(8,32),256,0,stream>>>(X3, Wv, Wv, Wv, CC, CC, V,  CC, CC, 0);
  // 5. first-stage LoRA projections (bf16 out)
  k_gemm_mfma<true><<<dim3(1,32),256,0,stream>>>(X0, gate_w1, gate_w1, gate_w1,
                                                 128, 128, GT, 128, CC, 128);
  k_gemm_mfma<true><<<dim3(1,32),256,0,stream>>>(X1, decay_w1, aaa_w1, ma_w1,
                                                 64, 80, P1, 96, CC, 64);
  k_gemm_mfma<true><<<dim3(1,32),256,0,stream>>>(X2, kkk_w1, mk_w1, mk_w1,
                                                 16, 32, P2, 32, CC, 16);
  // 6. decay second-stage projection: W2A = P1[:, :64] @ decay_w2  -> S3
  k_gemm_nn<64,0><<<dim3(8,32),256,0,stream>>>(P1, 96, decay_w2, W2A, nullptr, nullptr);
  // 7. fused elementwise (4 tokens/block); UX holds -u = -exp(w) as f16
  k_elem<<<1024, 256, 0, stream>>>(K0, P1, P2, W2A,
                                   kkk_w2, aaa_w2, ma_w2, mk_w2,
                                   t_decay, t_aaaaa, t_misc_a, t_misc_k,
                                   KKN, Bb, UX);
  // 7b. pair pre-pass: u into KKN odd rows, d scalars into Dsc
  k_pre2<<<2048, 256, 0, stream>>>(KKN, Bb, K0, UX, Dsc);
  // 8. delta-rule recurrence (v10: 2-step fused, 16-lane rows, 8-step prefetch)
  k_rec<<<256, 256, 0, stream>>>(R, UX, K0, V, KKN, Bb, Dsc, Yb);
  // 9. gate second-stage: GV = GT @ gate_w2 -> S1 (Bb dead after k_rec)
  k_gemm_nn<128,0><<<dim3(8,32),256,0,stream>>>(GT, 128, gate_w2, GV, nullptr, nullptr);
  // 10. groupnorm + bonus + gate
  k_post<<<4096, 256, 0, stream>>>(Yb, R, K0, V, GV, ln_w, ln_b, t_faaaa, YG);
  // 11. out = yg @ Wo^T -> f32
  k_gemm_mfma<false><<<dim3(8,32),256,0,stream>>>(YG, Wo, Wo, Wo, CC, CC, d_out, CC, CC, 0);
}

// Round 6
// 849.907 us; speedup vs baseline: 1.1544x; 1.1544x over previous
//
#include <hip/hip_runtime.h>
#include <cstdint>
#include <cstddef>

// Problem constants
#define BB   4
#define TT   1024
#define CC   1024
#define HH   16
#define HSS  64
#define NNtok 4096            // B*T
#define EPSGN 0.00064f

typedef unsigned short bf16u;
typedef __attribute__((ext_vector_type(8))) short short8;
typedef __attribute__((ext_vector_type(4))) float f32x4;
#define SLOT 4194304ull       // elements per 8MiB bf16 slot (= NNtok*CC)

__device__ __forceinline__ float bf2f(bf16u u){
  union { unsigned int i; float f; } cv; cv.i = ((unsigned int)u) << 16; return cv.f;
}
__device__ __forceinline__ unsigned short f2bfbits(unsigned int x){
  return (unsigned short)((x + 0x7fffu + ((x >> 16) & 1u)) >> 16);   // RNE
}
__device__ __forceinline__ bf16u f2bf(float f){
  union { float f; unsigned int i; } cv; cv.f = f;
  return f2bfbits(cv.i);
}
__device__ __forceinline__ void ld4bf(const bf16u* p, float* o){
  ushort4 u = *reinterpret_cast<const ushort4*>(p);
  o[0]=bf2f(u.x); o[1]=bf2f(u.y); o[2]=bf2f(u.z); o[3]=bf2f(u.w);
}
__device__ __forceinline__ void st4bf(bf16u* p, const float* v){
  ushort4 u; u.x=f2bf(v[0]); u.y=f2bf(v[1]); u.z=f2bf(v[2]); u.w=f2bf(v[3]);
  *reinterpret_cast<ushort4*>(p) = u;
}
__device__ __forceinline__ unsigned short f2h(float f){
  union { _Float16 h; unsigned short s; } c; c.h = (_Float16)f; return c.s;
}
__device__ __forceinline__ void st4h(bf16u* p, const float* v){
  ushort4 u; u.x=f2h(v[0]); u.y=f2h(v[1]); u.z=f2h(v[2]); u.w=f2h(v[3]);
  *reinterpret_cast<ushort4*>(p) = u;
}
__device__ __forceinline__ void ld4f(const float* p, float* o){
  float4 v = *reinterpret_cast<const float4*>(p);
  o[0]=v.x; o[1]=v.y; o[2]=v.z; o[3]=v.w;
}
__device__ __forceinline__ float sigm(float x){ return 1.f / (1.f + expf(-x)); }

// unpack helpers
__device__ __forceinline__ float bflo(unsigned int u){
  union { unsigned int i; float f; } c; c.i = u << 16; return c.f;
}
__device__ __forceinline__ float bfhi(unsigned int u){
  union { unsigned int i; float f; } c; c.i = u & 0xffff0000u; return c.f;
}
__device__ __forceinline__ float hlo(unsigned int u){
  union { unsigned short s; _Float16 h; } c; c.s = (unsigned short)(u & 0xffffu); return (float)c.h;
}
__device__ __forceinline__ float hhi(unsigned int u){
  union { unsigned short s; _Float16 h; } c; c.s = (unsigned short)(u >> 16); return (float)c.h;
}
__device__ __forceinline__ float hval(unsigned short s){
  union { unsigned short s; _Float16 h; } c; c.s = s; return (float)c.h;
}
__device__ __forceinline__ float dot4(const float* x, const float* y){
  return (x[0]*y[0] + x[1]*y[1]) + (x[2]*y[2] + x[3]*y[3]);
}

// 16-lane sum via DPP (groups must be 16-lane aligned). Pure VALU.
template<int CTRL>
__device__ __forceinline__ float dpp_add(float v){
  union { float f; int i; } a, b;
  a.f = v;
  b.i = __builtin_amdgcn_update_dpp(a.i, a.i, CTRL, 0xF, 0xF, false);
  return v + b.f;
}
__device__ __forceinline__ float red16(float v){
  v = dpp_add<0xB1>(v);    // quad_perm [1,0,3,2]  (xor 1)
  v = dpp_add<0x4E>(v);    // quad_perm [2,3,0,1]  (xor 2)
  v = dpp_add<0x124>(v);   // row_ror:4
  v = dpp_add<0x128>(v);   // row_ror:8
  return v;
}

// ---------------------------------------------------------------------------
// mix = x + (x[t-1]-x[t])*time_maa_x  (x[-1]=0), stored bf16
// ---------------------------------------------------------------------------
__global__ __launch_bounds__(256) void k_prep(const float* __restrict__ x,
                                              const float* __restrict__ tmx,
                                              bf16u* __restrict__ MIX){
  int e = (blockIdx.x * 256 + threadIdx.x) * 4;
  int n = e >> 10;
  int c = e & (CC - 1);
  int t = n & (TT - 1);
  float xf[4]; ld4f(x + e, xf);
  float pf[4] = {0.f, 0.f, 0.f, 0.f};
  if (t > 0) ld4f(x + e - CC, pf);
  float tm[4]; ld4f(tmx + c, tm);
  float mv[4];
  #pragma unroll
  for (int i = 0; i < 4; ++i) mv[i] = xf[i] + (pf[i] - xf[i]) * tm[i];
  st4bf(MIX + e, mv);
}

// ---------------------------------------------------------------------------
// MFMA NT GEMM: OUT[M,Nd] = X[M,K](bf16) @ W[Nd,K]^T, W as up to 3 row-blocks
// (f32). tanh on cols < act_n. OB: bf16 out else f32. 128x128, BK=32.
// ---------------------------------------------------------------------------
template<bool OB>
__global__ __launch_bounds__(256) void k_gemm_mfma(const bf16u* __restrict__ X,
                                                   const float* __restrict__ Wa,
                                                   const float* __restrict__ Wb,
                                                   const float* __restrict__ Wc,
                                                   int na, int nab,
                                                   void* __restrict__ OUTv,
                                                   int Nd, int Kd, int act_n){
  __shared__ short As[128 * 40];
  __shared__ short Bs[128 * 40];
  const int tid  = threadIdx.x;
  const int lane = tid & 63;
  const int wv   = tid >> 6;
  const int wm   = wv >> 1, wn = wv & 1;
  const int bn0  = blockIdx.x * 128;
  const int bm0  = blockIdx.y * 128;
  const int l15  = lane & 15;
  const int quad = lane >> 4;

  f32x4 acc[4][4];
  #pragma unroll
  for (int mi = 0; mi < 4; ++mi)
    #pragma unroll
    for (int ni = 0; ni < 4; ++ni)
      #pragma unroll
      for (int rg = 0; rg < 4; ++rg) acc[mi][ni][rg] = 0.f;

  const int r    = tid >> 1;
  const int half = (tid & 1) * 16;

  int rr = bn0 + r;
  const float* wsrc = nullptr;
  if (rr < na)        wsrc = Wa + (size_t)rr * Kd;
  else if (rr < nab)  wsrc = Wb + (size_t)(rr - na) * Kd;
  else if (rr < Nd)   wsrc = Wc + (size_t)(rr - nab) * Kd;
  const bf16u* xsrc = X + (size_t)(bm0 + r) * Kd;

  for (int k0 = 0; k0 < Kd; k0 += 32){
    uint4 xa = *(const uint4*)(xsrc + k0 + half);
    uint4 xb = *(const uint4*)(xsrc + k0 + half + 8);
    uint4 w0 = make_uint4(0,0,0,0), w1 = w0, w2 = w0, w3 = w0;
    if (wsrc){
      w0 = *(const uint4*)(wsrc + k0 + half);
      w1 = *(const uint4*)(wsrc + k0 + half + 4);
      w2 = *(const uint4*)(wsrc + k0 + half + 8);
      w3 = *(const uint4*)(wsrc + k0 + half + 12);
    }
    union { unsigned short s[8]; uint4 v; } p0, p1;
    p0.s[0]=f2bfbits(w0.x); p0.s[1]=f2bfbits(w0.y); p0.s[2]=f2bfbits(w0.z); p0.s[3]=f2bfbits(w0.w);
    p0.s[4]=f2bfbits(w1.x); p0.s[5]=f2bfbits(w1.y); p0.s[6]=f2bfbits(w1.z); p0.s[7]=f2bfbits(w1.w);
    p1.s[0]=f2bfbits(w2.x); p1.s[1]=f2bfbits(w2.y); p1.s[2]=f2bfbits(w2.z); p1.s[3]=f2bfbits(w2.w);
    p1.s[4]=f2bfbits(w3.x); p1.s[5]=f2bfbits(w3.y); p1.s[6]=f2bfbits(w3.z); p1.s[7]=f2bfbits(w3.w);

    *(uint4*)&As[r * 40 + half]     = xa;
    *(uint4*)&As[r * 40 + half + 8] = xb;
    *(uint4*)&Bs[r * 40 + half]     = p0.v;
    *(uint4*)&Bs[r * 40 + half + 8] = p1.v;
    __syncthreads();

    short8 af[4], bfg[4];
    #pragma unroll
    for (int mi = 0; mi < 4; ++mi)
      af[mi] = *(const short8*)&As[(wm*64 + mi*16 + l15) * 40 + quad*8];
    #pragma unroll
    for (int ni = 0; ni < 4; ++ni)
      bfg[ni] = *(const short8*)&Bs[(wn*64 + ni*16 + l15) * 40 + quad*8];
    #pragma unroll
    for (int mi = 0; mi < 4; ++mi)
      #pragma unroll
      for (int ni = 0; ni < 4; ++ni)
        acc[mi][ni] = __builtin_amdgcn_mfma_f32_16x16x32_bf16(af[mi], bfg[ni], acc[mi][ni], 0, 0, 0);
    __syncthreads();
  }

  #pragma unroll
  for (int mi = 0; mi < 4; ++mi){
    #pragma unroll
    for (int ni = 0; ni < 4; ++ni){
      int col = bn0 + wn*64 + ni*16 + l15;
      if (col >= Nd) continue;
      #pragma unroll
      for (int rg = 0; rg < 4; ++rg){
        int row = bm0 + wm*64 + mi*16 + quad*4 + rg;
        float v = acc[mi][ni][rg];
        if (col < act_n) v = tanhf(v);
        if (OB) ((bf16u*)OUTv)[(size_t)row * Nd + col] = f2bf(v);
        else    ((float*)OUTv)[(size_t)row * Nd + col] = v;
      }
    }
  }
}

// ---------------------------------------------------------------------------
// MFMA NN GEMM: OUT[M, CC] = A[M, KD](bf16, row stride lda) @ B[KD, CC](f32).
// EP=0: plain bf16 store. EP=1: token-shift epilogue.
// ---------------------------------------------------------------------------
template<int KD, int EP>
__global__ __launch_bounds__(256) void k_gemm_nn(const bf16u* __restrict__ A, int lda,
                                                 const float* __restrict__ B,
                                                 bf16u* __restrict__ OUT,
                                                 const float* __restrict__ x,
                                                 const float* __restrict__ tma_g){
  __shared__ short As[128 * (KD + 8)];
  __shared__ short Bs[128 * (KD + 8)];
  const int tid  = threadIdx.x;
  const int lane = tid & 63;
  const int wv   = tid >> 6;
  const int wm   = wv >> 1, wn = wv & 1;
  const int bn0  = blockIdx.x * 128;
  const int bm0  = blockIdx.y * 128;
  const int l15  = lane & 15;
  const int quad = lane >> 4;

  for (int idx = tid; idx < 128 * (KD / 8); idx += 256){
    int r  = idx / (KD / 8);
    int kc = (idx % (KD / 8)) * 8;
    *(uint4*)&As[r * (KD + 8) + kc] =
        *(const uint4*)(A + (size_t)(bm0 + r) * lda + kc);
  }
  for (int idx = tid; idx < KD * 128; idx += 256){
    int k = idx >> 7, c = idx & 127;
    Bs[c * (KD + 8) + k] = (short)f2bf(B[(size_t)k * CC + bn0 + c]);
  }
  __syncthreads();

  f32x4 acc[4][4];
  #pragma unroll
  for (int mi = 0; mi < 4; ++mi)
    #pragma unroll
    for (int ni = 0; ni < 4; ++ni)
      #pragma unroll
      for (int rg = 0; rg < 4; ++rg) acc[mi][ni][rg] = 0.f;

  #pragma unroll
  for (int kk = 0; kk < KD; kk += 32){
    short8 af[4], bfg[4];
    #pragma unroll
    for (int mi = 0; mi < 4; ++mi)
      af[mi] = *(const short8*)&As[(wm*64 + mi*16 + l15) * (KD + 8) + kk + quad*8];
    #pragma unroll
    for (int ni = 0; ni < 4; ++ni)
      bfg[ni] = *(const short8*)&Bs[(wn*64 + ni*16 + l15) * (KD + 8) + kk + quad*8];
    #pragma unroll
    for (int mi = 0; mi < 4; ++mi)
      #pragma unroll
      for (int ni = 0; ni < 4; ++ni)
        acc[mi][ni] = __builtin_amdgcn_mfma_f32_16x16x32_bf16(af[mi], bfg[ni], acc[mi][ni], 0, 0, 0);
  }

  #pragma unroll
  for (int mi = 0; mi < 4; ++mi){
    #pragma unroll
    for (int ni = 0; ni < 4; ++ni){
      int col = bn0 + wn*64 + ni*16 + l15;
      float tm = (EP == 1) ? tma_g[col] : 0.f;
      #pragma unroll
      for (int rg = 0; rg < 4; ++rg){
        int row = bm0 + wm*64 + mi*16 + quad*4 + rg;
        float v = acc[mi][ni][rg];
        if (EP == 1){
          float xv = x[(size_t)row * CC + col];
          float xp = ((row & (TT - 1)) == 0) ? 0.f : x[(size_t)row * CC + col - CC];
          v = xv + (xp - xv) * (v + tm);
        }
        OUT[(size_t)row * CC + col] = f2bf(v);
      }
    }
  }
}

// ---------------------------------------------------------------------------
// Fused elementwise + pair precompute, 4 tokens (2 pairs) per block.
// Per token: a=kkn, b, kf, -u (f16, self-normalizing; validated r4/r5).
// Per pair (linearity of the recurrence, all vs base S_{t-1}):
//   u1  = wd_t∘a_{t+1} + (b_t·a_{t+1})a_t      -> KKN odd row
//   q'_e = wd_t∘q_t + (b_t·q_t)a_t             -> R even row (in place)
//   z    = wd_{t+1}∘q_{t+1} + (b_{t+1}·q_{t+1})a_{t+1}
//   q'_o = wd_t∘z + (b_t·z)a_t                 -> R odd row (in place)
//   scalars (d=k_t·a_{t+1}, e1=k_t·q_t, e20=k_t·z, e21=k_{t+1}·q_{t+1})
//     -> Dsc float4 per (pair, head)
// Also rk = red16(r·kf·faaaa) per (token, head) -> RKsc (frees R for the
// in-place q' transform; k_post no longer reads R/KF/faaaa).
// wd uses the f16-ROUNDTRIPPED -u so precompute & k_rec use identical decay.
// ---------------------------------------------------------------------------
__global__ __launch_bounds__(256) void k_elem(bf16u* __restrict__ K0,
    const bf16u* __restrict__ P1, const bf16u* __restrict__ P2,
    const bf16u* __restrict__ W2A,
    const float* __restrict__ kw2, const float* __restrict__ aw2,
    const float* __restrict__ maw2, const float* __restrict__ mkw2,
    const float* __restrict__ td,  const float* __restrict__ taa,
    const float* __restrict__ tma, const float* __restrict__ tmk,
    const float* __restrict__ faaaa,
    bf16u* __restrict__ KKN, bf16u* __restrict__ Bb, bf16u* __restrict__ UX,
    bf16u* __restrict__ Rq, float* __restrict__ Dsc, float* __restrict__ RKsc){
  int n0 = blockIdx.x * 4, tid = threadIdx.x;
  __shared__ float at_l[4][16], mat_l[4][16], kt_l[4][16], mkt_l[4][16];
  {
    int grp = tid >> 6, q = tid & 63, tt = q >> 4, j = q & 15;
    if (grp == 0)      at_l[tt][j]  = bf2f(P1[(size_t)(n0+tt)*96 + 64 + j]);
    else if (grp == 1) mat_l[tt][j] = bf2f(P1[(size_t)(n0+tt)*96 + 80 + j]);
    else if (grp == 2) kt_l[tt][j]  = bf2f(P2[(size_t)(n0+tt)*32 + j]);
    else               mkt_l[tt][j] = bf2f(P2[(size_t)(n0+tt)*32 + 16 + j]);
  }
  __syncthreads();
  int c  = tid * 4;
  int h  = tid >> 4;       // head (16 lanes per head)
  int lg = tid & 15;

  float kkk[4][4], aa[4][4], mam[4][4], mkm[4][4];
  #pragma unroll
  for (int tt = 0; tt < 4; ++tt)
    #pragma unroll
    for (int i = 0; i < 4; ++i){ kkk[tt][i]=0; aa[tt][i]=0; mam[tt][i]=0; mkm[tt][i]=0; }

  #pragma unroll 4
  for (int j = 0; j < 16; ++j){
    float wk[4], wa[4], wm[4], wq[4];
    ld4f(kw2  + (size_t)j*CC + c, wk);
    ld4f(aw2  + (size_t)j*CC + c, wa);
    ld4f(maw2 + (size_t)j*CC + c, wm);
    ld4f(mkw2 + (size_t)j*CC + c, wq);
    #pragma unroll
    for (int tt = 0; tt < 4; ++tt){
      float s1 = kt_l[tt][j], s2 = at_l[tt][j], s3 = mat_l[tt][j], s4 = mkt_l[tt][j];
      #pragma unroll
      for (int i = 0; i < 4; ++i){
        kkk[tt][i] += s1 * wk[i];
        aa[tt][i]  += s2 * wa[i];
        mam[tt][i] += s3 * wm[i];
        mkm[tt][i] += s4 * wq[i];
      }
    }
  }

  float td4[4], taa4[4], tma4[4], tmk4[4], fa4[4];
  ld4f(td + c, td4); ld4f(taa + c, taa4); ld4f(tma + c, tma4); ld4f(tmk + c, tmk4);
  ld4f(faaaa + c, fa4);

// per-token elementwise: fills A_ (kkn), B_ (b), KF_ (k), WD_ (decay factor),
// stores Bb, K0, UX. KKN stored by caller (even=a, odd=u1).
#define ELEM_TOKEN(TT_, E_, A_, B_, KF_, WD_) do{ \
    float k0a[4]; ld4bf(K0 + (E_), k0a); \
    float w2a[4]; ld4bf(W2A + (E_), w2a); \
    float ssq = 0.f; \
    _Pragma("unroll") \
    for (int i = 0; i < 4; ++i){ A_[i] = k0a[i] + kkk[TT_][i]; ssq += A_[i]*A_[i]; } \
    ssq = red16(ssq); \
    float rinv = 1.f / fmaxf(sqrtf(ssq), 1e-12f); \
    float outw_[4]; \
    _Pragma("unroll") \
    for (int i = 0; i < 4; ++i){ \
      float z  = td4[i] + w2a[i]; \
      float nz = -z; \
      float sp = (nz > 15.f) ? nz : log1pf(expf(nz)); \
      float w  = -sp - 0.5f; \
      float av  = sigm(taa4[i] + aa[TT_][i]); \
      float mav = sigm(tma4[i] + mam[TT_][i]); \
      float mkv = sigm(tmk4[i] + mkm[TT_][i]); \
      A_[i] *= rinv; \
      B_[i]  = -A_[i] * av; \
      KF_[i] = k0a[i] * (mav + av * (1.f - mav)) * expf(w * mkv); \
      float ou = -expf(w); \
      outw_[i] = ou; \
      WD_[i]   = __expf(hval(f2h(ou)));     /* f16-consistent decay */ \
    } \
    st4bf(Bb + (E_), B_); \
    st4bf(K0 + (E_), KF_); \
    st4h (UX + (E_), outw_); \
  }while(0)

  #pragma unroll
  for (int p = 0; p < 2; ++p){
    const int ttE = 2*p, ttO = ttE + 1;
    size_t eE = (size_t)(n0 + ttE) * CC + c;
    size_t eO = eE + CC;
    float aE[4], bE[4], kfE[4], wdE[4];
    float aO[4], bO[4], kfO[4], wdO[4];
    ELEM_TOKEN(ttE, eE, aE, bE, kfE, wdE);
    ELEM_TOKEN(ttO, eO, aO, bO, kfO, wdO);
    st4bf(KKN + eE, aE);

    float rE[4], rO[4];
    ld4bf(Rq + eE, rE); ld4bf(Rq + eO, rO);

    // rk for k_post (before R is overwritten)
    float rkE = red16(rE[0]*kfE[0]*fa4[0] + rE[1]*kfE[1]*fa4[1]
                    + rE[2]*kfE[2]*fa4[2] + rE[3]*kfE[3]*fa4[3]);
    float rkO = red16(rO[0]*kfO[0]*fa4[0] + rO[1]*kfO[1]*fa4[1]
                    + rO[2]*kfO[2]*fa4[2] + rO[3]*kfO[3]*fa4[3]);

    // u1 over KKN odd row
    float c1 = red16(dot4(bE, aO));
    float d  = red16(dot4(kfE, aO));
    float u1[4];
    #pragma unroll
    for (int i = 0; i < 4; ++i) u1[i] = wdE[i]*aO[i] + c1*aE[i];
    st4bf(KKN + eO, u1);

    // q' even
    float cq = red16(dot4(bE, rE));
    float e1 = red16(dot4(kfE, rE));
    float qe[4];
    #pragma unroll
    for (int i = 0; i < 4; ++i) qe[i] = wdE[i]*rE[i] + cq*aE[i];
    st4bf(Rq + eE, qe);

    // z = M_{t+1} q_{t+1}; q' odd = M_t z
    float cz  = red16(dot4(bO, rO));
    float e21 = red16(dot4(kfO, rO));
    float z[4];
    #pragma unroll
    for (int i = 0; i < 4; ++i) z[i] = wdO[i]*rO[i] + cz*aO[i];
    float cy  = red16(dot4(bE, z));
    float e20 = red16(dot4(kfE, z));
    float qo[4];
    #pragma unroll
    for (int i = 0; i < 4; ++i) qo[i] = wdE[i]*z[i] + cy*aE[i];
    st4bf(Rq + eO, qo);

    if (lg == 0){
      size_t pr = (size_t)((n0 + ttE) >> 1);
      float4 dv; dv.x = d; dv.y = e1; dv.z = e20; dv.w = e21;
      *(float4*)(Dsc + (pr * HH + h) * 4) = dv;
      RKsc[(size_t)(n0 + ttE) * HH + h] = rkE;
      RKsc[(size_t)(n0 + ttO) * HH + h] = rkO;
    }
  }
#undef ELEM_TOKEN
}

// ---------------------------------------------------------------------------
// Recurrence v11: 16-lane rows, 2-step pairs, ALL FOUR reductions (sa_E,
// sa_O, y_E, y_O) are dots against the same base S via the k_elem transform
// -> 4 independent red16 chains pipeline back-to-back; yp no longer depends
// on the post-update S; deferred-flush machinery gone. Scalar fixups come
// from one float4 (Dsc). XCD clustering kept (FETCH 98->25MB).
// ---------------------------------------------------------------------------
__global__ __launch_bounds__(256) void k_rec(const bf16u* __restrict__ Qp,
                                             const bf16u* __restrict__ WT,
                                             const bf16u* __restrict__ KFt,
                                             const bf16u* __restrict__ Vt,
                                             const bf16u* __restrict__ Aa,
                                             const bf16u* __restrict__ Bv,
                                             const float* __restrict__ Dsc,
                                             bf16u* __restrict__ Y){
  const int p  = blockIdx.x;                 // 0..255
  const int g  = (p & 7) | ((p >> 5) << 3);  // (b,h) group 0..63, XCD-clustered
  const int rg = (p >> 3) & 3;               // row quartet within the head
  const int b  = g >> 4;
  const int h  = g & 15;
  const int tid = threadIdx.x;
  const int cg  = tid & 15;                  // 16 lanes per row
  const int i   = rg * 16 + (tid >> 4);      // state row 0..63
  const size_t base0 = (size_t)(b * TT) * CC + h * HSS;
  const size_t colb  = base0 + cg * 4;
  const size_t rowb  = base0 + i;
  const size_t dscb  = ((size_t)(b * (TT/2)) * HH + h) * 4;

  float S0 = 0.f, S1 = 0.f, S2 = 0.f, S3 = 0.f;

  uint2 qEA,qOA,aEA,uOA,kEA,kOA,bEA,bOA,wEA,wOA; unsigned short vEA,vOA; float4 dA;
  uint2 qEB,qOB,aEB,uOB,kEB,kOB,bEB,bOB,wEB,wOB; unsigned short vEB,vOB; float4 dB;
  uint2 qEC,qOC,aEC,uOC,kEC,kOC,bEC,bOC,wEC,wOC; unsigned short vEC,vOC; float4 dC;
  uint2 qED,qOD,aED,uOD,kED,kOD,bED,bOD,wED,wOD; unsigned short vED,vOD; float4 dD;

#define PL(S, T_) do{ \
    size_t cE_ = colb + (size_t)(T_) * CC, cO_ = cE_ + CC; \
    qE##S = *(const uint2*)(Qp  + cE_); qO##S = *(const uint2*)(Qp  + cO_); \
    aE##S = *(const uint2*)(Aa  + cE_); uO##S = *(const uint2*)(Aa  + cO_); \
    kE##S = *(const uint2*)(KFt + cE_); kO##S = *(const uint2*)(KFt + cO_); \
    bE##S = *(const uint2*)(Bv  + cE_); bO##S = *(const uint2*)(Bv  + cO_); \
    wE##S = *(const uint2*)(WT  + cE_); wO##S = *(const uint2*)(WT  + cO_); \
    vE##S = Vt[rowb + (size_t)(T_) * CC]; \
    vO##S = Vt[rowb + (size_t)(T_ + 1) * CC]; \
    d##S  = *(const float4*)(Dsc + dscb + (size_t)((T_) >> 1) * (HH*4)); \
  }while(0)

#define PSTEP(S, T_) do{ \
    float a0=bflo(aE##S.x), a1=bfhi(aE##S.x), a2=bflo(aE##S.y), a3=bfhi(aE##S.y); \
    float u0=bflo(uO##S.x), u1=bfhi(uO##S.x), u2=bflo(uO##S.y), u3=bfhi(uO##S.y); \
    float g0=bflo(qE##S.x), g1=bfhi(qE##S.x), g2=bflo(qE##S.y), g3=bfhi(qE##S.y); \
    float o0=bflo(qO##S.x), o1=bfhi(qO##S.x), o2=bflo(qO##S.y), o3=bfhi(qO##S.y); \
    float pE_ = (S0*a0 + S1*a1) + (S2*a2 + S3*a3); \
    float pO_ = (S0*u0 + S1*u1) + (S2*u2 + S3*u3); \
    float yE_ = (S0*g0 + S1*g1) + (S2*g2 + S3*g3); \
    float yO_ = (S0*o0 + S1*o1) + (S2*o2 + S3*o3); \
    pE_ = red16(pE_); \
    pO_ = red16(pO_); \
    yE_ = red16(yE_); \
    yO_ = red16(yO_); \
    float vEf = bf2f(vE##S), vOf = bf2f(vO##S); \
    float saE = pE_; \
    float saO = fmaf(d##S.x, vEf, pO_); \
    float ypE = fmaf(d##S.y, vEf, yE_); \
    float ypO = fmaf(d##S.z, vEf, fmaf(d##S.w, vOf, yO_)); \
    float k0=bflo(kE##S.x), k1=bfhi(kE##S.x), k2=bflo(kE##S.y), k3=bfhi(kE##S.y); \
    float b0=bflo(bE##S.x), b1=bfhi(bE##S.x), b2=bflo(bE##S.y), b3=bfhi(bE##S.y); \
    float w0=__expf(hlo(wE##S.x)), w1=__expf(hhi(wE##S.x)); \
    float w2=__expf(hlo(wE##S.y)), w3=__expf(hhi(wE##S.y)); \
    S0 = fmaf(S0, w0, fmaf(saE, b0, vEf * k0)); \
    S1 = fmaf(S1, w1, fmaf(saE, b1, vEf * k1)); \
    S2 = fmaf(S2, w2, fmaf(saE, b2, vEf * k2)); \
    S3 = fmaf(S3, w3, fmaf(saE, b3, vEf * k3)); \
    float ko0=bflo(kO##S.x), ko1=bfhi(kO##S.x), ko2=bflo(kO##S.y), ko3=bfhi(kO##S.y); \
    float bo0=bflo(bO##S.x), bo1=bfhi(bO##S.x), bo2=bflo(bO##S.y), bo3=bfhi(bO##S.y); \
    float wo0=__expf(hlo(wO##S.x)), wo1=__expf(hhi(wO##S.x)); \
    float wo2=__expf(hlo(wO##S.y)), wo3=__expf(hhi(wO##S.y)); \
    S0 = fmaf(S0, wo0, fmaf(saO, bo0, vOf * ko0)); \
    S1 = fmaf(S1, wo1, fmaf(saO, bo1, vOf * ko1)); \
    S2 = fmaf(S2, wo2, fmaf(saO, bo2, vOf * ko2)); \
    S3 = fmaf(S3, wo3, fmaf(saO, bo3, vOf * ko3)); \
    if (cg == 0){ \
      Y[rowb + (size_t)(T_) * CC]     = f2bf(ypE); \
      Y[rowb + (size_t)(T_ + 1) * CC] = f2bf(ypO); \
    } \
  }while(0)

  PL(A, 0); PL(B, 2); PL(C, 4); PL(D, 6);
  for (int t = 0; t < TT; t += 8){
    PSTEP(A, t);
    if (t + 8  < TT) PL(A, t + 8);
    PSTEP(B, t + 2);
    if (t + 10 < TT) PL(B, t + 10);
    PSTEP(C, t + 4);
    if (t + 12 < TT) PL(C, t + 12);
    PSTEP(D, t + 6);
    if (t + 14 < TT) PL(D, t + 14);
  }
#undef PL
#undef PSTEP
}

// ---------------------------------------------------------------------------
// Post: GroupNorm + precomputed bonus rk*v + precomputed gate GV -> YG (bf16)
// ---------------------------------------------------------------------------
__global__ __launch_bounds__(256) void k_post(const bf16u* __restrict__ Y,
                                              const bf16u* __restrict__ Vt,
                                              const bf16u* __restrict__ GV,
                                              const float* __restrict__ lnw,
                                              const float* __restrict__ lnb,
                                              const float* __restrict__ RKsc,
                                              bf16u* __restrict__ YG){
  int n = blockIdx.x, tid = threadIdx.x;
  int c = tid * 4;
  size_t e = (size_t)n * CC + c;

  float ya[4]; ld4bf(Y + e, ya);
  float s = ya[0] + ya[1] + ya[2] + ya[3];
  s = red16(s);
  float mu = s * (1.f / 64.f);
  float d[4], vs = 0.f;
  #pragma unroll
  for (int i = 0; i < 4; ++i){ d[i] = ya[i] - mu; vs += d[i] * d[i]; }
  vs = red16(vs);
  float rstd = rsqrtf(vs * (1.f / 64.f) + EPSGN);

  float rk = RKsc[(size_t)n * HH + (tid >> 4)];

  float va[4]; ld4bf(Vt + e, va);
  float lw4[4], lb4[4];
  ld4f(lnw + c, lw4); ld4f(lnb + c, lb4);
  float g[4]; ld4bf(GV + e, g);
  float o[4];
  #pragma unroll
  for (int i = 0; i < 4; ++i){
    float yn = d[i] * rstd * lw4[i] + lb4[i] + rk * va[i];
    o[i] = yn * g[i];
  }
  st4bf(YG + e, o);
}

// ---------------------------------------------------------------------------
extern "C" void kernel_launch(void* const* d_in, const int* in_sizes, int n_in,
                              void* d_out, int out_size, void* d_ws, size_t ws_size,
                              hipStream_t stream){
  (void)in_sizes; (void)n_in; (void)out_size; (void)ws_size;
  const float* x        = (const float*)d_in[0];
  const float* tmx      = (const float*)d_in[1];
  const float* tmaa     = (const float*)d_in[2];
  const float* maa_w1   = (const float*)d_in[3];
  const float* maa_w2   = (const float*)d_in[4];
  const float* decay_w1 = (const float*)d_in[5];
  const float* decay_w2 = (const float*)d_in[6];
  const float* aaa_w1   = (const float*)d_in[7];
  const float* aaa_w2   = (const float*)d_in[8];
  const float* kkk_w1   = (const float*)d_in[9];
  const float* kkk_w2   = (const float*)d_in[10];
  const float* gate_w1  = (const float*)d_in[11];
  const float* gate_w2  = (const float*)d_in[12];
  const float* ma_w1    = (const float*)d_in[13];
  const float* ma_w2    = (const float*)d_in[14];
  const float* mk_w1    = (const float*)d_in[15];
  const float* mk_w2    = (const float*)d_in[16];
  const float* t_decay  = (const float*)d_in[17];
  const float* t_faaaa  = (const float*)d_in[18];
  const float* t_aaaaa  = (const float*)d_in[19];
  const float* t_misc_a = (const float*)d_in[20];
  const float* t_misc_k = (const float*)d_in[21];
  const float* Wr       = (const float*)d_in[22];
  const float* Wk       = (const float*)d_in[23];
  const float* Wv       = (const float*)d_in[24];
  const float* Wo       = (const float*)d_in[25];
  const float* ln_w     = (const float*)d_in[26];
  const float* ln_b     = (const float*)d_in[27];

  // Slot map (8MiB bf16 each), 56 MiB + ~3.8 MiB smalls:
  // S0: MIX -> X0 -> KKN(a even / u1 odd) -> YG | S1: X1 -> Bb -> GV
  // S2: X2 -> UX(-u f16) | S3: X3 -> W2A -> Yb | S4: R -> q' | S5: K0 -> KF
  // S6: V
  bf16u* bw  = (bf16u*)d_ws;
  bf16u* MIX = bw + 0*SLOT;
  bf16u* X0  = bw + 0*SLOT;
  bf16u* KKN = bw + 0*SLOT;
  bf16u* YG  = bw + 0*SLOT;
  bf16u* X1  = bw + 1*SLOT;
  bf16u* Bb  = bw + 1*SLOT;
  bf16u* GV  = bw + 1*SLOT;
  bf16u* X2  = bw + 2*SLOT;
  bf16u* UX  = bw + 2*SLOT;
  bf16u* X3  = bw + 3*SLOT;
  bf16u* W2A = bw + 3*SLOT;
  bf16u* Yb  = bw + 3*SLOT;
  bf16u* R   = bw + 4*SLOT;   // becomes q'
  bf16u* K0  = bw + 5*SLOT;   // becomes KF
  bf16u* V   = bw + 6*SLOT;
  char*  wsb = (char*)d_ws;
  bf16u* LO  = (bf16u*)(wsb + (56ull<<20));   // [N,128] bf16, 1 MiB
  bf16u* GT  = (bf16u*)(wsb + (57ull<<20));   // [N,128] bf16, 1 MiB
  bf16u* P1  = (bf16u*)(wsb + (58ull<<20));   // [N,96]  bf16 (dt|at|ma)
  bf16u* P2  = (bf16u*)(wsb + (58ull<<20) + (768ull<<10)); // [N,32] bf16
  float* Dsc = (float*)(wsb + (59ull<<20));   // [N/2,16] float4, 512 KiB
  float* RKsc= (float*)(wsb + (59ull<<20) + (512ull<<10)); // [N,16] f32, 256 KiB

  // 1. mix
  k_prep<<<4096, 256, 0, stream>>>(x, tmx, MIX);
  // 2. lo = tanh(mix @ maa_w1^T) [N,128] bf16
  k_gemm_mfma<true><<<dim3(1,32),256,0,stream>>>(MIX, maa_w1, maa_w1, maa_w1,
                                                 128, 128, LO, 128, CC, 128);
  // 3. xm[g] = x + xx*(lo_g @ maa_w2_g + tmaa_g)   (NN GEMM + fused epilogue)
  bf16u* XMs[4] = {X0, X1, X2, X3};
  for (int g = 0; g < 4; ++g)
    k_gemm_nn<32,1><<<dim3(8,32),256,0,stream>>>(LO + g*32, 128,
                                                 maa_w2 + (size_t)g*32*CC,
                                                 XMs[g], x, tmaa + (size_t)g*CC);
  // 4. big projections (bf16 out)
  k_gemm_mfma<true><<<dim3(8,32),256,0,stream>>>(X0, Wr, Wr, Wr, CC, CC, R,  CC, CC, 0);
  k_gemm_mfma<true><<<dim3(8,32),256,0,stream>>>(X2, Wk, Wk, Wk, CC, CC, K0, CC, CC, 0);
  k_gemm_mfma<true><<<dim3(8,32),256,0,stream>>>(X3, Wv, Wv, Wv, CC, CC, V,  CC, CC, 0);
  // 5. first-stage LoRA projections (bf16 out)
  k_gemm_mfma<true><<<dim3(1,32),256,0,stream>>>(X0, gate_w1, gate_w1, gate_w1,
                                                 128, 128, GT, 128, CC, 128);
  k_gemm_mfma<true><<<dim3(1,32),256,0,stream>>>(X1, decay_w1, aaa_w1, ma_w1,
                                                 64, 80, P1, 96, CC, 64);
  k_gemm_mfma<true><<<dim3(1,32),256,0,stream>>>(X2, kkk_w1, mk_w1, mk_w1,
                                                 16, 32, P2, 32, CC, 16);
  // 6. decay second-stage projection: W2A = P1[:, :64] @ decay_w2  -> S3
  k_gemm_nn<64,0><<<dim3(8,32),256,0,stream>>>(P1, 96, decay_w2, W2A, nullptr, nullptr);
  // 7. fused elementwise + pair precompute (u1, q', scalars, rk)
  k_elem<<<1024, 256, 0, stream>>>(K0, P1, P2, W2A,
                                   kkk_w2, aaa_w2, ma_w2, mk_w2,
                                   t_decay, t_aaaaa, t_misc_a, t_misc_k, t_faaaa,
                                   KKN, Bb, UX, R, Dsc, RKsc);
  // 8. delta-rule recurrence (v11: all-4-reductions-from-base-S pairs)
  k_rec<<<256, 256, 0, stream>>>(R, UX, K0, V, KKN, Bb, Dsc, Yb);
  // 9. gate second-stage: GV = GT @ gate_w2 -> S1 (Bb dead after k_rec)
  k_gemm_nn<128,0><<<dim3(8,32),256,0,stream>>>(GT, 128, gate_w2, GV, nullptr, nullptr);
  // 10. groupnorm + bonus + gate
  k_post<<<4096, 256, 0, stream>>>(Yb, V, GV, ln_w, ln_b, RKsc, YG);
  // 11. out = yg @ Wo^T -> f32
  k_gemm_mfma<false><<<dim3(8,32),256,0,stream>>>(YG, Wo, Wo, Wo, CC, CC, d_out, CC, CC, 0);
}

// Round 7
// 849.726 us; speedup vs baseline: 1.1547x; 1.0002x over previous
//
#include <hip/hip_runtime.h>
#include <cstdint>
#include <cstddef>

// Problem constants
#define BB   4
#define TT   1024
#define CC   1024
#define HH   16
#define HSS  64
#define NNtok 4096            // B*T
#define EPSGN 0.00064f

typedef unsigned short bf16u;
typedef __attribute__((ext_vector_type(8))) short short8;
typedef __attribute__((ext_vector_type(4))) float f32x4;
#define SLOT 4194304ull       // elements per 8MiB bf16 slot (= NNtok*CC)

__device__ __forceinline__ float bf2f(bf16u u){
  union { unsigned int i; float f; } cv; cv.i = ((unsigned int)u) << 16; return cv.f;
}
__device__ __forceinline__ unsigned short f2bfbits(unsigned int x){
  return (unsigned short)((x + 0x7fffu + ((x >> 16) & 1u)) >> 16);   // RNE
}
__device__ __forceinline__ bf16u f2bf(float f){
  union { float f; unsigned int i; } cv; cv.f = f;
  return f2bfbits(cv.i);
}
__device__ __forceinline__ void ld4bf(const bf16u* p, float* o){
  ushort4 u = *reinterpret_cast<const ushort4*>(p);
  o[0]=bf2f(u.x); o[1]=bf2f(u.y); o[2]=bf2f(u.z); o[3]=bf2f(u.w);
}
__device__ __forceinline__ void st4bf(bf16u* p, const float* v){
  ushort4 u; u.x=f2bf(v[0]); u.y=f2bf(v[1]); u.z=f2bf(v[2]); u.w=f2bf(v[3]);
  *reinterpret_cast<ushort4*>(p) = u;
}
__device__ __forceinline__ unsigned short f2h(float f){
  union { _Float16 h; unsigned short s; } c; c.h = (_Float16)f; return c.s;
}
__device__ __forceinline__ void st4h(bf16u* p, const float* v){
  ushort4 u; u.x=f2h(v[0]); u.y=f2h(v[1]); u.z=f2h(v[2]); u.w=f2h(v[3]);
  *reinterpret_cast<ushort4*>(p) = u;
}
__device__ __forceinline__ void ld4f(const float* p, float* o){
  float4 v = *reinterpret_cast<const float4*>(p);
  o[0]=v.x; o[1]=v.y; o[2]=v.z; o[3]=v.w;
}
__device__ __forceinline__ float sigm(float x){ return 1.f / (1.f + expf(-x)); }

// unpack helpers
__device__ __forceinline__ float bflo(unsigned int u){
  union { unsigned int i; float f; } c; c.i = u << 16; return c.f;
}
__device__ __forceinline__ float bfhi(unsigned int u){
  union { unsigned int i; float f; } c; c.i = u & 0xffff0000u; return c.f;
}
__device__ __forceinline__ float hlo(unsigned int u){
  union { unsigned short s; _Float16 h; } c; c.s = (unsigned short)(u & 0xffffu); return (float)c.h;
}
__device__ __forceinline__ float hhi(unsigned int u){
  union { unsigned short s; _Float16 h; } c; c.s = (unsigned short)(u >> 16); return (float)c.h;
}
__device__ __forceinline__ float hval(unsigned short s){
  union { unsigned short s; _Float16 h; } c; c.s = s; return (float)c.h;
}
__device__ __forceinline__ float dot4(const float* x, const float* y){
  return (x[0]*y[0] + x[1]*y[1]) + (x[2]*y[2] + x[3]*y[3]);
}

// 16-lane sum via DPP. old=0 + bound_ctrl=1 is the canonical GCNDPPCombine
// pattern: folds into a single v_add_f32_dpp (vs mov_dpp+add = 2 instrs).
// Semantically identical here: quad_perm / row_ror never produce invalid
// source lanes, so bound_ctrl's zero-fill never triggers.
template<int CTRL>
__device__ __forceinline__ float dpp_add(float v){
  union { float f; int i; } a, b;
  a.f = v;
  b.i = __builtin_amdgcn_update_dpp(0, a.i, CTRL, 0xF, 0xF, true);
  return v + b.f;
}
__device__ __forceinline__ float red16(float v){
  v = dpp_add<0xB1>(v);    // quad_perm [1,0,3,2]  (xor 1)
  v = dpp_add<0x4E>(v);    // quad_perm [2,3,0,1]  (xor 2)
  v = dpp_add<0x124>(v);   // row_ror:4
  v = dpp_add<0x128>(v);   // row_ror:8
  return v;
}

// ---------------------------------------------------------------------------
// mix = x + (x[t-1]-x[t])*time_maa_x  (x[-1]=0), stored bf16
// ---------------------------------------------------------------------------
__global__ __launch_bounds__(256) void k_prep(const float* __restrict__ x,
                                              const float* __restrict__ tmx,
                                              bf16u* __restrict__ MIX){
  int e = (blockIdx.x * 256 + threadIdx.x) * 4;
  int n = e >> 10;
  int c = e & (CC - 1);
  int t = n & (TT - 1);
  float xf[4]; ld4f(x + e, xf);
  float pf[4] = {0.f, 0.f, 0.f, 0.f};
  if (t > 0) ld4f(x + e - CC, pf);
  float tm[4]; ld4f(tmx + c, tm);
  float mv[4];
  #pragma unroll
  for (int i = 0; i < 4; ++i) mv[i] = xf[i] + (pf[i] - xf[i]) * tm[i];
  st4bf(MIX + e, mv);
}

// ---------------------------------------------------------------------------
// MFMA NT GEMM: OUT[M,Nd] = X[M,K](bf16) @ W[Nd,K]^T, W as up to 3 row-blocks
// (f32). tanh on cols < act_n. OB: bf16 out else f32. 128x128, BK=32.
// ---------------------------------------------------------------------------
template<bool OB>
__global__ __launch_bounds__(256) void k_gemm_mfma(const bf16u* __restrict__ X,
                                                   const float* __restrict__ Wa,
                                                   const float* __restrict__ Wb,
                                                   const float* __restrict__ Wc,
                                                   int na, int nab,
                                                   void* __restrict__ OUTv,
                                                   int Nd, int Kd, int act_n){
  __shared__ short As[128 * 40];
  __shared__ short Bs[128 * 40];
  const int tid  = threadIdx.x;
  const int lane = tid & 63;
  const int wv   = tid >> 6;
  const int wm   = wv >> 1, wn = wv & 1;
  const int bn0  = blockIdx.x * 128;
  const int bm0  = blockIdx.y * 128;
  const int l15  = lane & 15;
  const int quad = lane >> 4;

  f32x4 acc[4][4];
  #pragma unroll
  for (int mi = 0; mi < 4; ++mi)
    #pragma unroll
    for (int ni = 0; ni < 4; ++ni)
      #pragma unroll
      for (int rg = 0; rg < 4; ++rg) acc[mi][ni][rg] = 0.f;

  const int r    = tid >> 1;
  const int half = (tid & 1) * 16;

  int rr = bn0 + r;
  const float* wsrc = nullptr;
  if (rr < na)        wsrc = Wa + (size_t)rr * Kd;
  else if (rr < nab)  wsrc = Wb + (size_t)(rr - na) * Kd;
  else if (rr < Nd)   wsrc = Wc + (size_t)(rr - nab) * Kd;
  const bf16u* xsrc = X + (size_t)(bm0 + r) * Kd;

  for (int k0 = 0; k0 < Kd; k0 += 32){
    uint4 xa = *(const uint4*)(xsrc + k0 + half);
    uint4 xb = *(const uint4*)(xsrc + k0 + half + 8);
    uint4 w0 = make_uint4(0,0,0,0), w1 = w0, w2 = w0, w3 = w0;
    if (wsrc){
      w0 = *(const uint4*)(wsrc + k0 + half);
      w1 = *(const uint4*)(wsrc + k0 + half + 4);
      w2 = *(const uint4*)(wsrc + k0 + half + 8);
      w3 = *(const uint4*)(wsrc + k0 + half + 12);
    }
    union { unsigned short s[8]; uint4 v; } p0, p1;
    p0.s[0]=f2bfbits(w0.x); p0.s[1]=f2bfbits(w0.y); p0.s[2]=f2bfbits(w0.z); p0.s[3]=f2bfbits(w0.w);
    p0.s[4]=f2bfbits(w1.x); p0.s[5]=f2bfbits(w1.y); p0.s[6]=f2bfbits(w1.z); p0.s[7]=f2bfbits(w1.w);
    p1.s[0]=f2bfbits(w2.x); p1.s[1]=f2bfbits(w2.y); p1.s[2]=f2bfbits(w2.z); p1.s[3]=f2bfbits(w2.w);
    p1.s[4]=f2bfbits(w3.x); p1.s[5]=f2bfbits(w3.y); p1.s[6]=f2bfbits(w3.z); p1.s[7]=f2bfbits(w3.w);

    *(uint4*)&As[r * 40 + half]     = xa;
    *(uint4*)&As[r * 40 + half + 8] = xb;
    *(uint4*)&Bs[r * 40 + half]     = p0.v;
    *(uint4*)&Bs[r * 40 + half + 8] = p1.v;
    __syncthreads();

    short8 af[4], bfg[4];
    #pragma unroll
    for (int mi = 0; mi < 4; ++mi)
      af[mi] = *(const short8*)&As[(wm*64 + mi*16 + l15) * 40 + quad*8];
    #pragma unroll
    for (int ni = 0; ni < 4; ++ni)
      bfg[ni] = *(const short8*)&Bs[(wn*64 + ni*16 + l15) * 40 + quad*8];
    #pragma unroll
    for (int mi = 0; mi < 4; ++mi)
      #pragma unroll
      for (int ni = 0; ni < 4; ++ni)
        acc[mi][ni] = __builtin_amdgcn_mfma_f32_16x16x32_bf16(af[mi], bfg[ni], acc[mi][ni], 0, 0, 0);
    __syncthreads();
  }

  #pragma unroll
  for (int mi = 0; mi < 4; ++mi){
    #pragma unroll
    for (int ni = 0; ni < 4; ++ni){
      int col = bn0 + wn*64 + ni*16 + l15;
      if (col >= Nd) continue;
      #pragma unroll
      for (int rg = 0; rg < 4; ++rg){
        int row = bm0 + wm*64 + mi*16 + quad*4 + rg;
        float v = acc[mi][ni][rg];
        if (col < act_n) v = tanhf(v);
        if (OB) ((bf16u*)OUTv)[(size_t)row * Nd + col] = f2bf(v);
        else    ((float*)OUTv)[(size_t)row * Nd + col] = v;
      }
    }
  }
}

// ---------------------------------------------------------------------------
// MFMA NN GEMM: OUT[M, CC] = A[M, KD](bf16, row stride lda) @ B[KD, CC](f32).
// EP=0: plain bf16 store. EP=1: token-shift epilogue.
// ---------------------------------------------------------------------------
template<int KD, int EP>
__global__ __launch_bounds__(256) void k_gemm_nn(const bf16u* __restrict__ A, int lda,
                                                 const float* __restrict__ B,
                                                 bf16u* __restrict__ OUT,
                                                 const float* __restrict__ x,
                                                 const float* __restrict__ tma_g){
  __shared__ short As[128 * (KD + 8)];
  __shared__ short Bs[128 * (KD + 8)];
  const int tid  = threadIdx.x;
  const int lane = tid & 63;
  const int wv   = tid >> 6;
  const int wm   = wv >> 1, wn = wv & 1;
  const int bn0  = blockIdx.x * 128;
  const int bm0  = blockIdx.y * 128;
  const int l15  = lane & 15;
  const int quad = lane >> 4;

  for (int idx = tid; idx < 128 * (KD / 8); idx += 256){
    int r  = idx / (KD / 8);
    int kc = (idx % (KD / 8)) * 8;
    *(uint4*)&As[r * (KD + 8) + kc] =
        *(const uint4*)(A + (size_t)(bm0 + r) * lda + kc);
  }
  for (int idx = tid; idx < KD * 128; idx += 256){
    int k = idx >> 7, c = idx & 127;
    Bs[c * (KD + 8) + k] = (short)f2bf(B[(size_t)k * CC + bn0 + c]);
  }
  __syncthreads();

  f32x4 acc[4][4];
  #pragma unroll
  for (int mi = 0; mi < 4; ++mi)
    #pragma unroll
    for (int ni = 0; ni < 4; ++ni)
      #pragma unroll
      for (int rg = 0; rg < 4; ++rg) acc[mi][ni][rg] = 0.f;

  #pragma unroll
  for (int kk = 0; kk < KD; kk += 32){
    short8 af[4], bfg[4];
    #pragma unroll
    for (int mi = 0; mi < 4; ++mi)
      af[mi] = *(const short8*)&As[(wm*64 + mi*16 + l15) * (KD + 8) + kk + quad*8];
    #pragma unroll
    for (int ni = 0; ni < 4; ++ni)
      bfg[ni] = *(const short8*)&Bs[(wn*64 + ni*16 + l15) * (KD + 8) + kk + quad*8];
    #pragma unroll
    for (int mi = 0; mi < 4; ++mi)
      #pragma unroll
      for (int ni = 0; ni < 4; ++ni)
        acc[mi][ni] = __builtin_amdgcn_mfma_f32_16x16x32_bf16(af[mi], bfg[ni], acc[mi][ni], 0, 0, 0);
  }

  #pragma unroll
  for (int mi = 0; mi < 4; ++mi){
    #pragma unroll
    for (int ni = 0; ni < 4; ++ni){
      int col = bn0 + wn*64 + ni*16 + l15;
      float tm = (EP == 1) ? tma_g[col] : 0.f;
      #pragma unroll
      for (int rg = 0; rg < 4; ++rg){
        int row = bm0 + wm*64 + mi*16 + quad*4 + rg;
        float v = acc[mi][ni][rg];
        if (EP == 1){
          float xv = x[(size_t)row * CC + col];
          float xp = ((row & (TT - 1)) == 0) ? 0.f : x[(size_t)row * CC + col - CC];
          v = xv + (xp - xv) * (v + tm);
        }
        OUT[(size_t)row * CC + col] = f2bf(v);
      }
    }
  }
}

// ---------------------------------------------------------------------------
// Fused elementwise + pair precompute, 4 tokens (2 pairs) per block.
// WMODE=1: decay factor w_t = exp(-exp(w)) stored as exact f32 in WF
//          (removes 8 cvt + 8 exp per pair from k_rec's issue stream).
// WMODE=0: legacy f16 -u in UX (self-normalizing; r4/r6-validated fallback
//          when workspace is too small for WF).
// Pair precompute (linearity vs base S): u1 -> KKN odd, q' -> R in place,
// scalars -> Dsc; rk -> RKsc (k_post no longer reads R/KF/faaaa).
// ---------------------------------------------------------------------------
template<int WMODE>
__global__ __launch_bounds__(256) void k_elem(bf16u* __restrict__ K0,
    const bf16u* __restrict__ P1, const bf16u* __restrict__ P2,
    const bf16u* __restrict__ W2A,
    const float* __restrict__ kw2, const float* __restrict__ aw2,
    const float* __restrict__ maw2, const float* __restrict__ mkw2,
    const float* __restrict__ td,  const float* __restrict__ taa,
    const float* __restrict__ tma, const float* __restrict__ tmk,
    const float* __restrict__ faaaa,
    bf16u* __restrict__ KKN, bf16u* __restrict__ Bb, bf16u* __restrict__ UX,
    float* __restrict__ WF,
    bf16u* __restrict__ Rq, float* __restrict__ Dsc, float* __restrict__ RKsc){
  int n0 = blockIdx.x * 4, tid = threadIdx.x;
  __shared__ float at_l[4][16], mat_l[4][16], kt_l[4][16], mkt_l[4][16];
  {
    int grp = tid >> 6, q = tid & 63, tt = q >> 4, j = q & 15;
    if (grp == 0)      at_l[tt][j]  = bf2f(P1[(size_t)(n0+tt)*96 + 64 + j]);
    else if (grp == 1) mat_l[tt][j] = bf2f(P1[(size_t)(n0+tt)*96 + 80 + j]);
    else if (grp == 2) kt_l[tt][j]  = bf2f(P2[(size_t)(n0+tt)*32 + j]);
    else               mkt_l[tt][j] = bf2f(P2[(size_t)(n0+tt)*32 + 16 + j]);
  }
  __syncthreads();
  int c  = tid * 4;
  int h  = tid >> 4;       // head (16 lanes per head)
  int lg = tid & 15;

  float kkk[4][4], aa[4][4], mam[4][4], mkm[4][4];
  #pragma unroll
  for (int tt = 0; tt < 4; ++tt)
    #pragma unroll
    for (int i = 0; i < 4; ++i){ kkk[tt][i]=0; aa[tt][i]=0; mam[tt][i]=0; mkm[tt][i]=0; }

  #pragma unroll 4
  for (int j = 0; j < 16; ++j){
    float wk[4], wa[4], wm[4], wq[4];
    ld4f(kw2  + (size_t)j*CC + c, wk);
    ld4f(aw2  + (size_t)j*CC + c, wa);
    ld4f(maw2 + (size_t)j*CC + c, wm);
    ld4f(mkw2 + (size_t)j*CC + c, wq);
    #pragma unroll
    for (int tt = 0; tt < 4; ++tt){
      float s1 = kt_l[tt][j], s2 = at_l[tt][j], s3 = mat_l[tt][j], s4 = mkt_l[tt][j];
      #pragma unroll
      for (int i = 0; i < 4; ++i){
        kkk[tt][i] += s1 * wk[i];
        aa[tt][i]  += s2 * wa[i];
        mam[tt][i] += s3 * wm[i];
        mkm[tt][i] += s4 * wq[i];
      }
    }
  }

  float td4[4], taa4[4], tma4[4], tmk4[4], fa4[4];
  ld4f(td + c, td4); ld4f(taa + c, taa4); ld4f(tma + c, tma4); ld4f(tmk + c, tmk4);
  ld4f(faaaa + c, fa4);

#define ELEM_TOKEN(TT_, E_, A_, B_, KF_, WD_) do{ \
    float k0a[4]; ld4bf(K0 + (E_), k0a); \
    float w2a[4]; ld4bf(W2A + (E_), w2a); \
    float ssq = 0.f; \
    _Pragma("unroll") \
    for (int i = 0; i < 4; ++i){ A_[i] = k0a[i] + kkk[TT_][i]; ssq += A_[i]*A_[i]; } \
    ssq = red16(ssq); \
    float rinv = 1.f / fmaxf(sqrtf(ssq), 1e-12f); \
    float outw_[4]; \
    _Pragma("unroll") \
    for (int i = 0; i < 4; ++i){ \
      float z  = td4[i] + w2a[i]; \
      float nz = -z; \
      float sp = (nz > 15.f) ? nz : log1pf(expf(nz)); \
      float w  = -sp - 0.5f; \
      float av  = sigm(taa4[i] + aa[TT_][i]); \
      float mav = sigm(tma4[i] + mam[TT_][i]); \
      float mkv = sigm(tmk4[i] + mkm[TT_][i]); \
      A_[i] *= rinv; \
      B_[i]  = -A_[i] * av; \
      KF_[i] = k0a[i] * (mav + av * (1.f - mav)) * expf(w * mkv); \
      float ou = -expf(w); \
      outw_[i] = ou; \
      if (WMODE == 1) WD_[i] = __expf(ou);              /* exact f32 w_t */ \
      else            WD_[i] = __expf(hval(f2h(ou)));   /* f16-consistent */ \
    } \
    st4bf(Bb + (E_), B_); \
    st4bf(K0 + (E_), KF_); \
    if (WMODE == 1) *(float4*)(WF + (E_)) = make_float4(WD_[0], WD_[1], WD_[2], WD_[3]); \
    else            st4h(UX + (E_), outw_); \
  }while(0)

  #pragma unroll
  for (int p = 0; p < 2; ++p){
    const int ttE = 2*p, ttO = ttE + 1;
    size_t eE = (size_t)(n0 + ttE) * CC + c;
    size_t eO = eE + CC;
    float aE[4], bE[4], kfE[4], wdE[4];
    float aO[4], bO[4], kfO[4], wdO[4];
    ELEM_TOKEN(ttE, eE, aE, bE, kfE, wdE);
    ELEM_TOKEN(ttO, eO, aO, bO, kfO, wdO);
    st4bf(KKN + eE, aE);

    float rE[4], rO[4];
    ld4bf(Rq + eE, rE); ld4bf(Rq + eO, rO);

    // rk for k_post (before R is overwritten)
    float rkE = red16(rE[0]*kfE[0]*fa4[0] + rE[1]*kfE[1]*fa4[1]
                    + rE[2]*kfE[2]*fa4[2] + rE[3]*kfE[3]*fa4[3]);
    float rkO = red16(rO[0]*kfO[0]*fa4[0] + rO[1]*kfO[1]*fa4[1]
                    + rO[2]*kfO[2]*fa4[2] + rO[3]*kfO[3]*fa4[3]);

    // u1 over KKN odd row
    float c1 = red16(dot4(bE, aO));
    float d  = red16(dot4(kfE, aO));
    float u1[4];
    #pragma unroll
    for (int i = 0; i < 4; ++i) u1[i] = wdE[i]*aO[i] + c1*aE[i];
    st4bf(KKN + eO, u1);

    // q' even
    float cq = red16(dot4(bE, rE));
    float e1 = red16(dot4(kfE, rE));
    float qe[4];
    #pragma unroll
    for (int i = 0; i < 4; ++i) qe[i] = wdE[i]*rE[i] + cq*aE[i];
    st4bf(Rq + eE, qe);

    // z = M_{t+1} q_{t+1}; q' odd = M_t z
    float cz  = red16(dot4(bO, rO));
    float e21 = red16(dot4(kfO, rO));
    float z[4];
    #pragma unroll
    for (int i = 0; i < 4; ++i) z[i] = wdO[i]*rO[i] + cz*aO[i];
    float cy  = red16(dot4(bE, z));
    float e20 = red16(dot4(kfE, z));
    float qo[4];
    #pragma unroll
    for (int i = 0; i < 4; ++i) qo[i] = wdE[i]*z[i] + cy*aE[i];
    st4bf(Rq + eO, qo);

    if (lg == 0){
      size_t pr = (size_t)((n0 + ttE) >> 1);
      float4 dv; dv.x = d; dv.y = e1; dv.z = e20; dv.w = e21;
      *(float4*)(Dsc + (pr * HH + h) * 4) = dv;
      RKsc[(size_t)(n0 + ttE) * HH + h] = rkE;
      RKsc[(size_t)(n0 + ttO) * HH + h] = rkO;
    }
  }
#undef ELEM_TOKEN
}

// ---------------------------------------------------------------------------
// Recurrence v12: v11 structure (all 4 reductions vs base S) + two issue
// trims: (1) WMODE=1 loads w_t as f32 float4 -> no cvt/exp on the hot path
// (~80 issue-cyc/pair saved; transcendentals are quarter-rate); (2) red16
// now folds to single v_add_f32_dpp per stage (-16 instr/pair).
// ---------------------------------------------------------------------------
template<int WMODE>
__global__ __launch_bounds__(256) void k_rec(const bf16u* __restrict__ Qp,
                                             const bf16u* __restrict__ WT,
                                             const float* __restrict__ WF,
                                             const bf16u* __restrict__ KFt,
                                             const bf16u* __restrict__ Vt,
                                             const bf16u* __restrict__ Aa,
                                             const bf16u* __restrict__ Bv,
                                             const float* __restrict__ Dsc,
                                             bf16u* __restrict__ Y){
  const int p  = blockIdx.x;                 // 0..255
  const int g  = (p & 7) | ((p >> 5) << 3);  // (b,h) group 0..63, XCD-clustered
  const int rg = (p >> 3) & 3;               // row quartet within the head
  const int b  = g >> 4;
  const int h  = g & 15;
  const int tid = threadIdx.x;
  const int cg  = tid & 15;                  // 16 lanes per row
  const int i   = rg * 16 + (tid >> 4);      // state row 0..63
  const size_t base0 = (size_t)(b * TT) * CC + h * HSS;
  const size_t colb  = base0 + cg * 4;
  const size_t rowb  = base0 + i;
  const size_t dscb  = ((size_t)(b * (TT/2)) * HH + h) * 4;

  float S0 = 0.f, S1 = 0.f, S2 = 0.f, S3 = 0.f;

  uint2 qEA,qOA,aEA,uOA,kEA,kOA,bEA,bOA,wEA,wOA; float4 fEA,fOA; unsigned short vEA,vOA; float4 dA;
  uint2 qEB,qOB,aEB,uOB,kEB,kOB,bEB,bOB,wEB,wOB; float4 fEB,fOB; unsigned short vEB,vOB; float4 dB;
  uint2 qEC,qOC,aEC,uOC,kEC,kOC,bEC,bOC,wEC,wOC; float4 fEC,fOC; unsigned short vEC,vOC; float4 dC;
  uint2 qED,qOD,aED,uOD,kED,kOD,bED,bOD,wED,wOD; float4 fED,fOD; unsigned short vED,vOD; float4 dD;

#define PL(S, T_) do{ \
    size_t cE_ = colb + (size_t)(T_) * CC, cO_ = cE_ + CC; \
    qE##S = *(const uint2*)(Qp  + cE_); qO##S = *(const uint2*)(Qp  + cO_); \
    aE##S = *(const uint2*)(Aa  + cE_); uO##S = *(const uint2*)(Aa  + cO_); \
    kE##S = *(const uint2*)(KFt + cE_); kO##S = *(const uint2*)(KFt + cO_); \
    bE##S = *(const uint2*)(Bv  + cE_); bO##S = *(const uint2*)(Bv  + cO_); \
    if (WMODE == 1){ \
      fE##S = *(const float4*)(WF + cE_); fO##S = *(const float4*)(WF + cO_); \
    } else { \
      wE##S = *(const uint2*)(WT + cE_);  wO##S = *(const uint2*)(WT + cO_); \
    } \
    vE##S = Vt[rowb + (size_t)(T_) * CC]; \
    vO##S = Vt[rowb + (size_t)(T_ + 1) * CC]; \
    d##S  = *(const float4*)(Dsc + dscb + (size_t)((T_) >> 1) * (HH*4)); \
  }while(0)

#define PSTEP(S, T_) do{ \
    float a0=bflo(aE##S.x), a1=bfhi(aE##S.x), a2=bflo(aE##S.y), a3=bfhi(aE##S.y); \
    float u0=bflo(uO##S.x), u1=bfhi(uO##S.x), u2=bflo(uO##S.y), u3=bfhi(uO##S.y); \
    float g0=bflo(qE##S.x), g1=bfhi(qE##S.x), g2=bflo(qE##S.y), g3=bfhi(qE##S.y); \
    float o0=bflo(qO##S.x), o1=bfhi(qO##S.x), o2=bflo(qO##S.y), o3=bfhi(qO##S.y); \
    float pE_ = (S0*a0 + S1*a1) + (S2*a2 + S3*a3); \
    float pO_ = (S0*u0 + S1*u1) + (S2*u2 + S3*u3); \
    float yE_ = (S0*g0 + S1*g1) + (S2*g2 + S3*g3); \
    float yO_ = (S0*o0 + S1*o1) + (S2*o2 + S3*o3); \
    pE_ = red16(pE_); \
    pO_ = red16(pO_); \
    yE_ = red16(yE_); \
    yO_ = red16(yO_); \
    float vEf = bf2f(vE##S), vOf = bf2f(vO##S); \
    float saE = pE_; \
    float saO = fmaf(d##S.x, vEf, pO_); \
    float ypE = fmaf(d##S.y, vEf, yE_); \
    float ypO = fmaf(d##S.z, vEf, fmaf(d##S.w, vOf, yO_)); \
    float k0=bflo(kE##S.x), k1=bfhi(kE##S.x), k2=bflo(kE##S.y), k3=bfhi(kE##S.y); \
    float b0=bflo(bE##S.x), b1=bfhi(bE##S.x), b2=bflo(bE##S.y), b3=bfhi(bE##S.y); \
    float w0, w1, w2, w3; \
    if (WMODE == 1){ w0=fE##S.x; w1=fE##S.y; w2=fE##S.z; w3=fE##S.w; } \
    else { w0=__expf(hlo(wE##S.x)); w1=__expf(hhi(wE##S.x)); \
           w2=__expf(hlo(wE##S.y)); w3=__expf(hhi(wE##S.y)); } \
    S0 = fmaf(S0, w0, fmaf(saE, b0, vEf * k0)); \
    S1 = fmaf(S1, w1, fmaf(saE, b1, vEf * k1)); \
    S2 = fmaf(S2, w2, fmaf(saE, b2, vEf * k2)); \
    S3 = fmaf(S3, w3, fmaf(saE, b3, vEf * k3)); \
    float ko0=bflo(kO##S.x), ko1=bfhi(kO##S.x), ko2=bflo(kO##S.y), ko3=bfhi(kO##S.y); \
    float bo0=bflo(bO##S.x), bo1=bfhi(bO##S.x), bo2=bflo(bO##S.y), bo3=bfhi(bO##S.y); \
    float wo0, wo1, wo2, wo3; \
    if (WMODE == 1){ wo0=fO##S.x; wo1=fO##S.y; wo2=fO##S.z; wo3=fO##S.w; } \
    else { wo0=__expf(hlo(wO##S.x)); wo1=__expf(hhi(wO##S.x)); \
           wo2=__expf(hlo(wO##S.y)); wo3=__expf(hhi(wO##S.y)); } \
    S0 = fmaf(S0, wo0, fmaf(saO, bo0, vOf * ko0)); \
    S1 = fmaf(S1, wo1, fmaf(saO, bo1, vOf * ko1)); \
    S2 = fmaf(S2, wo2, fmaf(saO, bo2, vOf * ko2)); \
    S3 = fmaf(S3, wo3, fmaf(saO, bo3, vOf * ko3)); \
    if (cg == 0){ \
      Y[rowb + (size_t)(T_) * CC]     = f2bf(ypE); \
      Y[rowb + (size_t)(T_ + 1) * CC] = f2bf(ypO); \
    } \
  }while(0)

  PL(A, 0); PL(B, 2); PL(C, 4); PL(D, 6);
  for (int t = 0; t < TT; t += 8){
    PSTEP(A, t);
    if (t + 8  < TT) PL(A, t + 8);
    PSTEP(B, t + 2);
    if (t + 10 < TT) PL(B, t + 10);
    PSTEP(C, t + 4);
    if (t + 12 < TT) PL(C, t + 12);
    PSTEP(D, t + 6);
    if (t + 14 < TT) PL(D, t + 14);
  }
#undef PL
#undef PSTEP
}

// ---------------------------------------------------------------------------
// Post: GroupNorm + precomputed bonus rk*v + precomputed gate GV -> YG (bf16)
// ---------------------------------------------------------------------------
__global__ __launch_bounds__(256) void k_post(const bf16u* __restrict__ Y,
                                              const bf16u* __restrict__ Vt,
                                              const bf16u* __restrict__ GV,
                                              const float* __restrict__ lnw,
                                              const float* __restrict__ lnb,
                                              const float* __restrict__ RKsc,
                                              bf16u* __restrict__ YG){
  int n = blockIdx.x, tid = threadIdx.x;
  int c = tid * 4;
  size_t e = (size_t)n * CC + c;

  float ya[4]; ld4bf(Y + e, ya);
  float s = ya[0] + ya[1] + ya[2] + ya[3];
  s = red16(s);
  float mu = s * (1.f / 64.f);
  float d[4], vs = 0.f;
  #pragma unroll
  for (int i = 0; i < 4; ++i){ d[i] = ya[i] - mu; vs += d[i] * d[i]; }
  vs = red16(vs);
  float rstd = rsqrtf(vs * (1.f / 64.f) + EPSGN);

  float rk = RKsc[(size_t)n * HH + (tid >> 4)];

  float va[4]; ld4bf(Vt + e, va);
  float lw4[4], lb4[4];
  ld4f(lnw + c, lw4); ld4f(lnb + c, lb4);
  float g[4]; ld4bf(GV + e, g);
  float o[4];
  #pragma unroll
  for (int i = 0; i < 4; ++i){
    float yn = d[i] * rstd * lw4[i] + lb4[i] + rk * va[i];
    o[i] = yn * g[i];
  }
  st4bf(YG + e, o);
}

// ---------------------------------------------------------------------------
extern "C" void kernel_launch(void* const* d_in, const int* in_sizes, int n_in,
                              void* d_out, int out_size, void* d_ws, size_t ws_size,
                              hipStream_t stream){
  (void)in_sizes; (void)n_in; (void)out_size;
  const float* x        = (const float*)d_in[0];
  const float* tmx      = (const float*)d_in[1];
  const float* tmaa     = (const float*)d_in[2];
  const float* maa_w1   = (const float*)d_in[3];
  const float* maa_w2   = (const float*)d_in[4];
  const float* decay_w1 = (const float*)d_in[5];
  const float* decay_w2 = (const float*)d_in[6];
  const float* aaa_w1   = (const float*)d_in[7];
  const float* aaa_w2   = (const float*)d_in[8];
  const float* kkk_w1   = (const float*)d_in[9];
  const float* kkk_w2   = (const float*)d_in[10];
  const float* gate_w1  = (const float*)d_in[11];
  const float* gate_w2  = (const float*)d_in[12];
  const float* ma_w1    = (const float*)d_in[13];
  const float* ma_w2    = (const float*)d_in[14];
  const float* mk_w1    = (const float*)d_in[15];
  const float* mk_w2    = (const float*)d_in[16];
  const float* t_decay  = (const float*)d_in[17];
  const float* t_faaaa  = (const float*)d_in[18];
  const float* t_aaaaa  = (const float*)d_in[19];
  const float* t_misc_a = (const float*)d_in[20];
  const float* t_misc_k = (const float*)d_in[21];
  const float* Wr       = (const float*)d_in[22];
  const float* Wk       = (const float*)d_in[23];
  const float* Wv       = (const float*)d_in[24];
  const float* Wo       = (const float*)d_in[25];
  const float* ln_w     = (const float*)d_in[26];
  const float* ln_b     = (const float*)d_in[27];

  // Slot map (8MiB bf16 each), 56 MiB slots + smalls at 56..60 MiB.
  // Fast path adds WF (f32 w_t, 16 MiB) at 60..76 MiB (needs ws >= 77 MiB;
  // falls back to r6's f16 UX path otherwise).
  bf16u* bw  = (bf16u*)d_ws;
  bf16u* MIX = bw + 0*SLOT;
  bf16u* X0  = bw + 0*SLOT;
  bf16u* KKN = bw + 0*SLOT;
  bf16u* YG  = bw + 0*SLOT;
  bf16u* X1  = bw + 1*SLOT;
  bf16u* Bb  = bw + 1*SLOT;
  bf16u* GV  = bw + 1*SLOT;
  bf16u* X2  = bw + 2*SLOT;
  bf16u* UX  = bw + 2*SLOT;
  bf16u* X3  = bw + 3*SLOT;
  bf16u* W2A = bw + 3*SLOT;
  bf16u* Yb  = bw + 3*SLOT;
  bf16u* R   = bw + 4*SLOT;   // becomes q'
  bf16u* K0  = bw + 5*SLOT;   // becomes KF
  bf16u* V   = bw + 6*SLOT;
  char*  wsb = (char*)d_ws;
  bf16u* LO  = (bf16u*)(wsb + (56ull<<20));   // [N,128] bf16, 1 MiB
  bf16u* GT  = (bf16u*)(wsb + (57ull<<20));   // [N,128] bf16, 1 MiB
  bf16u* P1  = (bf16u*)(wsb + (58ull<<20));   // [N,96]  bf16 (dt|at|ma)
  bf16u* P2  = (bf16u*)(wsb + (58ull<<20) + (768ull<<10)); // [N,32] bf16
  float* Dsc = (float*)(wsb + (59ull<<20));   // [N/2,16] float4, 512 KiB
  float* RKsc= (float*)(wsb + (59ull<<20) + (512ull<<10)); // [N,16] f32, 256 KiB
  float* WF  = (float*)(wsb + (60ull<<20));   // [N,CC] f32 w_t, 16 MiB
  const bool wf32 = ws_size >= (77ull<<20);

  // 1. mix
  k_prep<<<4096, 256, 0, stream>>>(x, tmx, MIX);
  // 2. lo = tanh(mix @ maa_w1^T) [N,128] bf16
  k_gemm_mfma<true><<<dim3(1,32),256,0,stream>>>(MIX, maa_w1, maa_w1, maa_w1,
                                                 128, 128, LO, 128, CC, 128);
  // 3. xm[g] = x + xx*(lo_g @ maa_w2_g + tmaa_g)   (NN GEMM + fused epilogue)
  bf16u* XMs[4] = {X0, X1, X2, X3};
  for (int g = 0; g < 4; ++g)
    k_gemm_nn<32,1><<<dim3(8,32),256,0,stream>>>(LO + g*32, 128,
                                                 maa_w2 + (size_t)g*32*CC,
                                                 XMs[g], x, tmaa + (size_t)g*CC);
  // 4. big projections (bf16 out)
  k_gemm_mfma<true><<<dim3(8,32),256,0,stream>>>(X0, Wr, Wr, Wr, CC, CC, R,  CC, CC, 0);
  k_gemm_mfma<true><<<dim3(8,32),256,0,stream>>>(X2, Wk, Wk, Wk, CC, CC, K0, CC, CC, 0);
  k_gemm_mfma<true><<<dim3(8,32),256,0,stream>>>(X3, Wv, Wv, Wv, CC, CC, V,  CC, CC, 0);
  // 5. first-stage LoRA projections (bf16 out)
  k_gemm_mfma<true><<<dim3(1,32),256,0,stream>>>(X0, gate_w1, gate_w1, gate_w1,
                                                 128, 128, GT, 128, CC, 128);
  k_gemm_mfma<true><<<dim3(1,32),256,0,stream>>>(X1, decay_w1, aaa_w1, ma_w1,
                                                 64, 80, P1, 96, CC, 64);
  k_gemm_mfma<true><<<dim3(1,32),256,0,stream>>>(X2, kkk_w1, mk_w1, mk_w1,
                                                 16, 32, P2, 32, CC, 16);
  // 6. decay second-stage projection: W2A = P1[:, :64] @ decay_w2  -> S3
  k_gemm_nn<64,0><<<dim3(8,32),256,0,stream>>>(P1, 96, decay_w2, W2A, nullptr, nullptr);
  // 7. fused elementwise + pair precompute (u1, q', scalars, rk)
  if (wf32)
    k_elem<1><<<1024, 256, 0, stream>>>(K0, P1, P2, W2A,
                                        kkk_w2, aaa_w2, ma_w2, mk_w2,
                                        t_decay, t_aaaaa, t_misc_a, t_misc_k, t_faaaa,
                                        KKN, Bb, UX, WF, R, Dsc, RKsc);
  else
    k_elem<0><<<1024, 256, 0, stream>>>(K0, P1, P2, W2A,
                                        kkk_w2, aaa_w2, ma_w2, mk_w2,
                                        t_decay, t_aaaaa, t_misc_a, t_misc_k, t_faaaa,
                                        KKN, Bb, UX, WF, R, Dsc, RKsc);
  // 8. delta-rule recurrence (v12: f32 decay + folded DPP reductions)
  if (wf32)
    k_rec<1><<<256, 256, 0, stream>>>(R, UX, WF, K0, V, KKN, Bb, Dsc, Yb);
  else
    k_rec<0><<<256, 256, 0, stream>>>(R, UX, WF, K0, V, KKN, Bb, Dsc, Yb);
  // 9. gate second-stage: GV = GT @ gate_w2 -> S1 (Bb dead after k_rec)
  k_gemm_nn<128,0><<<dim3(8,32),256,0,stream>>>(GT, 128, gate_w2, GV, nullptr, nullptr);
  // 10. groupnorm + bonus + gate
  k_post<<<4096, 256, 0, stream>>>(Yb, V, GV, ln_w, ln_b, RKsc, YG);
  // 11. out = yg @ Wo^T -> f32
  k_gemm_mfma<false><<<dim3(8,32),256,0,stream>>>(YG, Wo, Wo, Wo, CC, CC, d_out, CC, CC, 0);
}

// Round 8
// 809.098 us; speedup vs baseline: 1.2127x; 1.0502x over previous
//
#include <hip/hip_runtime.h>
#include <cstdint>
#include <cstddef>

// Problem constants
#define BB   4
#define TT   1024
#define CC   1024
#define HH   16
#define HSS  64
#define NNtok 4096            // B*T
#define EPSGN 0.00064f

typedef unsigned short bf16u;
typedef __attribute__((ext_vector_type(8))) short short8;
typedef __attribute__((ext_vector_type(4))) float f32x4;
#define SLOT 4194304ull       // elements per 8MiB bf16 slot (= NNtok*CC)

__device__ __forceinline__ float bf2f(bf16u u){
  union { unsigned int i; float f; } cv; cv.i = ((unsigned int)u) << 16; return cv.f;
}
__device__ __forceinline__ unsigned short f2bfbits(unsigned int x){
  return (unsigned short)((x + 0x7fffu + ((x >> 16) & 1u)) >> 16);   // RNE
}
__device__ __forceinline__ bf16u f2bf(float f){
  union { float f; unsigned int i; } cv; cv.f = f;
  return f2bfbits(cv.i);
}
__device__ __forceinline__ void ld4bf(const bf16u* p, float* o){
  ushort4 u = *reinterpret_cast<const ushort4*>(p);
  o[0]=bf2f(u.x); o[1]=bf2f(u.y); o[2]=bf2f(u.z); o[3]=bf2f(u.w);
}
__device__ __forceinline__ void st4bf(bf16u* p, const float* v){
  ushort4 u; u.x=f2bf(v[0]); u.y=f2bf(v[1]); u.z=f2bf(v[2]); u.w=f2bf(v[3]);
  *reinterpret_cast<ushort4*>(p) = u;
}
__device__ __forceinline__ unsigned short f2h(float f){
  union { _Float16 h; unsigned short s; } c; c.h = (_Float16)f; return c.s;
}
__device__ __forceinline__ void st4h(bf16u* p, const float* v){
  ushort4 u; u.x=f2h(v[0]); u.y=f2h(v[1]); u.z=f2h(v[2]); u.w=f2h(v[3]);
  *reinterpret_cast<ushort4*>(p) = u;
}
__device__ __forceinline__ void ld4f(const float* p, float* o){
  float4 v = *reinterpret_cast<const float4*>(p);
  o[0]=v.x; o[1]=v.y; o[2]=v.z; o[3]=v.w;
}
__device__ __forceinline__ float sigm(float x){ return 1.f / (1.f + expf(-x)); }

// unpack helpers
__device__ __forceinline__ float bflo(unsigned int u){
  union { unsigned int i; float f; } c; c.i = u << 16; return c.f;
}
__device__ __forceinline__ float bfhi(unsigned int u){
  union { unsigned int i; float f; } c; c.i = u & 0xffff0000u; return c.f;
}
__device__ __forceinline__ float hlo(unsigned int u){
  union { unsigned short s; _Float16 h; } c; c.s = (unsigned short)(u & 0xffffu); return (float)c.h;
}
__device__ __forceinline__ float hhi(unsigned int u){
  union { unsigned short s; _Float16 h; } c; c.s = (unsigned short)(u >> 16); return (float)c.h;
}
__device__ __forceinline__ float hval(unsigned short s){
  union { unsigned short s; _Float16 h; } c; c.s = s; return (float)c.h;
}
__device__ __forceinline__ float dot4(const float* x, const float* y){
  return (x[0]*y[0] + x[1]*y[1]) + (x[2]*y[2] + x[3]*y[3]);
}

// 16-lane sum via DPP. old=0 + bound_ctrl=1 folds to single v_add_f32_dpp.
template<int CTRL>
__device__ __forceinline__ float dpp_add(float v){
  union { float f; int i; } a, b;
  a.f = v;
  b.i = __builtin_amdgcn_update_dpp(0, a.i, CTRL, 0xF, 0xF, true);
  return v + b.f;
}
__device__ __forceinline__ float red16(float v){
  v = dpp_add<0xB1>(v);    // quad_perm [1,0,3,2]  (xor 1)
  v = dpp_add<0x4E>(v);    // quad_perm [2,3,0,1]  (xor 2)
  v = dpp_add<0x124>(v);   // row_ror:4
  v = dpp_add<0x128>(v);   // row_ror:8
  return v;
}
// 32-lane sum in all lanes: red16 then exchange complementary 16-rows
// between two DISTINCT-register copies (laundered; rounds 1/3 failed when
// regalloc coalesced both operands into one phys reg -> self-swap).
// Validated in r4-r7 context (red16) and r4 (full red32).
__device__ __forceinline__ float red32(float v){
  v = red16(v);
  union { float f; int i; } x, y;
  x.f = v; y.f = v;
  asm volatile("" : "+v"(y.i));   // distinct-vreg launder
  asm volatile("v_permlane16_swap_b32 %0, %1" : "+v"(x.i), "+v"(y.i));
  return x.f + y.f;
}

// ---------------------------------------------------------------------------
// mix = x + (x[t-1]-x[t])*time_maa_x  (x[-1]=0), stored bf16
// ---------------------------------------------------------------------------
__global__ __launch_bounds__(256) void k_prep(const float* __restrict__ x,
                                              const float* __restrict__ tmx,
                                              bf16u* __restrict__ MIX){
  int e = (blockIdx.x * 256 + threadIdx.x) * 4;
  int n = e >> 10;
  int c = e & (CC - 1);
  int t = n & (TT - 1);
  float xf[4]; ld4f(x + e, xf);
  float pf[4] = {0.f, 0.f, 0.f, 0.f};
  if (t > 0) ld4f(x + e - CC, pf);
  float tm[4]; ld4f(tmx + c, tm);
  float mv[4];
  #pragma unroll
  for (int i = 0; i < 4; ++i) mv[i] = xf[i] + (pf[i] - xf[i]) * tm[i];
  st4bf(MIX + e, mv);
}

// ---------------------------------------------------------------------------
// MFMA NT GEMM: OUT[M,Nd] = X[M,K](bf16) @ W[Nd,K]^T, W as up to 3 row-blocks
// (f32). tanh on cols < act_n. OB: bf16 out else f32. 128x128, BK=32.
// ---------------------------------------------------------------------------
template<bool OB>
__global__ __launch_bounds__(256) void k_gemm_mfma(const bf16u* __restrict__ X,
                                                   const float* __restrict__ Wa,
                                                   const float* __restrict__ Wb,
                                                   const float* __restrict__ Wc,
                                                   int na, int nab,
                                                   void* __restrict__ OUTv,
                                                   int Nd, int Kd, int act_n){
  __shared__ short As[128 * 40];
  __shared__ short Bs[128 * 40];
  const int tid  = threadIdx.x;
  const int lane = tid & 63;
  const int wv   = tid >> 6;
  const int wm   = wv >> 1, wn = wv & 1;
  const int bn0  = blockIdx.x * 128;
  const int bm0  = blockIdx.y * 128;
  const int l15  = lane & 15;
  const int quad = lane >> 4;

  f32x4 acc[4][4];
  #pragma unroll
  for (int mi = 0; mi < 4; ++mi)
    #pragma unroll
    for (int ni = 0; ni < 4; ++ni)
      #pragma unroll
      for (int rg = 0; rg < 4; ++rg) acc[mi][ni][rg] = 0.f;

  const int r    = tid >> 1;
  const int half = (tid & 1) * 16;

  int rr = bn0 + r;
  const float* wsrc = nullptr;
  if (rr < na)        wsrc = Wa + (size_t)rr * Kd;
  else if (rr < nab)  wsrc = Wb + (size_t)(rr - na) * Kd;
  else if (rr < Nd)   wsrc = Wc + (size_t)(rr - nab) * Kd;
  const bf16u* xsrc = X + (size_t)(bm0 + r) * Kd;

  for (int k0 = 0; k0 < Kd; k0 += 32){
    uint4 xa = *(const uint4*)(xsrc + k0 + half);
    uint4 xb = *(const uint4*)(xsrc + k0 + half + 8);
    uint4 w0 = make_uint4(0,0,0,0), w1 = w0, w2 = w0, w3 = w0;
    if (wsrc){
      w0 = *(const uint4*)(wsrc + k0 + half);
      w1 = *(const uint4*)(wsrc + k0 + half + 4);
      w2 = *(const uint4*)(wsrc + k0 + half + 8);
      w3 = *(const uint4*)(wsrc + k0 + half + 12);
    }
    union { unsigned short s[8]; uint4 v; } p0, p1;
    p0.s[0]=f2bfbits(w0.x); p0.s[1]=f2bfbits(w0.y); p0.s[2]=f2bfbits(w0.z); p0.s[3]=f2bfbits(w0.w);
    p0.s[4]=f2bfbits(w1.x); p0.s[5]=f2bfbits(w1.y); p0.s[6]=f2bfbits(w1.z); p0.s[7]=f2bfbits(w1.w);
    p1.s[0]=f2bfbits(w2.x); p1.s[1]=f2bfbits(w2.y); p1.s[2]=f2bfbits(w2.z); p1.s[3]=f2bfbits(w2.w);
    p1.s[4]=f2bfbits(w3.x); p1.s[5]=f2bfbits(w3.y); p1.s[6]=f2bfbits(w3.z); p1.s[7]=f2bfbits(w3.w);

    *(uint4*)&As[r * 40 + half]     = xa;
    *(uint4*)&As[r * 40 + half + 8] = xb;
    *(uint4*)&Bs[r * 40 + half]     = p0.v;
    *(uint4*)&Bs[r * 40 + half + 8] = p1.v;
    __syncthreads();

    short8 af[4], bfg[4];
    #pragma unroll
    for (int mi = 0; mi < 4; ++mi)
      af[mi] = *(const short8*)&As[(wm*64 + mi*16 + l15) * 40 + quad*8];
    #pragma unroll
    for (int ni = 0; ni < 4; ++ni)
      bfg[ni] = *(const short8*)&Bs[(wn*64 + ni*16 + l15) * 40 + quad*8];
    #pragma unroll
    for (int mi = 0; mi < 4; ++mi)
      #pragma unroll
      for (int ni = 0; ni < 4; ++ni)
        acc[mi][ni] = __builtin_amdgcn_mfma_f32_16x16x32_bf16(af[mi], bfg[ni], acc[mi][ni], 0, 0, 0);
    __syncthreads();
  }

  #pragma unroll
  for (int mi = 0; mi < 4; ++mi){
    #pragma unroll
    for (int ni = 0; ni < 4; ++ni){
      int col = bn0 + wn*64 + ni*16 + l15;
      if (col >= Nd) continue;
      #pragma unroll
      for (int rg = 0; rg < 4; ++rg){
        int row = bm0 + wm*64 + mi*16 + quad*4 + rg;
        float v = acc[mi][ni][rg];
        if (col < act_n) v = tanhf(v);
        if (OB) ((bf16u*)OUTv)[(size_t)row * Nd + col] = f2bf(v);
        else    ((float*)OUTv)[(size_t)row * Nd + col] = v;
      }
    }
  }
}

// ---------------------------------------------------------------------------
// MFMA NN GEMM: OUT[M, CC] = A[M, KD](bf16, row stride lda) @ B[KD, CC](f32).
// EP=0: plain bf16 store. EP=1: token-shift epilogue.
// ---------------------------------------------------------------------------
template<int KD, int EP>
__global__ __launch_bounds__(256) void k_gemm_nn(const bf16u* __restrict__ A, int lda,
                                                 const float* __restrict__ B,
                                                 bf16u* __restrict__ OUT,
                                                 const float* __restrict__ x,
                                                 const float* __restrict__ tma_g){
  __shared__ short As[128 * (KD + 8)];
  __shared__ short Bs[128 * (KD + 8)];
  const int tid  = threadIdx.x;
  const int lane = tid & 63;
  const int wv   = tid >> 6;
  const int wm   = wv >> 1, wn = wv & 1;
  const int bn0  = blockIdx.x * 128;
  const int bm0  = blockIdx.y * 128;
  const int l15  = lane & 15;
  const int quad = lane >> 4;

  for (int idx = tid; idx < 128 * (KD / 8); idx += 256){
    int r  = idx / (KD / 8);
    int kc = (idx % (KD / 8)) * 8;
    *(uint4*)&As[r * (KD + 8) + kc] =
        *(const uint4*)(A + (size_t)(bm0 + r) * lda + kc);
  }
  for (int idx = tid; idx < KD * 128; idx += 256){
    int k = idx >> 7, c = idx & 127;
    Bs[c * (KD + 8) + k] = (short)f2bf(B[(size_t)k * CC + bn0 + c]);
  }
  __syncthreads();

  f32x4 acc[4][4];
  #pragma unroll
  for (int mi = 0; mi < 4; ++mi)
    #pragma unroll
    for (int ni = 0; ni < 4; ++ni)
      #pragma unroll
      for (int rg = 0; rg < 4; ++rg) acc[mi][ni][rg] = 0.f;

  #pragma unroll
  for (int kk = 0; kk < KD; kk += 32){
    short8 af[4], bfg[4];
    #pragma unroll
    for (int mi = 0; mi < 4; ++mi)
      af[mi] = *(const short8*)&As[(wm*64 + mi*16 + l15) * (KD + 8) + kk + quad*8];
    #pragma unroll
    for (int ni = 0; ni < 4; ++ni)
      bfg[ni] = *(const short8*)&Bs[(wn*64 + ni*16 + l15) * (KD + 8) + kk + quad*8];
    #pragma unroll
    for (int mi = 0; mi < 4; ++mi)
      #pragma unroll
      for (int ni = 0; ni < 4; ++ni)
        acc[mi][ni] = __builtin_amdgcn_mfma_f32_16x16x32_bf16(af[mi], bfg[ni], acc[mi][ni], 0, 0, 0);
  }

  #pragma unroll
  for (int mi = 0; mi < 4; ++mi){
    #pragma unroll
    for (int ni = 0; ni < 4; ++ni){
      int col = bn0 + wn*64 + ni*16 + l15;
      float tm = (EP == 1) ? tma_g[col] : 0.f;
      #pragma unroll
      for (int rg = 0; rg < 4; ++rg){
        int row = bm0 + wm*64 + mi*16 + quad*4 + rg;
        float v = acc[mi][ni][rg];
        if (EP == 1){
          float xv = x[(size_t)row * CC + col];
          float xp = ((row & (TT - 1)) == 0) ? 0.f : x[(size_t)row * CC + col - CC];
          v = xv + (xp - xv) * (v + tm);
        }
        OUT[(size_t)row * CC + col] = f2bf(v);
      }
    }
  }
}

// ---------------------------------------------------------------------------
// Fused elementwise + pair precompute, 4 tokens (2 pairs) per block.
// WMODE=1: w_t stored exact f32 in WF. WMODE=0: f16 -u fallback (r4/r6).
// Pair precompute (linearity vs base S): u1 -> KKN odd, q' -> R in place,
// scalars -> Dsc; rk -> RKsc.
// ---------------------------------------------------------------------------
template<int WMODE>
__global__ __launch_bounds__(256) void k_elem(bf16u* __restrict__ K0,
    const bf16u* __restrict__ P1, const bf16u* __restrict__ P2,
    const bf16u* __restrict__ W2A,
    const float* __restrict__ kw2, const float* __restrict__ aw2,
    const float* __restrict__ maw2, const float* __restrict__ mkw2,
    const float* __restrict__ td,  const float* __restrict__ taa,
    const float* __restrict__ tma, const float* __restrict__ tmk,
    const float* __restrict__ faaaa,
    bf16u* __restrict__ KKN, bf16u* __restrict__ Bb, bf16u* __restrict__ UX,
    float* __restrict__ WF,
    bf16u* __restrict__ Rq, float* __restrict__ Dsc, float* __restrict__ RKsc){
  int n0 = blockIdx.x * 4, tid = threadIdx.x;
  __shared__ float at_l[4][16], mat_l[4][16], kt_l[4][16], mkt_l[4][16];
  {
    int grp = tid >> 6, q = tid & 63, tt = q >> 4, j = q & 15;
    if (grp == 0)      at_l[tt][j]  = bf2f(P1[(size_t)(n0+tt)*96 + 64 + j]);
    else if (grp == 1) mat_l[tt][j] = bf2f(P1[(size_t)(n0+tt)*96 + 80 + j]);
    else if (grp == 2) kt_l[tt][j]  = bf2f(P2[(size_t)(n0+tt)*32 + j]);
    else               mkt_l[tt][j] = bf2f(P2[(size_t)(n0+tt)*32 + 16 + j]);
  }
  __syncthreads();
  int c  = tid * 4;
  int h  = tid >> 4;       // head (16 lanes per head)
  int lg = tid & 15;

  float kkk[4][4], aa[4][4], mam[4][4], mkm[4][4];
  #pragma unroll
  for (int tt = 0; tt < 4; ++tt)
    #pragma unroll
    for (int i = 0; i < 4; ++i){ kkk[tt][i]=0; aa[tt][i]=0; mam[tt][i]=0; mkm[tt][i]=0; }

  #pragma unroll 4
  for (int j = 0; j < 16; ++j){
    float wk[4], wa[4], wm[4], wq[4];
    ld4f(kw2  + (size_t)j*CC + c, wk);
    ld4f(aw2  + (size_t)j*CC + c, wa);
    ld4f(maw2 + (size_t)j*CC + c, wm);
    ld4f(mkw2 + (size_t)j*CC + c, wq);
    #pragma unroll
    for (int tt = 0; tt < 4; ++tt){
      float s1 = kt_l[tt][j], s2 = at_l[tt][j], s3 = mat_l[tt][j], s4 = mkt_l[tt][j];
      #pragma unroll
      for (int i = 0; i < 4; ++i){
        kkk[tt][i] += s1 * wk[i];
        aa[tt][i]  += s2 * wa[i];
        mam[tt][i] += s3 * wm[i];
        mkm[tt][i] += s4 * wq[i];
      }
    }
  }

  float td4[4], taa4[4], tma4[4], tmk4[4], fa4[4];
  ld4f(td + c, td4); ld4f(taa + c, taa4); ld4f(tma + c, tma4); ld4f(tmk + c, tmk4);
  ld4f(faaaa + c, fa4);

#define ELEM_TOKEN(TT_, E_, A_, B_, KF_, WD_) do{ \
    float k0a[4]; ld4bf(K0 + (E_), k0a); \
    float w2a[4]; ld4bf(W2A + (E_), w2a); \
    float ssq = 0.f; \
    _Pragma("unroll") \
    for (int i = 0; i < 4; ++i){ A_[i] = k0a[i] + kkk[TT_][i]; ssq += A_[i]*A_[i]; } \
    ssq = red16(ssq); \
    float rinv = 1.f / fmaxf(sqrtf(ssq), 1e-12f); \
    float outw_[4]; \
    _Pragma("unroll") \
    for (int i = 0; i < 4; ++i){ \
      float z  = td4[i] + w2a[i]; \
      float nz = -z; \
      float sp = (nz > 15.f) ? nz : log1pf(expf(nz)); \
      float w  = -sp - 0.5f; \
      float av  = sigm(taa4[i] + aa[TT_][i]); \
      float mav = sigm(tma4[i] + mam[TT_][i]); \
      float mkv = sigm(tmk4[i] + mkm[TT_][i]); \
      A_[i] *= rinv; \
      B_[i]  = -A_[i] * av; \
      KF_[i] = k0a[i] * (mav + av * (1.f - mav)) * expf(w * mkv); \
      float ou = -expf(w); \
      outw_[i] = ou; \
      if (WMODE == 1) WD_[i] = __expf(ou);              /* exact f32 w_t */ \
      else            WD_[i] = __expf(hval(f2h(ou)));   /* f16-consistent */ \
    } \
    st4bf(Bb + (E_), B_); \
    st4bf(K0 + (E_), KF_); \
    if (WMODE == 1) *(float4*)(WF + (E_)) = make_float4(WD_[0], WD_[1], WD_[2], WD_[3]); \
    else            st4h(UX + (E_), outw_); \
  }while(0)

  #pragma unroll
  for (int p = 0; p < 2; ++p){
    const int ttE = 2*p, ttO = ttE + 1;
    size_t eE = (size_t)(n0 + ttE) * CC + c;
    size_t eO = eE + CC;
    float aE[4], bE[4], kfE[4], wdE[4];
    float aO[4], bO[4], kfO[4], wdO[4];
    ELEM_TOKEN(ttE, eE, aE, bE, kfE, wdE);
    ELEM_TOKEN(ttO, eO, aO, bO, kfO, wdO);
    st4bf(KKN + eE, aE);

    float rE[4], rO[4];
    ld4bf(Rq + eE, rE); ld4bf(Rq + eO, rO);

    // rk for k_post (before R is overwritten)
    float rkE = red16(rE[0]*kfE[0]*fa4[0] + rE[1]*kfE[1]*fa4[1]
                    + rE[2]*kfE[2]*fa4[2] + rE[3]*kfE[3]*fa4[3]);
    float rkO = red16(rO[0]*kfO[0]*fa4[0] + rO[1]*kfO[1]*fa4[1]
                    + rO[2]*kfO[2]*fa4[2] + rO[3]*kfO[3]*fa4[3]);

    // u1 over KKN odd row
    float c1 = red16(dot4(bE, aO));
    float d  = red16(dot4(kfE, aO));
    float u1[4];
    #pragma unroll
    for (int i = 0; i < 4; ++i) u1[i] = wdE[i]*aO[i] + c1*aE[i];
    st4bf(KKN + eO, u1);

    // q' even
    float cq = red16(dot4(bE, rE));
    float e1 = red16(dot4(kfE, rE));
    float qe[4];
    #pragma unroll
    for (int i = 0; i < 4; ++i) qe[i] = wdE[i]*rE[i] + cq*aE[i];
    st4bf(Rq + eE, qe);

    // z = M_{t+1} q_{t+1}; q' odd = M_t z
    float cz  = red16(dot4(bO, rO));
    float e21 = red16(dot4(kfO, rO));
    float z[4];
    #pragma unroll
    for (int i = 0; i < 4; ++i) z[i] = wdO[i]*rO[i] + cz*aO[i];
    float cy  = red16(dot4(bE, z));
    float e20 = red16(dot4(kfE, z));
    float qo[4];
    #pragma unroll
    for (int i = 0; i < 4; ++i) qo[i] = wdE[i]*z[i] + cy*aE[i];
    st4bf(Rq + eO, qo);

    if (lg == 0){
      size_t pr = (size_t)((n0 + ttE) >> 1);
      float4 dv; dv.x = d; dv.y = e1; dv.z = e20; dv.w = e21;
      *(float4*)(Dsc + (pr * HH + h) * 4) = dv;
      RKsc[(size_t)(n0 + ttE) * HH + h] = rkE;
      RKsc[(size_t)(n0 + ttO) * HH + h] = rkO;
    }
  }
#undef ELEM_TOKEN
}

// ---------------------------------------------------------------------------
// Recurrence v13: v12 math (pair fusion, all 4 reductions vs base S, f32 w)
// ported to 32-lane/row geometry: 512 blocks -> 2048 waves -> 2 waves/SIMD.
// Rationale (r7 counters): VALUBusy 36% with dur flat => stall-dominated;
// second wave/SIMD fills stalls, and per-slot VGPR halves (~18) so the
// 4-slot / 8-token prefetch survives register allocation (r7's 16-lane
// version needed ~120 regs for slots vs 84 allocated -> prefetch collapsed).
// red32 = folded-DPP red16 + laundered permlane16_swap (validated r4).
// ---------------------------------------------------------------------------
template<int WMODE>
__global__ __launch_bounds__(256) void k_rec(const bf16u* __restrict__ Qp,
                                             const bf16u* __restrict__ WT,
                                             const float* __restrict__ WF,
                                             const bf16u* __restrict__ KFt,
                                             const bf16u* __restrict__ Vt,
                                             const bf16u* __restrict__ Aa,
                                             const bf16u* __restrict__ Bv,
                                             const float* __restrict__ Dsc,
                                             bf16u* __restrict__ Y){
  const int p   = blockIdx.x;                 // 0..511
  const int g   = (p & 7) | ((p >> 6) << 3);  // (b,h) group 0..63, XCD-clustered
  const int oct = (p >> 3) & 7;               // row octet within the head
  const int b   = g >> 4;
  const int h   = g & 15;
  const int tid = threadIdx.x;
  const int l31 = tid & 31;                   // 32 lanes per row
  const int i   = oct * 8 + (tid >> 5);       // state row 0..63
  const size_t base0 = (size_t)(b * TT) * CC + h * HSS;
  const size_t colb  = base0 + l31 * 2;       // 2 cols per lane
  const size_t rowb  = base0 + i;
  const size_t dscb  = ((size_t)(b * (TT/2)) * HH + h) * 4;

  float S0 = 0.f, S1 = 0.f;                   // state cols (2*l31, 2*l31+1)

  unsigned int qEA,qOA,aEA,uOA,kEA,kOA,bEA,bOA,wEA,wOA; float2 fEA,fOA; unsigned short vEA,vOA; float4 dA;
  unsigned int qEB,qOB,aEB,uOB,kEB,kOB,bEB,bOB,wEB,wOB; float2 fEB,fOB; unsigned short vEB,vOB; float4 dB;
  unsigned int qEC,qOC,aEC,uOC,kEC,kOC,bEC,bOC,wEC,wOC; float2 fEC,fOC; unsigned short vEC,vOC; float4 dC;
  unsigned int qED,qOD,aED,uOD,kED,kOD,bED,bOD,wED,wOD; float2 fED,fOD; unsigned short vED,vOD; float4 dD;

#define PL(S, T_) do{ \
    size_t cE_ = colb + (size_t)(T_) * CC, cO_ = cE_ + CC; \
    qE##S = *(const unsigned int*)(Qp  + cE_); qO##S = *(const unsigned int*)(Qp  + cO_); \
    aE##S = *(const unsigned int*)(Aa  + cE_); uO##S = *(const unsigned int*)(Aa  + cO_); \
    kE##S = *(const unsigned int*)(KFt + cE_); kO##S = *(const unsigned int*)(KFt + cO_); \
    bE##S = *(const unsigned int*)(Bv  + cE_); bO##S = *(const unsigned int*)(Bv  + cO_); \
    if (WMODE == 1){ \
      fE##S = *(const float2*)(WF + cE_); fO##S = *(const float2*)(WF + cO_); \
    } else { \
      wE##S = *(const unsigned int*)(WT + cE_); wO##S = *(const unsigned int*)(WT + cO_); \
    } \
    vE##S = Vt[rowb + (size_t)(T_) * CC]; \
    vO##S = Vt[rowb + (size_t)(T_ + 1) * CC]; \
    d##S  = *(const float4*)(Dsc + dscb + (size_t)((T_) >> 1) * (HH*4)); \
  }while(0)

#define PSTEP(S, T_) do{ \
    float a0=bflo(aE##S), a1=bfhi(aE##S); \
    float u0=bflo(uO##S), u1=bfhi(uO##S); \
    float g0=bflo(qE##S), g1=bfhi(qE##S); \
    float o0=bflo(qO##S), o1=bfhi(qO##S); \
    float pE_ = fmaf(S1, a1, S0 * a0); \
    float pO_ = fmaf(S1, u1, S0 * u0); \
    float yE_ = fmaf(S1, g1, S0 * g0); \
    float yO_ = fmaf(S1, o1, S0 * o0); \
    pE_ = red32(pE_); \
    pO_ = red32(pO_); \
    yE_ = red32(yE_); \
    yO_ = red32(yO_); \
    float vEf = bf2f(vE##S), vOf = bf2f(vO##S); \
    float saE = pE_; \
    float saO = fmaf(d##S.x, vEf, pO_); \
    float ypE = fmaf(d##S.y, vEf, yE_); \
    float ypO = fmaf(d##S.z, vEf, fmaf(d##S.w, vOf, yO_)); \
    float k0=bflo(kE##S), k1=bfhi(kE##S); \
    float b0=bflo(bE##S), b1=bfhi(bE##S); \
    float w0, w1; \
    if (WMODE == 1){ w0=fE##S.x; w1=fE##S.y; } \
    else { w0=__expf(hlo(wE##S)); w1=__expf(hhi(wE##S)); } \
    S0 = fmaf(S0, w0, fmaf(saE, b0, vEf * k0)); \
    S1 = fmaf(S1, w1, fmaf(saE, b1, vEf * k1)); \
    float ko0=bflo(kO##S), ko1=bfhi(kO##S); \
    float bo0=bflo(bO##S), bo1=bfhi(bO##S); \
    float wo0, wo1; \
    if (WMODE == 1){ wo0=fO##S.x; wo1=fO##S.y; } \
    else { wo0=__expf(hlo(wO##S)); wo1=__expf(hhi(wO##S)); } \
    S0 = fmaf(S0, wo0, fmaf(saO, bo0, vOf * ko0)); \
    S1 = fmaf(S1, wo1, fmaf(saO, bo1, vOf * ko1)); \
    if (l31 == 0){ \
      Y[rowb + (size_t)(T_) * CC]     = f2bf(ypE); \
      Y[rowb + (size_t)(T_ + 1) * CC] = f2bf(ypO); \
    } \
  }while(0)

  PL(A, 0); PL(B, 2); PL(C, 4); PL(D, 6);
  for (int t = 0; t < TT; t += 8){
    PSTEP(A, t);
    if (t + 8  < TT) PL(A, t + 8);
    PSTEP(B, t + 2);
    if (t + 10 < TT) PL(B, t + 10);
    PSTEP(C, t + 4);
    if (t + 12 < TT) PL(C, t + 12);
    PSTEP(D, t + 6);
    if (t + 14 < TT) PL(D, t + 14);
  }
#undef PL
#undef PSTEP
}

// ---------------------------------------------------------------------------
// Post: GroupNorm + precomputed bonus rk*v + precomputed gate GV -> YG (bf16)
// ---------------------------------------------------------------------------
__global__ __launch_bounds__(256) void k_post(const bf16u* __restrict__ Y,
                                              const bf16u* __restrict__ Vt,
                                              const bf16u* __restrict__ GV,
                                              const float* __restrict__ lnw,
                                              const float* __restrict__ lnb,
                                              const float* __restrict__ RKsc,
                                              bf16u* __restrict__ YG){
  int n = blockIdx.x, tid = threadIdx.x;
  int c = tid * 4;
  size_t e = (size_t)n * CC + c;

  float ya[4]; ld4bf(Y + e, ya);
  float s = ya[0] + ya[1] + ya[2] + ya[3];
  s = red16(s);
  float mu = s * (1.f / 64.f);
  float d[4], vs = 0.f;
  #pragma unroll
  for (int i = 0; i < 4; ++i){ d[i] = ya[i] - mu; vs += d[i] * d[i]; }
  vs = red16(vs);
  float rstd = rsqrtf(vs * (1.f / 64.f) + EPSGN);

  float rk = RKsc[(size_t)n * HH + (tid >> 4)];

  float va[4]; ld4bf(Vt + e, va);
  float lw4[4], lb4[4];
  ld4f(lnw + c, lw4); ld4f(lnb + c, lb4);
  float g[4]; ld4bf(GV + e, g);
  float o[4];
  #pragma unroll
  for (int i = 0; i < 4; ++i){
    float yn = d[i] * rstd * lw4[i] + lb4[i] + rk * va[i];
    o[i] = yn * g[i];
  }
  st4bf(YG + e, o);
}

// ---------------------------------------------------------------------------
extern "C" void kernel_launch(void* const* d_in, const int* in_sizes, int n_in,
                              void* d_out, int out_size, void* d_ws, size_t ws_size,
                              hipStream_t stream){
  (void)in_sizes; (void)n_in; (void)out_size;
  const float* x        = (const float*)d_in[0];
  const float* tmx      = (const float*)d_in[1];
  const float* tmaa     = (const float*)d_in[2];
  const float* maa_w1   = (const float*)d_in[3];
  const float* maa_w2   = (const float*)d_in[4];
  const float* decay_w1 = (const float*)d_in[5];
  const float* decay_w2 = (const float*)d_in[6];
  const float* aaa_w1   = (const float*)d_in[7];
  const float* aaa_w2   = (const float*)d_in[8];
  const float* kkk_w1   = (const float*)d_in[9];
  const float* kkk_w2   = (const float*)d_in[10];
  const float* gate_w1  = (const float*)d_in[11];
  const float* gate_w2  = (const float*)d_in[12];
  const float* ma_w1    = (const float*)d_in[13];
  const float* ma_w2    = (const float*)d_in[14];
  const float* mk_w1    = (const float*)d_in[15];
  const float* mk_w2    = (const float*)d_in[16];
  const float* t_decay  = (const float*)d_in[17];
  const float* t_faaaa  = (const float*)d_in[18];
  const float* t_aaaaa  = (const float*)d_in[19];
  const float* t_misc_a = (const float*)d_in[20];
  const float* t_misc_k = (const float*)d_in[21];
  const float* Wr       = (const float*)d_in[22];
  const float* Wk       = (const float*)d_in[23];
  const float* Wv       = (const float*)d_in[24];
  const float* Wo       = (const float*)d_in[25];
  const float* ln_w     = (const float*)d_in[26];
  const float* ln_b     = (const float*)d_in[27];

  // Slot map (8MiB bf16 each), 56 MiB slots + smalls at 56..60 MiB.
  // Fast path adds WF (f32 w_t, 16 MiB) at 60..76 MiB (ws >= 77 MiB).
  bf16u* bw  = (bf16u*)d_ws;
  bf16u* MIX = bw + 0*SLOT;
  bf16u* X0  = bw + 0*SLOT;
  bf16u* KKN = bw + 0*SLOT;
  bf16u* YG  = bw + 0*SLOT;
  bf16u* X1  = bw + 1*SLOT;
  bf16u* Bb  = bw + 1*SLOT;
  bf16u* GV  = bw + 1*SLOT;
  bf16u* X2  = bw + 2*SLOT;
  bf16u* UX  = bw + 2*SLOT;
  bf16u* X3  = bw + 3*SLOT;
  bf16u* W2A = bw + 3*SLOT;
  bf16u* Yb  = bw + 3*SLOT;
  bf16u* R   = bw + 4*SLOT;   // becomes q'
  bf16u* K0  = bw + 5*SLOT;   // becomes KF
  bf16u* V   = bw + 6*SLOT;
  char*  wsb = (char*)d_ws;
  bf16u* LO  = (bf16u*)(wsb + (56ull<<20));   // [N,128] bf16, 1 MiB
  bf16u* GT  = (bf16u*)(wsb + (57ull<<20));   // [N,128] bf16, 1 MiB
  bf16u* P1  = (bf16u*)(wsb + (58ull<<20));   // [N,96]  bf16 (dt|at|ma)
  bf16u* P2  = (bf16u*)(wsb + (58ull<<20) + (768ull<<10)); // [N,32] bf16
  float* Dsc = (float*)(wsb + (59ull<<20));   // [N/2,16] float4, 512 KiB
  float* RKsc= (float*)(wsb + (59ull<<20) + (512ull<<10)); // [N,16] f32, 256 KiB
  float* WF  = (float*)(wsb + (60ull<<20));   // [N,CC] f32 w_t, 16 MiB
  const bool wf32 = ws_size >= (77ull<<20);

  // 1. mix
  k_prep<<<4096, 256, 0, stream>>>(x, tmx, MIX);
  // 2. lo = tanh(mix @ maa_w1^T) [N,128] bf16
  k_gemm_mfma<true><<<dim3(1,32),256,0,stream>>>(MIX, maa_w1, maa_w1, maa_w1,
                                                 128, 128, LO, 128, CC, 128);
  // 3. xm[g] = x + xx*(lo_g @ maa_w2_g + tmaa_g)   (NN GEMM + fused epilogue)
  bf16u* XMs[4] = {X0, X1, X2, X3};
  for (int g = 0; g < 4; ++g)
    k_gemm_nn<32,1><<<dim3(8,32),256,0,stream>>>(LO + g*32, 128,
                                                 maa_w2 + (size_t)g*32*CC,
                                                 XMs[g], x, tmaa + (size_t)g*CC);
  // 4. big projections (bf16 out)
  k_gemm_mfma<true><<<dim3(8,32),256,0,stream>>>(X0, Wr, Wr, Wr, CC, CC, R,  CC, CC, 0);
  k_gemm_mfma<true><<<dim3(8,32),256,0,stream>>>(X2, Wk, Wk, Wk, CC, CC, K0, CC, CC, 0);
  k_gemm_mfma<true><<<dim3(8,32),256,0,stream>>>(X3, Wv, Wv, Wv, CC, CC, V,  CC, CC, 0);
  // 5. first-stage LoRA projections (bf16 out)
  k_gemm_mfma<true><<<dim3(1,32),256,0,stream>>>(X0, gate_w1, gate_w1, gate_w1,
                                                 128, 128, GT, 128, CC, 128);
  k_gemm_mfma<true><<<dim3(1,32),256,0,stream>>>(X1, decay_w1, aaa_w1, ma_w1,
                                                 64, 80, P1, 96, CC, 64);
  k_gemm_mfma<true><<<dim3(1,32),256,0,stream>>>(X2, kkk_w1, mk_w1, mk_w1,
                                                 16, 32, P2, 32, CC, 16);
  // 6. decay second-stage projection: W2A = P1[:, :64] @ decay_w2  -> S3
  k_gemm_nn<64,0><<<dim3(8,32),256,0,stream>>>(P1, 96, decay_w2, W2A, nullptr, nullptr);
  // 7. fused elementwise + pair precompute (u1, q', scalars, rk)
  if (wf32)
    k_elem<1><<<1024, 256, 0, stream>>>(K0, P1, P2, W2A,
                                        kkk_w2, aaa_w2, ma_w2, mk_w2,
                                        t_decay, t_aaaaa, t_misc_a, t_misc_k, t_faaaa,
                                        KKN, Bb, UX, WF, R, Dsc, RKsc);
  else
    k_elem<0><<<1024, 256, 0, stream>>>(K0, P1, P2, W2A,
                                        kkk_w2, aaa_w2, ma_w2, mk_w2,
                                        t_decay, t_aaaaa, t_misc_a, t_misc_k, t_faaaa,
                                        KKN, Bb, UX, WF, R, Dsc, RKsc);
  // 8. delta-rule recurrence (v13: 32-lane rows, 2 waves/SIMD, pair-fused)
  if (wf32)
    k_rec<1><<<512, 256, 0, stream>>>(R, UX, WF, K0, V, KKN, Bb, Dsc, Yb);
  else
    k_rec<0><<<512, 256, 0, stream>>>(R, UX, WF, K0, V, KKN, Bb, Dsc, Yb);
  // 9. gate second-stage: GV = GT @ gate_w2 -> S1 (Bb dead after k_rec)
  k_gemm_nn<128,0><<<dim3(8,32),256,0,stream>>>(GT, 128, gate_w2, GV, nullptr, nullptr);
  // 10. groupnorm + bonus + gate
  k_post<<<4096, 256, 0, stream>>>(Yb, V, GV, ln_w, ln_b, RKsc, YG);
  // 11. out = yg @ Wo^T -> f32
  k_gemm_mfma<false><<<dim3(8,32),256,0,stream>>>(YG, Wo, Wo, Wo, CC, CC, d_out, CC, CC, 0);
}

// Round 9
// 716.376 us; speedup vs baseline: 1.3696x; 1.1294x over previous
//
#include <hip/hip_runtime.h>
#include <cstdint>
#include <cstddef>

// Problem constants
#define BB   4
#define TT   1024
#define CC   1024
#define HH   16
#define HSS  64
#define NNtok 4096            // B*T
#define EPSGN 0.00064f
#define W2TS 192              // W2TB col count (maa_w2 128 | decay_w2 64)

typedef unsigned short bf16u;
typedef __attribute__((ext_vector_type(8))) short short8;
typedef __attribute__((ext_vector_type(4))) float f32x4;
#define SLOT 4194304ull       // elements per 8MiB bf16 slot (= NNtok*CC)

__device__ __forceinline__ float bf2f(bf16u u){
  union { unsigned int i; float f; } cv; cv.i = ((unsigned int)u) << 16; return cv.f;
}
__device__ __forceinline__ unsigned short f2bfbits(unsigned int x){
  return (unsigned short)((x + 0x7fffu + ((x >> 16) & 1u)) >> 16);   // RNE
}
__device__ __forceinline__ bf16u f2bf(float f){
  union { float f; unsigned int i; } cv; cv.f = f;
  return f2bfbits(cv.i);
}
__device__ __forceinline__ void ld4bf(const bf16u* p, float* o){
  ushort4 u = *reinterpret_cast<const ushort4*>(p);
  o[0]=bf2f(u.x); o[1]=bf2f(u.y); o[2]=bf2f(u.z); o[3]=bf2f(u.w);
}
__device__ __forceinline__ void st4bf(bf16u* p, const float* v){
  ushort4 u; u.x=f2bf(v[0]); u.y=f2bf(v[1]); u.z=f2bf(v[2]); u.w=f2bf(v[3]);
  *reinterpret_cast<ushort4*>(p) = u;
}
__device__ __forceinline__ unsigned short f2h(float f){
  union { _Float16 h; unsigned short s; } c; c.h = (_Float16)f; return c.s;
}
__device__ __forceinline__ void st4h(bf16u* p, const float* v){
  ushort4 u; u.x=f2h(v[0]); u.y=f2h(v[1]); u.z=f2h(v[2]); u.w=f2h(v[3]);
  *reinterpret_cast<ushort4*>(p) = u;
}
__device__ __forceinline__ void ld4f(const float* p, float* o){
  float4 v = *reinterpret_cast<const float4*>(p);
  o[0]=v.x; o[1]=v.y; o[2]=v.z; o[3]=v.w;
}
__device__ __forceinline__ float sigm(float x){ return 1.f / (1.f + expf(-x)); }

// unpack helpers
__device__ __forceinline__ float bflo(unsigned int u){
  union { unsigned int i; float f; } c; c.i = u << 16; return c.f;
}
__device__ __forceinline__ float bfhi(unsigned int u){
  union { unsigned int i; float f; } c; c.i = u & 0xffff0000u; return c.f;
}
__device__ __forceinline__ float hlo(unsigned int u){
  union { unsigned short s; _Float16 h; } c; c.s = (unsigned short)(u & 0xffffu); return (float)c.h;
}
__device__ __forceinline__ float hhi(unsigned int u){
  union { unsigned short s; _Float16 h; } c; c.s = (unsigned short)(u >> 16); return (float)c.h;
}
__device__ __forceinline__ float hval(unsigned short s){
  union { unsigned short s; _Float16 h; } c; c.s = s; return (float)c.h;
}
__device__ __forceinline__ float dot4(const float* x, const float* y){
  return (x[0]*y[0] + x[1]*y[1]) + (x[2]*y[2] + x[3]*y[3]);
}

// 16-lane sum via DPP. old=0 + bound_ctrl=1 folds to single v_add_f32_dpp.
template<int CTRL>
__device__ __forceinline__ float dpp_add(float v){
  union { float f; int i; } a, b;
  a.f = v;
  b.i = __builtin_amdgcn_update_dpp(0, a.i, CTRL, 0xF, 0xF, true);
  return v + b.f;
}
__device__ __forceinline__ float red16(float v){
  v = dpp_add<0xB1>(v);    // quad_perm [1,0,3,2]  (xor 1)
  v = dpp_add<0x4E>(v);    // quad_perm [2,3,0,1]  (xor 2)
  v = dpp_add<0x124>(v);   // row_ror:4
  v = dpp_add<0x128>(v);   // row_ror:8
  return v;
}
// 32-lane sum in all lanes: red16 then exchange complementary 16-rows
// between two DISTINCT-register copies (laundered; rounds 1/3 failed when
// regalloc coalesced both operands into one phys reg -> self-swap).
__device__ __forceinline__ float red32(float v){
  v = red16(v);
  union { float f; int i; } x, y;
  x.f = v; y.f = v;
  asm volatile("" : "+v"(y.i));   // distinct-vreg launder
  asm volatile("v_permlane16_swap_b32 %0, %1" : "+v"(x.i), "+v"(y.i));
  return x.f + y.f;
}

// ---------------------------------------------------------------------------
// mix = x + (x[t-1]-x[t])*time_maa_x  (x[-1]=0), stored bf16
// ---------------------------------------------------------------------------
__global__ __launch_bounds__(256) void k_prep(const float* __restrict__ x,
                                              const float* __restrict__ tmx,
                                              bf16u* __restrict__ MIX){
  int e = (blockIdx.x * 256 + threadIdx.x) * 4;
  int n = e >> 10;
  int c = e & (CC - 1);
  int t = n & (TT - 1);
  float xf[4]; ld4f(x + e, xf);
  float pf[4] = {0.f, 0.f, 0.f, 0.f};
  if (t > 0) ld4f(x + e - CC, pf);
  float tm[4]; ld4f(tmx + c, tm);
  float mv[4];
  #pragma unroll
  for (int i = 0; i < 4; ++i) mv[i] = xf[i] + (pf[i] - xf[i]) * tm[i];
  st4bf(MIX + e, mv);
}

// ---------------------------------------------------------------------------
// Weight pre-conversion (once per call, ~5us):
//  blocks 0..3071   : Wr/Wk/Wv f32 -> bf16 (RNE f2bf == old in-GEMM rounding)
//  blocks 3072..3455: W1B concat [maa_w1|gate_w1|decay_w1|aaa_w1|ma_w1|kkk_w1|mk_w1]
//  blocks 3456..3647: W2TB transpose [c][j]: j<128 maa_w2 (flat [128][1024]),
//                     j in 128..191 decay_w2
// All outputs live in the WF region (60..67.4 MiB) and are dead before
// k_elem overwrites it at step 7.
// ---------------------------------------------------------------------------
__global__ __launch_bounds__(256) void k_wconv1(
    const float* __restrict__ Wr, const float* __restrict__ Wk,
    const float* __restrict__ Wv,
    const float* __restrict__ maa_w1, const float* __restrict__ gate_w1,
    const float* __restrict__ decay_w1, const float* __restrict__ aaa_w1,
    const float* __restrict__ ma_w1, const float* __restrict__ kkk_w1,
    const float* __restrict__ mk_w1,
    const float* __restrict__ maa_w2, const float* __restrict__ decay_w2,
    bf16u* __restrict__ WrB, bf16u* __restrict__ WkB, bf16u* __restrict__ WvB,
    bf16u* __restrict__ W1B, bf16u* __restrict__ W2TB){
  int blk = blockIdx.x, tid = threadIdx.x;
  if (blk < 3072){
    const float* src = (blk < 1024) ? Wr : (blk < 2048) ? Wk : Wv;
    bf16u* dst = (blk < 1024) ? WrB : (blk < 2048) ? WkB : WvB;
    size_t e = (size_t)(blk & 1023) * 1024 + (size_t)tid * 4;
    float v[4]; ld4f(src + e, v);
    st4bf(dst + e, v);
  } else if (blk < 3456){
    int row = blk - 3072;
    const float* src;
    if      (row < 128) src = maa_w1   + (size_t)row * 1024;
    else if (row < 256) src = gate_w1  + (size_t)(row - 128) * 1024;
    else if (row < 320) src = decay_w1 + (size_t)(row - 256) * 1024;
    else if (row < 336) src = aaa_w1   + (size_t)(row - 320) * 1024;
    else if (row < 352) src = ma_w1    + (size_t)(row - 336) * 1024;
    else if (row < 368) src = kkk_w1   + (size_t)(row - 352) * 1024;
    else                src = mk_w1    + (size_t)(row - 368) * 1024;
    float v[4]; ld4f(src + tid * 4, v);
    st4bf(W1B + (size_t)row * 1024 + tid * 4, v);
  } else {
    int j = blk - 3456;   // 0..191
    const float* src = (j < 128) ? (maa_w2 + (size_t)j * 1024)
                                 : (decay_w2 + (size_t)(j - 128) * 1024);
    for (int c = tid; c < 1024; c += 256)
      W2TB[(size_t)c * W2TS + j] = f2bf(src[c]);
  }
}

// Wo -> bf16, runs AFTER k_rec into the then-dead WF region.
__global__ __launch_bounds__(256) void k_wconv2(const float* __restrict__ Wo,
                                                bf16u* __restrict__ WoB){
  size_t e = ((size_t)blockIdx.x * 256 + threadIdx.x) * 4;
  float v[4]; ld4f(Wo + e, v);
  st4bf(WoB + e, v);
}

// ---------------------------------------------------------------------------
// MFMA NT GEMM, bf16-W variant: OUT[M,Nd] = X[M,K](bf16) @ WB[Nd,K]^T (bf16).
// Staging is pure uint4 copies: removes 4 f32 uint4 loads + 48 convert-VALU
// per thread per K-iter vs the f32 variant (the dominant staging cost) and
// halves W fetch bytes. tanh on cols < act_n. 128x128, BK=32.
// ---------------------------------------------------------------------------
template<bool OB>
__global__ __launch_bounds__(256) void k_gemm_mfma_b(const bf16u* __restrict__ X,
                                                     const bf16u* __restrict__ WB,
                                                     void* __restrict__ OUTv,
                                                     int Nd, int Kd, int act_n){
  __shared__ short As[128 * 40];
  __shared__ short Bs[128 * 40];
  const int tid  = threadIdx.x;
  const int lane = tid & 63;
  const int wv   = tid >> 6;
  const int wm   = wv >> 1, wn = wv & 1;
  const int bn0  = blockIdx.x * 128;
  const int bm0  = blockIdx.y * 128;
  const int l15  = lane & 15;
  const int quad = lane >> 4;

  f32x4 acc[4][4];
  #pragma unroll
  for (int mi = 0; mi < 4; ++mi)
    #pragma unroll
    for (int ni = 0; ni < 4; ++ni)
      #pragma unroll
      for (int rg = 0; rg < 4; ++rg) acc[mi][ni][rg] = 0.f;

  const int r    = tid >> 1;
  const int half = (tid & 1) * 16;

  const bf16u* wsrc = (bn0 + r < Nd) ? WB + (size_t)(bn0 + r) * Kd : nullptr;
  const bf16u* xsrc = X + (size_t)(bm0 + r) * Kd;

  for (int k0 = 0; k0 < Kd; k0 += 32){
    uint4 xa = *(const uint4*)(xsrc + k0 + half);
    uint4 xb = *(const uint4*)(xsrc + k0 + half + 8);
    uint4 wa = make_uint4(0,0,0,0), wb = wa;
    if (wsrc){
      wa = *(const uint4*)(wsrc + k0 + half);
      wb = *(const uint4*)(wsrc + k0 + half + 8);
    }
    *(uint4*)&As[r * 40 + half]     = xa;
    *(uint4*)&As[r * 40 + half + 8] = xb;
    *(uint4*)&Bs[r * 40 + half]     = wa;
    *(uint4*)&Bs[r * 40 + half + 8] = wb;
    __syncthreads();

    short8 af[4], bfg[4];
    #pragma unroll
    for (int mi = 0; mi < 4; ++mi)
      af[mi] = *(const short8*)&As[(wm*64 + mi*16 + l15) * 40 + quad*8];
    #pragma unroll
    for (int ni = 0; ni < 4; ++ni)
      bfg[ni] = *(const short8*)&Bs[(wn*64 + ni*16 + l15) * 40 + quad*8];
    #pragma unroll
    for (int mi = 0; mi < 4; ++mi)
      #pragma unroll
      for (int ni = 0; ni < 4; ++ni)
        acc[mi][ni] = __builtin_amdgcn_mfma_f32_16x16x32_bf16(af[mi], bfg[ni], acc[mi][ni], 0, 0, 0);
    __syncthreads();
  }

  #pragma unroll
  for (int mi = 0; mi < 4; ++mi){
    #pragma unroll
    for (int ni = 0; ni < 4; ++ni){
      int col = bn0 + wn*64 + ni*16 + l15;
      if (col >= Nd) continue;
      #pragma unroll
      for (int rg = 0; rg < 4; ++rg){
        int row = bm0 + wm*64 + mi*16 + quad*4 + rg;
        float v = acc[mi][ni][rg];
        if (col < act_n) v = tanhf(v);
        if (OB) ((bf16u*)OUTv)[(size_t)row * Nd + col] = f2bf(v);
        else    ((float*)OUTv)[(size_t)row * Nd + col] = v;
      }
    }
  }
}

// ---------------------------------------------------------------------------
// MFMA NN GEMM, pre-transposed bf16 B: OUT[M,CC] = A[M,KD] @ BT[:, koff:koff+KD]^T
// where BT is [CC][W2TS] bf16 (so Bs staging = coalesced uint4 copies, no
// per-element f32 transpose+convert). EP=1: token-shift epilogue.
// ---------------------------------------------------------------------------
template<int KD, int EP>
__global__ __launch_bounds__(256) void k_gemm_nn_b(const bf16u* __restrict__ A, int lda,
                                                   const bf16u* __restrict__ BT, int koff,
                                                   bf16u* __restrict__ OUT,
                                                   const float* __restrict__ x,
                                                   const float* __restrict__ tma_g){
  __shared__ short As[128 * (KD + 8)];
  __shared__ short Bs[128 * (KD + 8)];
  const int tid  = threadIdx.x;
  const int lane = tid & 63;
  const int wv   = tid >> 6;
  const int wm   = wv >> 1, wn = wv & 1;
  const int bn0  = blockIdx.x * 128;
  const int bm0  = blockIdx.y * 128;
  const int l15  = lane & 15;
  const int quad = lane >> 4;

  for (int idx = tid; idx < 128 * (KD / 8); idx += 256){
    int r  = idx / (KD / 8);
    int kc = (idx % (KD / 8)) * 8;
    *(uint4*)&As[r * (KD + 8) + kc] =
        *(const uint4*)(A + (size_t)(bm0 + r) * lda + kc);
  }
  for (int idx = tid; idx < 128 * (KD / 8); idx += 256){
    int cc_ = idx / (KD / 8);
    int kc  = (idx % (KD / 8)) * 8;
    *(uint4*)&Bs[cc_ * (KD + 8) + kc] =
        *(const uint4*)(BT + (size_t)(bn0 + cc_) * W2TS + koff + kc);
  }
  __syncthreads();

  f32x4 acc[4][4];
  #pragma unroll
  for (int mi = 0; mi < 4; ++mi)
    #pragma unroll
    for (int ni = 0; ni < 4; ++ni)
      #pragma unroll
      for (int rg = 0; rg < 4; ++rg) acc[mi][ni][rg] = 0.f;

  #pragma unroll
  for (int kk = 0; kk < KD; kk += 32){
    short8 af[4], bfg[4];
    #pragma unroll
    for (int mi = 0; mi < 4; ++mi)
      af[mi] = *(const short8*)&As[(wm*64 + mi*16 + l15) * (KD + 8) + kk + quad*8];
    #pragma unroll
    for (int ni = 0; ni < 4; ++ni)
      bfg[ni] = *(const short8*)&Bs[(wn*64 + ni*16 + l15) * (KD + 8) + kk + quad*8];
    #pragma unroll
    for (int mi = 0; mi < 4; ++mi)
      #pragma unroll
      for (int ni = 0; ni < 4; ++ni)
        acc[mi][ni] = __builtin_amdgcn_mfma_f32_16x16x32_bf16(af[mi], bfg[ni], acc[mi][ni], 0, 0, 0);
  }

  #pragma unroll
  for (int mi = 0; mi < 4; ++mi){
    #pragma unroll
    for (int ni = 0; ni < 4; ++ni){
      int col = bn0 + wn*64 + ni*16 + l15;
      float tm = (EP == 1) ? tma_g[col] : 0.f;
      #pragma unroll
      for (int rg = 0; rg < 4; ++rg){
        int row = bm0 + wm*64 + mi*16 + quad*4 + rg;
        float v = acc[mi][ni][rg];
        if (EP == 1){
          float xv = x[(size_t)row * CC + col];
          float xp = ((row & (TT - 1)) == 0) ? 0.f : x[(size_t)row * CC + col - CC];
          v = xv + (xp - xv) * (v + tm);
        }
        OUT[(size_t)row * CC + col] = f2bf(v);
      }
    }
  }
}

// ---------------------------------------------------------------------------
// LEGACY f32-W GEMMs (fallback path + GV, whose weight area is reused by WF)
// ---------------------------------------------------------------------------
template<bool OB>
__global__ __launch_bounds__(256) void k_gemm_mfma(const bf16u* __restrict__ X,
                                                   const float* __restrict__ Wa,
                                                   const float* __restrict__ Wb,
                                                   const float* __restrict__ Wc,
                                                   int na, int nab,
                                                   void* __restrict__ OUTv,
                                                   int Nd, int Kd, int act_n){
  __shared__ short As[128 * 40];
  __shared__ short Bs[128 * 40];
  const int tid  = threadIdx.x;
  const int lane = tid & 63;
  const int wv   = tid >> 6;
  const int wm   = wv >> 1, wn = wv & 1;
  const int bn0  = blockIdx.x * 128;
  const int bm0  = blockIdx.y * 128;
  const int l15  = lane & 15;
  const int quad = lane >> 4;

  f32x4 acc[4][4];
  #pragma unroll
  for (int mi = 0; mi < 4; ++mi)
    #pragma unroll
    for (int ni = 0; ni < 4; ++ni)
      #pragma unroll
      for (int rg = 0; rg < 4; ++rg) acc[mi][ni][rg] = 0.f;

  const int r    = tid >> 1;
  const int half = (tid & 1) * 16;

  int rr = bn0 + r;
  const float* wsrc = nullptr;
  if (rr < na)        wsrc = Wa + (size_t)rr * Kd;
  else if (rr < nab)  wsrc = Wb + (size_t)(rr - na) * Kd;
  else if (rr < Nd)   wsrc = Wc + (size_t)(rr - nab) * Kd;
  const bf16u* xsrc = X + (size_t)(bm0 + r) * Kd;

  for (int k0 = 0; k0 < Kd; k0 += 32){
    uint4 xa = *(const uint4*)(xsrc + k0 + half);
    uint4 xb = *(const uint4*)(xsrc + k0 + half + 8);
    uint4 w0 = make_uint4(0,0,0,0), w1 = w0, w2 = w0, w3 = w0;
    if (wsrc){
      w0 = *(const uint4*)(wsrc + k0 + half);
      w1 = *(const uint4*)(wsrc + k0 + half + 4);
      w2 = *(const uint4*)(wsrc + k0 + half + 8);
      w3 = *(const uint4*)(wsrc + k0 + half + 12);
    }
    union { unsigned short s[8]; uint4 v; } p0, p1;
    p0.s[0]=f2bfbits(w0.x); p0.s[1]=f2bfbits(w0.y); p0.s[2]=f2bfbits(w0.z); p0.s[3]=f2bfbits(w0.w);
    p0.s[4]=f2bfbits(w1.x); p0.s[5]=f2bfbits(w1.y); p0.s[6]=f2bfbits(w1.z); p0.s[7]=f2bfbits(w1.w);
    p1.s[0]=f2bfbits(w2.x); p1.s[1]=f2bfbits(w2.y); p1.s[2]=f2bfbits(w2.z); p1.s[3]=f2bfbits(w2.w);
    p1.s[4]=f2bfbits(w3.x); p1.s[5]=f2bfbits(w3.y); p1.s[6]=f2bfbits(w3.z); p1.s[7]=f2bfbits(w3.w);

    *(uint4*)&As[r * 40 + half]     = xa;
    *(uint4*)&As[r * 40 + half + 8] = xb;
    *(uint4*)&Bs[r * 40 + half]     = p0.v;
    *(uint4*)&Bs[r * 40 + half + 8] = p1.v;
    __syncthreads();

    short8 af[4], bfg[4];
    #pragma unroll
    for (int mi = 0; mi < 4; ++mi)
      af[mi] = *(const short8*)&As[(wm*64 + mi*16 + l15) * 40 + quad*8];
    #pragma unroll
    for (int ni = 0; ni < 4; ++ni)
      bfg[ni] = *(const short8*)&Bs[(wn*64 + ni*16 + l15) * 40 + quad*8];
    #pragma unroll
    for (int mi = 0; mi < 4; ++mi)
      #pragma unroll
      for (int ni = 0; ni < 4; ++ni)
        acc[mi][ni] = __builtin_amdgcn_mfma_f32_16x16x32_bf16(af[mi], bfg[ni], acc[mi][ni], 0, 0, 0);
    __syncthreads();
  }

  #pragma unroll
  for (int mi = 0; mi < 4; ++mi){
    #pragma unroll
    for (int ni = 0; ni < 4; ++ni){
      int col = bn0 + wn*64 + ni*16 + l15;
      if (col >= Nd) continue;
      #pragma unroll
      for (int rg = 0; rg < 4; ++rg){
        int row = bm0 + wm*64 + mi*16 + quad*4 + rg;
        float v = acc[mi][ni][rg];
        if (col < act_n) v = tanhf(v);
        if (OB) ((bf16u*)OUTv)[(size_t)row * Nd + col] = f2bf(v);
        else    ((float*)OUTv)[(size_t)row * Nd + col] = v;
      }
    }
  }
}

template<int KD, int EP>
__global__ __launch_bounds__(256) void k_gemm_nn(const bf16u* __restrict__ A, int lda,
                                                 const float* __restrict__ B,
                                                 bf16u* __restrict__ OUT,
                                                 const float* __restrict__ x,
                                                 const float* __restrict__ tma_g){
  __shared__ short As[128 * (KD + 8)];
  __shared__ short Bs[128 * (KD + 8)];
  const int tid  = threadIdx.x;
  const int lane = tid & 63;
  const int wv   = tid >> 6;
  const int wm   = wv >> 1, wn = wv & 1;
  const int bn0  = blockIdx.x * 128;
  const int bm0  = blockIdx.y * 128;
  const int l15  = lane & 15;
  const int quad = lane >> 4;

  for (int idx = tid; idx < 128 * (KD / 8); idx += 256){
    int r  = idx / (KD / 8);
    int kc = (idx % (KD / 8)) * 8;
    *(uint4*)&As[r * (KD + 8) + kc] =
        *(const uint4*)(A + (size_t)(bm0 + r) * lda + kc);
  }
  for (int idx = tid; idx < KD * 128; idx += 256){
    int k = idx >> 7, c = idx & 127;
    Bs[c * (KD + 8) + k] = (short)f2bf(B[(size_t)k * CC + bn0 + c]);
  }
  __syncthreads();

  f32x4 acc[4][4];
  #pragma unroll
  for (int mi = 0; mi < 4; ++mi)
    #pragma unroll
    for (int ni = 0; ni < 4; ++ni)
      #pragma unroll
      for (int rg = 0; rg < 4; ++rg) acc[mi][ni][rg] = 0.f;

  #pragma unroll
  for (int kk = 0; kk < KD; kk += 32){
    short8 af[4], bfg[4];
    #pragma unroll
    for (int mi = 0; mi < 4; ++mi)
      af[mi] = *(const short8*)&As[(wm*64 + mi*16 + l15) * (KD + 8) + kk + quad*8];
    #pragma unroll
    for (int ni = 0; ni < 4; ++ni)
      bfg[ni] = *(const short8*)&Bs[(wn*64 + ni*16 + l15) * (KD + 8) + kk + quad*8];
    #pragma unroll
    for (int mi = 0; mi < 4; ++mi)
      #pragma unroll
      for (int ni = 0; ni < 4; ++ni)
        acc[mi][ni] = __builtin_amdgcn_mfma_f32_16x16x32_bf16(af[mi], bfg[ni], acc[mi][ni], 0, 0, 0);
  }

  #pragma unroll
  for (int mi = 0; mi < 4; ++mi){
    #pragma unroll
    for (int ni = 0; ni < 4; ++ni){
      int col = bn0 + wn*64 + ni*16 + l15;
      float tm = (EP == 1) ? tma_g[col] : 0.f;
      #pragma unroll
      for (int rg = 0; rg < 4; ++rg){
        int row = bm0 + wm*64 + mi*16 + quad*4 + rg;
        float v = acc[mi][ni][rg];
        if (EP == 1){
          float xv = x[(size_t)row * CC + col];
          float xp = ((row & (TT - 1)) == 0) ? 0.f : x[(size_t)row * CC + col - CC];
          v = xv + (xp - xv) * (v + tm);
        }
        OUT[(size_t)row * CC + col] = f2bf(v);
      }
    }
  }
}

// ---------------------------------------------------------------------------
// Fused elementwise + pair precompute, 4 tokens (2 pairs) per block.
// WMODE=1: w_t stored exact f32 in WF. WMODE=0: f16 -u fallback.
// ---------------------------------------------------------------------------
template<int WMODE>
__global__ __launch_bounds__(256) void k_elem(bf16u* __restrict__ K0,
    const bf16u* __restrict__ P1, const bf16u* __restrict__ P2,
    const bf16u* __restrict__ W2A,
    const float* __restrict__ kw2, const float* __restrict__ aw2,
    const float* __restrict__ maw2, const float* __restrict__ mkw2,
    const float* __restrict__ td,  const float* __restrict__ taa,
    const float* __restrict__ tma, const float* __restrict__ tmk,
    const float* __restrict__ faaaa,
    bf16u* __restrict__ KKN, bf16u* __restrict__ Bb, bf16u* __restrict__ UX,
    float* __restrict__ WF,
    bf16u* __restrict__ Rq, float* __restrict__ Dsc, float* __restrict__ RKsc){
  int n0 = blockIdx.x * 4, tid = threadIdx.x;
  __shared__ float at_l[4][16], mat_l[4][16], kt_l[4][16], mkt_l[4][16];
  {
    int grp = tid >> 6, q = tid & 63, tt = q >> 4, j = q & 15;
    if (grp == 0)      at_l[tt][j]  = bf2f(P1[(size_t)(n0+tt)*96 + 64 + j]);
    else if (grp == 1) mat_l[tt][j] = bf2f(P1[(size_t)(n0+tt)*96 + 80 + j]);
    else if (grp == 2) kt_l[tt][j]  = bf2f(P2[(size_t)(n0+tt)*32 + j]);
    else               mkt_l[tt][j] = bf2f(P2[(size_t)(n0+tt)*32 + 16 + j]);
  }
  __syncthreads();
  int c  = tid * 4;
  int h  = tid >> 4;       // head (16 lanes per head)
  int lg = tid & 15;

  float kkk[4][4], aa[4][4], mam[4][4], mkm[4][4];
  #pragma unroll
  for (int tt = 0; tt < 4; ++tt)
    #pragma unroll
    for (int i = 0; i < 4; ++i){ kkk[tt][i]=0; aa[tt][i]=0; mam[tt][i]=0; mkm[tt][i]=0; }

  #pragma unroll 4
  for (int j = 0; j < 16; ++j){
    float wk[4], wa[4], wm[4], wq[4];
    ld4f(kw2  + (size_t)j*CC + c, wk);
    ld4f(aw2  + (size_t)j*CC + c, wa);
    ld4f(maw2 + (size_t)j*CC + c, wm);
    ld4f(mkw2 + (size_t)j*CC + c, wq);
    #pragma unroll
    for (int tt = 0; tt < 4; ++tt){
      float s1 = kt_l[tt][j], s2 = at_l[tt][j], s3 = mat_l[tt][j], s4 = mkt_l[tt][j];
      #pragma unroll
      for (int i = 0; i < 4; ++i){
        kkk[tt][i] += s1 * wk[i];
        aa[tt][i]  += s2 * wa[i];
        mam[tt][i] += s3 * wm[i];
        mkm[tt][i] += s4 * wq[i];
      }
    }
  }

  float td4[4], taa4[4], tma4[4], tmk4[4], fa4[4];
  ld4f(td + c, td4); ld4f(taa + c, taa4); ld4f(tma + c, tma4); ld4f(tmk + c, tmk4);
  ld4f(faaaa + c, fa4);

#define ELEM_TOKEN(TT_, E_, A_, B_, KF_, WD_) do{ \
    float k0a[4]; ld4bf(K0 + (E_), k0a); \
    float w2a[4]; ld4bf(W2A + (E_), w2a); \
    float ssq = 0.f; \
    _Pragma("unroll") \
    for (int i = 0; i < 4; ++i){ A_[i] = k0a[i] + kkk[TT_][i]; ssq += A_[i]*A_[i]; } \
    ssq = red16(ssq); \
    float rinv = 1.f / fmaxf(sqrtf(ssq), 1e-12f); \
    float outw_[4]; \
    _Pragma("unroll") \
    for (int i = 0; i < 4; ++i){ \
      float z  = td4[i] + w2a[i]; \
      float nz = -z; \
      float sp = (nz > 15.f) ? nz : log1pf(expf(nz)); \
      float w  = -sp - 0.5f; \
      float av  = sigm(taa4[i] + aa[TT_][i]); \
      float mav = sigm(tma4[i] + mam[TT_][i]); \
      float mkv = sigm(tmk4[i] + mkm[TT_][i]); \
      A_[i] *= rinv; \
      B_[i]  = -A_[i] * av; \
      KF_[i] = k0a[i] * (mav + av * (1.f - mav)) * expf(w * mkv); \
      float ou = -expf(w); \
      outw_[i] = ou; \
      if (WMODE == 1) WD_[i] = __expf(ou);              /* exact f32 w_t */ \
      else            WD_[i] = __expf(hval(f2h(ou)));   /* f16-consistent */ \
    } \
    st4bf(Bb + (E_), B_); \
    st4bf(K0 + (E_), KF_); \
    if (WMODE == 1) *(float4*)(WF + (E_)) = make_float4(WD_[0], WD_[1], WD_[2], WD_[3]); \
    else            st4h(UX + (E_), outw_); \
  }while(0)

  #pragma unroll
  for (int p = 0; p < 2; ++p){
    const int ttE = 2*p, ttO = ttE + 1;
    size_t eE = (size_t)(n0 + ttE) * CC + c;
    size_t eO = eE + CC;
    float aE[4], bE[4], kfE[4], wdE[4];
    float aO[4], bO[4], kfO[4], wdO[4];
    ELEM_TOKEN(ttE, eE, aE, bE, kfE, wdE);
    ELEM_TOKEN(ttO, eO, aO, bO, kfO, wdO);
    st4bf(KKN + eE, aE);

    float rE[4], rO[4];
    ld4bf(Rq + eE, rE); ld4bf(Rq + eO, rO);

    // rk for k_post (before R is overwritten)
    float rkE = red16(rE[0]*kfE[0]*fa4[0] + rE[1]*kfE[1]*fa4[1]
                    + rE[2]*kfE[2]*fa4[2] + rE[3]*kfE[3]*fa4[3]);
    float rkO = red16(rO[0]*kfO[0]*fa4[0] + rO[1]*kfO[1]*fa4[1]
                    + rO[2]*kfO[2]*fa4[2] + rO[3]*kfO[3]*fa4[3]);

    // u1 over KKN odd row
    float c1 = red16(dot4(bE, aO));
    float d  = red16(dot4(kfE, aO));
    float u1[4];
    #pragma unroll
    for (int i = 0; i < 4; ++i) u1[i] = wdE[i]*aO[i] + c1*aE[i];
    st4bf(KKN + eO, u1);

    // q' even
    float cq = red16(dot4(bE, rE));
    float e1 = red16(dot4(kfE, rE));
    float qe[4];
    #pragma unroll
    for (int i = 0; i < 4; ++i) qe[i] = wdE[i]*rE[i] + cq*aE[i];
    st4bf(Rq + eE, qe);

    // z = M_{t+1} q_{t+1}; q' odd = M_t z
    float cz  = red16(dot4(bO, rO));
    float e21 = red16(dot4(kfO, rO));
    float z[4];
    #pragma unroll
    for (int i = 0; i < 4; ++i) z[i] = wdO[i]*rO[i] + cz*aO[i];
    float cy  = red16(dot4(bE, z));
    float e20 = red16(dot4(kfE, z));
    float qo[4];
    #pragma unroll
    for (int i = 0; i < 4; ++i) qo[i] = wdE[i]*z[i] + cy*aE[i];
    st4bf(Rq + eO, qo);

    if (lg == 0){
      size_t pr = (size_t)((n0 + ttE) >> 1);
      float4 dv; dv.x = d; dv.y = e1; dv.z = e20; dv.w = e21;
      *(float4*)(Dsc + (pr * HH + h) * 4) = dv;
      RKsc[(size_t)(n0 + ttE) * HH + h] = rkE;
      RKsc[(size_t)(n0 + ttO) * HH + h] = rkO;
    }
  }
#undef ELEM_TOKEN
}

// ---------------------------------------------------------------------------
// Recurrence v13 (r8-validated): 32-lane rows, 2 waves/SIMD, pair-fused,
// all 4 reductions vs base S, f32 decay (WMODE=1).
// ---------------------------------------------------------------------------
template<int WMODE>
__global__ __launch_bounds__(256) void k_rec(const bf16u* __restrict__ Qp,
                                             const bf16u* __restrict__ WT,
                                             const float* __restrict__ WF,
                                             const bf16u* __restrict__ KFt,
                                             const bf16u* __restrict__ Vt,
                                             const bf16u* __restrict__ Aa,
                                             const bf16u* __restrict__ Bv,
                                             const float* __restrict__ Dsc,
                                             bf16u* __restrict__ Y){
  const int p   = blockIdx.x;                 // 0..511
  const int g   = (p & 7) | ((p >> 6) << 3);  // (b,h) group 0..63, XCD-clustered
  const int oct = (p >> 3) & 7;               // row octet within the head
  const int b   = g >> 4;
  const int h   = g & 15;
  const int tid = threadIdx.x;
  const int l31 = tid & 31;                   // 32 lanes per row
  const int i   = oct * 8 + (tid >> 5);       // state row 0..63
  const size_t base0 = (size_t)(b * TT) * CC + h * HSS;
  const size_t colb  = base0 + l31 * 2;       // 2 cols per lane
  const size_t rowb  = base0 + i;
  const size_t dscb  = ((size_t)(b * (TT/2)) * HH + h) * 4;

  float S0 = 0.f, S1 = 0.f;                   // state cols (2*l31, 2*l31+1)

  unsigned int qEA,qOA,aEA,uOA,kEA,kOA,bEA,bOA,wEA,wOA; float2 fEA,fOA; unsigned short vEA,vOA; float4 dA;
  unsigned int qEB,qOB,aEB,uOB,kEB,kOB,bEB,bOB,wEB,wOB; float2 fEB,fOB; unsigned short vEB,vOB; float4 dB;
  unsigned int qEC,qOC,aEC,uOC,kEC,kOC,bEC,bOC,wEC,wOC; float2 fEC,fOC; unsigned short vEC,vOC; float4 dC;
  unsigned int qED,qOD,aED,uOD,kED,kOD,bED,bOD,wED,wOD; float2 fED,fOD; unsigned short vED,vOD; float4 dD;

#define PL(S, T_) do{ \
    size_t cE_ = colb + (size_t)(T_) * CC, cO_ = cE_ + CC; \
    qE##S = *(const unsigned int*)(Qp  + cE_); qO##S = *(const unsigned int*)(Qp  + cO_); \
    aE##S = *(const unsigned int*)(Aa  + cE_); uO##S = *(const unsigned int*)(Aa  + cO_); \
    kE##S = *(const unsigned int*)(KFt + cE_); kO##S = *(const unsigned int*)(KFt + cO_); \
    bE##S = *(const unsigned int*)(Bv  + cE_); bO##S = *(const unsigned int*)(Bv  + cO_); \
    if (WMODE == 1){ \
      fE##S = *(const float2*)(WF + cE_); fO##S = *(const float2*)(WF + cO_); \
    } else { \
      wE##S = *(const unsigned int*)(WT + cE_); wO##S = *(const unsigned int*)(WT + cO_); \
    } \
    vE##S = Vt[rowb + (size_t)(T_) * CC]; \
    vO##S = Vt[rowb + (size_t)(T_ + 1) * CC]; \
    d##S  = *(const float4*)(Dsc + dscb + (size_t)((T_) >> 1) * (HH*4)); \
  }while(0)

#define PSTEP(S, T_) do{ \
    float a0=bflo(aE##S), a1=bfhi(aE##S); \
    float u0=bflo(uO##S), u1=bfhi(uO##S); \
    float g0=bflo(qE##S), g1=bfhi(qE##S); \
    float o0=bflo(qO##S), o1=bfhi(qO##S); \
    float pE_ = fmaf(S1, a1, S0 * a0); \
    float pO_ = fmaf(S1, u1, S0 * u0); \
    float yE_ = fmaf(S1, g1, S0 * g0); \
    float yO_ = fmaf(S1, o1, S0 * o0); \
    pE_ = red32(pE_); \
    pO_ = red32(pO_); \
    yE_ = red32(yE_); \
    yO_ = red32(yO_); \
    float vEf = bf2f(vE##S), vOf = bf2f(vO##S); \
    float saE = pE_; \
    float saO = fmaf(d##S.x, vEf, pO_); \
    float ypE = fmaf(d##S.y, vEf, yE_); \
    float ypO = fmaf(d##S.z, vEf, fmaf(d##S.w, vOf, yO_)); \
    float k0=bflo(kE##S), k1=bfhi(kE##S); \
    float b0=bflo(bE##S), b1=bfhi(bE##S); \
    float w0, w1; \
    if (WMODE == 1){ w0=fE##S.x; w1=fE##S.y; } \
    else { w0=__expf(hlo(wE##S)); w1=__expf(hhi(wE##S)); } \
    S0 = fmaf(S0, w0, fmaf(saE, b0, vEf * k0)); \
    S1 = fmaf(S1, w1, fmaf(saE, b1, vEf * k1)); \
    float ko0=bflo(kO##S), ko1=bfhi(kO##S); \
    float bo0=bflo(bO##S), bo1=bfhi(bO##S); \
    float wo0, wo1; \
    if (WMODE == 1){ wo0=fO##S.x; wo1=fO##S.y; } \
    else { wo0=__expf(hlo(wO##S)); wo1=__expf(hhi(wO##S)); } \
    S0 = fmaf(S0, wo0, fmaf(saO, bo0, vOf * ko0)); \
    S1 = fmaf(S1, wo1, fmaf(saO, bo1, vOf * ko1)); \
    if (l31 == 0){ \
      Y[rowb + (size_t)(T_) * CC]     = f2bf(ypE); \
      Y[rowb + (size_t)(T_ + 1) * CC] = f2bf(ypO); \
    } \
  }while(0)

  PL(A, 0); PL(B, 2); PL(C, 4); PL(D, 6);
  for (int t = 0; t < TT; t += 8){
    PSTEP(A, t);
    if (t + 8  < TT) PL(A, t + 8);
    PSTEP(B, t + 2);
    if (t + 10 < TT) PL(B, t + 10);
    PSTEP(C, t + 4);
    if (t + 12 < TT) PL(C, t + 12);
    PSTEP(D, t + 6);
    if (t + 14 < TT) PL(D, t + 14);
  }
#undef PL
#undef PSTEP
}

// ---------------------------------------------------------------------------
// Post: GroupNorm + precomputed bonus rk*v + precomputed gate GV -> YG (bf16)
// ---------------------------------------------------------------------------
__global__ __launch_bounds__(256) void k_post(const bf16u* __restrict__ Y,
                                              const bf16u* __restrict__ Vt,
                                              const bf16u* __restrict__ GV,
                                              const float* __restrict__ lnw,
                                              const float* __restrict__ lnb,
                                              const float* __restrict__ RKsc,
                                              bf16u* __restrict__ YG){
  int n = blockIdx.x, tid = threadIdx.x;
  int c = tid * 4;
  size_t e = (size_t)n * CC + c;

  float ya[4]; ld4bf(Y + e, ya);
  float s = ya[0] + ya[1] + ya[2] + ya[3];
  s = red16(s);
  float mu = s * (1.f / 64.f);
  float d[4], vs = 0.f;
  #pragma unroll
  for (int i = 0; i < 4; ++i){ d[i] = ya[i] - mu; vs += d[i] * d[i]; }
  vs = red16(vs);
  float rstd = rsqrtf(vs * (1.f / 64.f) + EPSGN);

  float rk = RKsc[(size_t)n * HH + (tid >> 4)];

  float va[4]; ld4bf(Vt + e, va);
  float lw4[4], lb4[4];
  ld4f(lnw + c, lw4); ld4f(lnb + c, lb4);
  float g[4]; ld4bf(GV + e, g);
  float o[4];
  #pragma unroll
  for (int i = 0; i < 4; ++i){
    float yn = d[i] * rstd * lw4[i] + lb4[i] + rk * va[i];
    o[i] = yn * g[i];
  }
  st4bf(YG + e, o);
}

// ---------------------------------------------------------------------------
extern "C" void kernel_launch(void* const* d_in, const int* in_sizes, int n_in,
                              void* d_out, int out_size, void* d_ws, size_t ws_size,
                              hipStream_t stream){
  (void)in_sizes; (void)n_in; (void)out_size;
  const float* x        = (const float*)d_in[0];
  const float* tmx      = (const float*)d_in[1];
  const float* tmaa     = (const float*)d_in[2];
  const float* maa_w1   = (const float*)d_in[3];
  const float* maa_w2   = (const float*)d_in[4];
  const float* decay_w1 = (const float*)d_in[5];
  const float* decay_w2 = (const float*)d_in[6];
  const float* aaa_w1   = (const float*)d_in[7];
  const float* aaa_w2   = (const float*)d_in[8];
  const float* kkk_w1   = (const float*)d_in[9];
  const float* kkk_w2   = (const float*)d_in[10];
  const float* gate_w1  = (const float*)d_in[11];
  const float* gate_w2  = (const float*)d_in[12];
  const float* ma_w1    = (const float*)d_in[13];
  const float* ma_w2    = (const float*)d_in[14];
  const float* mk_w1    = (const float*)d_in[15];
  const float* mk_w2    = (const float*)d_in[16];
  const float* t_decay  = (const float*)d_in[17];
  const float* t_faaaa  = (const float*)d_in[18];
  const float* t_aaaaa  = (const float*)d_in[19];
  const float* t_misc_a = (const float*)d_in[20];
  const float* t_misc_k = (const float*)d_in[21];
  const float* Wr       = (const float*)d_in[22];
  const float* Wk       = (const float*)d_in[23];
  const float* Wv       = (const float*)d_in[24];
  const float* Wo       = (const float*)d_in[25];
  const float* ln_w     = (const float*)d_in[26];
  const float* ln_b     = (const float*)d_in[27];

  // Slot map (8MiB bf16 each), 56 MiB slots + smalls at 56..60 MiB.
  // 60..76 MiB region is time-shared:
  //   phase A (steps 0-6):  WrB@60 WkB@62 WvB@64 W1B@66 W2TB@67  (bf16 weights)
  //   phase B (steps 7-8):  WF (f32 w_t, 16 MiB) — k_elem overwrites phase A
  //   phase C (steps 9-11): WoB@60 (k_wconv2, after k_rec; WF dead)
  bf16u* bw  = (bf16u*)d_ws;
  bf16u* MIX = bw + 0*SLOT;
  bf16u* X0  = bw + 0*SLOT;
  bf16u* KKN = bw + 0*SLOT;
  bf16u* YG  = bw + 0*SLOT;
  bf16u* X1  = bw + 1*SLOT;
  bf16u* Bb  = bw + 1*SLOT;
  bf16u* GV  = bw + 1*SLOT;
  bf16u* X2  = bw + 2*SLOT;
  bf16u* UX  = bw + 2*SLOT;
  bf16u* X3  = bw + 3*SLOT;
  bf16u* W2A = bw + 3*SLOT;
  bf16u* Yb  = bw + 3*SLOT;
  bf16u* R   = bw + 4*SLOT;   // becomes q'
  bf16u* K0  = bw + 5*SLOT;   // becomes KF
  bf16u* V   = bw + 6*SLOT;
  char*  wsb = (char*)d_ws;
  bf16u* LO  = (bf16u*)(wsb + (56ull<<20));   // [N,128] bf16, 1 MiB
  bf16u* GT  = (bf16u*)(wsb + (57ull<<20));   // [N,128] bf16, 1 MiB
  bf16u* P1  = (bf16u*)(wsb + (58ull<<20));   // [N,96]  bf16 (dt|at|ma)
  bf16u* P2  = (bf16u*)(wsb + (58ull<<20) + (768ull<<10)); // [N,32] bf16
  float* Dsc = (float*)(wsb + (59ull<<20));   // [N/2,16] float4, 512 KiB
  float* RKsc= (float*)(wsb + (59ull<<20) + (512ull<<10)); // [N,16] f32, 256 KiB
  float* WF  = (float*)(wsb + (60ull<<20));   // [N,CC] f32 w_t, 16 MiB
  bf16u* WrB = (bf16u*)(wsb + (60ull<<20));
  bf16u* WkB = (bf16u*)(wsb + (62ull<<20));
  bf16u* WvB = (bf16u*)(wsb + (64ull<<20));
  bf16u* W1B = (bf16u*)(wsb + (66ull<<20));   // 384 rows x 1024, 0.75 MiB
  bf16u* W2TB= (bf16u*)(wsb + (67ull<<20));   // [1024][192], 0.375 MiB
  bf16u* WoB = (bf16u*)(wsb + (60ull<<20));   // phase C, aliases WrB/WF
  const bool fast = ws_size >= (77ull<<20);

  if (fast){
    // 0. weight pre-conversion (bf16; identical RNE rounding to old in-GEMM)
    k_wconv1<<<3648, 256, 0, stream>>>(Wr, Wk, Wv, maa_w1, gate_w1, decay_w1,
                                       aaa_w1, ma_w1, kkk_w1, mk_w1,
                                       maa_w2, decay_w2,
                                       WrB, WkB, WvB, W1B, W2TB);
    // 1. mix
    k_prep<<<4096, 256, 0, stream>>>(x, tmx, MIX);
    // 2. lo = tanh(mix @ maa_w1^T)
    k_gemm_mfma_b<true><<<dim3(1,32),256,0,stream>>>(MIX, W1B, LO, 128, CC, 128);
    // 3. xm[g] = x + xx*(lo_g @ maa_w2_g + tmaa_g)
    bf16u* XMs[4] = {X0, X1, X2, X3};
    for (int g = 0; g < 4; ++g)
      k_gemm_nn_b<32,1><<<dim3(8,32),256,0,stream>>>(LO + g*32, 128, W2TB, g*32,
                                                     XMs[g], x, tmaa + (size_t)g*CC);
    // 4. big projections
    k_gemm_mfma_b<true><<<dim3(8,32),256,0,stream>>>(X0, WrB, R,  CC, CC, 0);
    k_gemm_mfma_b<true><<<dim3(8,32),256,0,stream>>>(X2, WkB, K0, CC, CC, 0);
    k_gemm_mfma_b<true><<<dim3(8,32),256,0,stream>>>(X3, WvB, V,  CC, CC, 0);
    // 5. first-stage LoRA projections
    k_gemm_mfma_b<true><<<dim3(1,32),256,0,stream>>>(X0, W1B + 128*1024, GT, 128, CC, 128);
    k_gemm_mfma_b<true><<<dim3(1,32),256,0,stream>>>(X1, W1B + 256*1024, P1, 96,  CC, 64);
    k_gemm_mfma_b<true><<<dim3(1,32),256,0,stream>>>(X2, W1B + 352*1024, P2, 32,  CC, 16);
    // 6. W2A = P1[:, :64] @ decay_w2 (last read of W2TB before WF overwrites)
    k_gemm_nn_b<64,0><<<dim3(8,32),256,0,stream>>>(P1, 96, W2TB, 128, W2A, nullptr, nullptr);
    // 7. fused elementwise + pair precompute (writes WF over phase-A weights)
    k_elem<1><<<1024, 256, 0, stream>>>(K0, P1, P2, W2A,
                                        kkk_w2, aaa_w2, ma_w2, mk_w2,
                                        t_decay, t_aaaaa, t_misc_a, t_misc_k, t_faaaa,
                                        KKN, Bb, UX, WF, R, Dsc, RKsc);
    // 8. delta-rule recurrence (r8-validated v13)
    k_rec<1><<<512, 256, 0, stream>>>(R, UX, WF, K0, V, KKN, Bb, Dsc, Yb);
    // 8b. Wo -> bf16 into now-dead WF region
    k_wconv2<<<1024, 256, 0, stream>>>(Wo, WoB);
    // 9. GV = GT @ gate_w2 (legacy f32-B path; gate_w2's bf16 copy would
    //    collide with WF, not worth a 4th phase)
    k_gemm_nn<128,0><<<dim3(8,32),256,0,stream>>>(GT, 128, gate_w2, GV, nullptr, nullptr);
    // 10. groupnorm + bonus + gate
    k_post<<<4096, 256, 0, stream>>>(Yb, V, GV, ln_w, ln_b, RKsc, YG);
    // 11. out = yg @ Wo^T -> f32
    k_gemm_mfma_b<false><<<dim3(8,32),256,0,stream>>>(YG, WoB, d_out, CC, CC, 0);
  } else {
    // Fallback: exact r8 sequence (f32 weights in-GEMM, f16 -u decay).
    k_prep<<<4096, 256, 0, stream>>>(x, tmx, MIX);
    k_gemm_mfma<true><<<dim3(1,32),256,0,stream>>>(MIX, maa_w1, maa_w1, maa_w1,
                                                   128, 128, LO, 128, CC, 128);
    bf16u* XMs[4] = {X0, X1, X2, X3};
    for (int g = 0; g < 4; ++g)
      k_gemm_nn<32,1><<<dim3(8,32),256,0,stream>>>(LO + g*32, 128,
                                                   maa_w2 + (size_t)g*32*CC,
                                                   XMs[g], x, tmaa + (size_t)g*CC);
    k_gemm_mfma<true><<<dim3(8,32),256,0,stream>>>(X0, Wr, Wr, Wr, CC, CC, R,  CC, CC, 0);
    k_gemm_mfma<true><<<dim3(8,32),256,0,stream>>>(X2, Wk, Wk, Wk, CC, CC, K0, CC, CC, 0);
    k_gemm_mfma<true><<<dim3(8,32),256,0,stream>>>(X3, Wv, Wv, Wv, CC, CC, V,  CC, CC, 0);
    k_gemm_mfma<true><<<dim3(1,32),256,0,stream>>>(X0, gate_w1, gate_w1, gate_w1,
                                                   128, 128, GT, 128, CC, 128);
    k_gemm_mfma<true><<<dim3(1,32),256,0,stream>>>(X1, decay_w1, aaa_w1, ma_w1,
                                                   64, 80, P1, 96, CC, 64);
    k_gemm_mfma<true><<<dim3(1,32),256,0,stream>>>(X2, kkk_w1, mk_w1, mk_w1,
                                                   16, 32, P2, 32, CC, 16);
    k_gemm_nn<64,0><<<dim3(8,32),256,0,stream>>>(P1, 96, decay_w2, W2A, nullptr, nullptr);
    k_elem<0><<<1024, 256, 0, stream>>>(K0, P1, P2, W2A,
                                        kkk_w2, aaa_w2, ma_w2, mk_w2,
                                        t_decay, t_aaaaa, t_misc_a, t_misc_k, t_faaaa,
                                        KKN, Bb, UX, WF, R, Dsc, RKsc);
    k_rec<0><<<512, 256, 0, stream>>>(R, UX, WF, K0, V, KKN, Bb, Dsc, Yb);
    k_gemm_nn<128,0><<<dim3(8,32),256,0,stream>>>(GT, 128, gate_w2, GV, nullptr, nullptr);
    k_post<<<4096, 256, 0, stream>>>(Yb, V, GV, ln_w, ln_b, RKsc, YG);
    k_gemm_mfma<false><<<dim3(8,32),256,0,stream>>>(YG, Wo, Wo, Wo, CC, CC, d_out, CC, CC, 0);
  }
}

// Round 10
// 677.191 us; speedup vs baseline: 1.4489x; 1.0579x over previous
//
#include <hip/hip_runtime.h>
#include <cstdint>
#include <cstddef>

// Problem constants
#define BB   4
#define TT   1024
#define CC   1024
#define HH   16
#define HSS  64
#define NNtok 4096            // B*T
#define EPSGN 0.00064f
#define W2TS 192              // W2TB col count (maa_w2 128 | decay_w2 64)

typedef unsigned short bf16u;
typedef __attribute__((ext_vector_type(8))) short short8;
typedef __attribute__((ext_vector_type(4))) float f32x4;
#define SLOT 4194304ull       // elements per 8MiB bf16 slot (= NNtok*CC)

__device__ __forceinline__ float bf2f(bf16u u){
  union { unsigned int i; float f; } cv; cv.i = ((unsigned int)u) << 16; return cv.f;
}
__device__ __forceinline__ unsigned short f2bfbits(unsigned int x){
  return (unsigned short)((x + 0x7fffu + ((x >> 16) & 1u)) >> 16);   // RNE
}
__device__ __forceinline__ bf16u f2bf(float f){
  union { float f; unsigned int i; } cv; cv.f = f;
  return f2bfbits(cv.i);
}
__device__ __forceinline__ void ld4bf(const bf16u* p, float* o){
  ushort4 u = *reinterpret_cast<const ushort4*>(p);
  o[0]=bf2f(u.x); o[1]=bf2f(u.y); o[2]=bf2f(u.z); o[3]=bf2f(u.w);
}
__device__ __forceinline__ void st4bf(bf16u* p, const float* v){
  ushort4 u; u.x=f2bf(v[0]); u.y=f2bf(v[1]); u.z=f2bf(v[2]); u.w=f2bf(v[3]);
  *reinterpret_cast<ushort4*>(p) = u;
}
__device__ __forceinline__ unsigned short f2h(float f){
  union { _Float16 h; unsigned short s; } c; c.h = (_Float16)f; return c.s;
}
__device__ __forceinline__ void st4h(bf16u* p, const float* v){
  ushort4 u; u.x=f2h(v[0]); u.y=f2h(v[1]); u.z=f2h(v[2]); u.w=f2h(v[3]);
  *reinterpret_cast<ushort4*>(p) = u;
}
__device__ __forceinline__ void ld4f(const float* p, float* o){
  float4 v = *reinterpret_cast<const float4*>(p);
  o[0]=v.x; o[1]=v.y; o[2]=v.z; o[3]=v.w;
}
__device__ __forceinline__ float sigm(float x){ return 1.f / (1.f + expf(-x)); }

// unpack helpers
__device__ __forceinline__ float bflo(unsigned int u){
  union { unsigned int i; float f; } c; c.i = u << 16; return c.f;
}
__device__ __forceinline__ float bfhi(unsigned int u){
  union { unsigned int i; float f; } c; c.i = u & 0xffff0000u; return c.f;
}
__device__ __forceinline__ float hlo(unsigned int u){
  union { unsigned short s; _Float16 h; } c; c.s = (unsigned short)(u & 0xffffu); return (float)c.h;
}
__device__ __forceinline__ float hhi(unsigned int u){
  union { unsigned short s; _Float16 h; } c; c.s = (unsigned short)(u >> 16); return (float)c.h;
}
__device__ __forceinline__ float hval(unsigned short s){
  union { unsigned short s; _Float16 h; } c; c.s = s; return (float)c.h;
}
__device__ __forceinline__ float dot4(const float* x, const float* y){
  return (x[0]*y[0] + x[1]*y[1]) + (x[2]*y[2] + x[3]*y[3]);
}

// 16-lane sum via DPP. old=0 + bound_ctrl=1 folds to single v_add_f32_dpp.
template<int CTRL>
__device__ __forceinline__ float dpp_add(float v){
  union { float f; int i; } a, b;
  a.f = v;
  b.i = __builtin_amdgcn_update_dpp(0, a.i, CTRL, 0xF, 0xF, true);
  return v + b.f;
}
__device__ __forceinline__ float red16(float v){
  v = dpp_add<0xB1>(v);    // quad_perm [1,0,3,2]  (xor 1)
  v = dpp_add<0x4E>(v);    // quad_perm [2,3,0,1]  (xor 2)
  v = dpp_add<0x124>(v);   // row_ror:4
  v = dpp_add<0x128>(v);   // row_ror:8
  return v;
}
// 32-lane sum in all lanes: red16 then exchange complementary 16-rows
// between two DISTINCT-register copies (laundered; rounds 1/3 failed when
// regalloc coalesced both operands into one phys reg -> self-swap).
__device__ __forceinline__ float red32(float v){
  v = red16(v);
  union { float f; int i; } x, y;
  x.f = v; y.f = v;
  asm volatile("" : "+v"(y.i));   // distinct-vreg launder
  asm volatile("v_permlane16_swap_b32 %0, %1" : "+v"(x.i), "+v"(y.i));
  return x.f + y.f;
}

// ---------------------------------------------------------------------------
// mix = x + (x[t-1]-x[t])*time_maa_x  (x[-1]=0), stored bf16
// ---------------------------------------------------------------------------
__global__ __launch_bounds__(256) void k_prep(const float* __restrict__ x,
                                              const float* __restrict__ tmx,
                                              bf16u* __restrict__ MIX){
  int e = (blockIdx.x * 256 + threadIdx.x) * 4;
  int n = e >> 10;
  int c = e & (CC - 1);
  int t = n & (TT - 1);
  float xf[4]; ld4f(x + e, xf);
  float pf[4] = {0.f, 0.f, 0.f, 0.f};
  if (t > 0) ld4f(x + e - CC, pf);
  float tm[4]; ld4f(tmx + c, tm);
  float mv[4];
  #pragma unroll
  for (int i = 0; i < 4; ++i) mv[i] = xf[i] + (pf[i] - xf[i]) * tm[i];
  st4bf(MIX + e, mv);
}

// ---------------------------------------------------------------------------
// Weight pre-conversion (once per call, ~5us). See r9 notes; outputs live in
// WF region (60..67.4 MiB), dead before k_elem overwrites it at step 7.
// ---------------------------------------------------------------------------
__global__ __launch_bounds__(256) void k_wconv1(
    const float* __restrict__ Wr, const float* __restrict__ Wk,
    const float* __restrict__ Wv,
    const float* __restrict__ maa_w1, const float* __restrict__ gate_w1,
    const float* __restrict__ decay_w1, const float* __restrict__ aaa_w1,
    const float* __restrict__ ma_w1, const float* __restrict__ kkk_w1,
    const float* __restrict__ mk_w1,
    const float* __restrict__ maa_w2, const float* __restrict__ decay_w2,
    bf16u* __restrict__ WrB, bf16u* __restrict__ WkB, bf16u* __restrict__ WvB,
    bf16u* __restrict__ W1B, bf16u* __restrict__ W2TB){
  int blk = blockIdx.x, tid = threadIdx.x;
  if (blk < 3072){
    const float* src = (blk < 1024) ? Wr : (blk < 2048) ? Wk : Wv;
    bf16u* dst = (blk < 1024) ? WrB : (blk < 2048) ? WkB : WvB;
    size_t e = (size_t)(blk & 1023) * 1024 + (size_t)tid * 4;
    float v[4]; ld4f(src + e, v);
    st4bf(dst + e, v);
  } else if (blk < 3456){
    int row = blk - 3072;
    const float* src;
    if      (row < 128) src = maa_w1   + (size_t)row * 1024;
    else if (row < 256) src = gate_w1  + (size_t)(row - 128) * 1024;
    else if (row < 320) src = decay_w1 + (size_t)(row - 256) * 1024;
    else if (row < 336) src = aaa_w1   + (size_t)(row - 320) * 1024;
    else if (row < 352) src = ma_w1    + (size_t)(row - 336) * 1024;
    else if (row < 368) src = kkk_w1   + (size_t)(row - 352) * 1024;
    else                src = mk_w1    + (size_t)(row - 368) * 1024;
    float v[4]; ld4f(src + tid * 4, v);
    st4bf(W1B + (size_t)row * 1024 + tid * 4, v);
  } else {
    int j = blk - 3456;   // 0..191
    const float* src = (j < 128) ? (maa_w2 + (size_t)j * 1024)
                                 : (decay_w2 + (size_t)(j - 128) * 1024);
    for (int c = tid; c < 1024; c += 256)
      W2TB[(size_t)c * W2TS + j] = f2bf(src[c]);
  }
}

// Wo -> bf16 and gate_w2 -> transposed bf16 GW2T [1024][128]; runs AFTER
// k_rec into the then-dead WF region. GV then uses the fast mfma_b path
// (bitwise-identical: same RNE convert, same MFMA accumulation order).
__global__ __launch_bounds__(256) void k_wconv2(const float* __restrict__ Wo,
                                                const float* __restrict__ gate_w2,
                                                bf16u* __restrict__ WoB,
                                                bf16u* __restrict__ GW2T){
  int blk = blockIdx.x, tid = threadIdx.x;
  if (blk < 1024){
    size_t e = ((size_t)blk * 256 + tid) * 4;
    float v[4]; ld4f(Wo + e, v);
    st4bf(WoB + e, v);
  } else {
    int c = (blk - 1024) * 2 + (tid >> 7);
    int j = tid & 127;
    GW2T[(size_t)c * 128 + j] = f2bf(gate_w2[(size_t)j * CC + c]);
  }
}

// ---------------------------------------------------------------------------
// MFMA NT GEMM, bf16-W, SOFTWARE-PIPELINED (r10): register prefetch of the
// next K-tile + ping-pong LDS -> global-load latency overlaps MFMA compute,
// and barriers drop from 2 to 1 per K-iter. Rationale: at 1 block/CU these
// GEMMs ran load->barrier->compute serially, exposing full L2/HBM latency
// per iteration (same stall disease as r7's k_rec; same cure family).
// ---------------------------------------------------------------------------
template<bool OB>
__global__ __launch_bounds__(256) void k_gemm_mfma_b(const bf16u* __restrict__ X,
                                                     const bf16u* __restrict__ WB,
                                                     void* __restrict__ OUTv,
                                                     int Nd, int Kd, int act_n){
  __shared__ short As[2][128 * 40];
  __shared__ short Bs[2][128 * 40];
  const int tid  = threadIdx.x;
  const int lane = tid & 63;
  const int wv   = tid >> 6;
  const int wm   = wv >> 1, wn = wv & 1;
  const int bn0  = blockIdx.x * 128;
  const int bm0  = blockIdx.y * 128;
  const int l15  = lane & 15;
  const int quad = lane >> 4;

  f32x4 acc[4][4];
  #pragma unroll
  for (int mi = 0; mi < 4; ++mi)
    #pragma unroll
    for (int ni = 0; ni < 4; ++ni)
      #pragma unroll
      for (int rg = 0; rg < 4; ++rg) acc[mi][ni][rg] = 0.f;

  const int r    = tid >> 1;
  const int half = (tid & 1) * 16;

  const bf16u* wsrc = (bn0 + r < Nd) ? WB + (size_t)(bn0 + r) * Kd : nullptr;
  const bf16u* xsrc = X + (size_t)(bm0 + r) * Kd;

  uint4 xa = *(const uint4*)(xsrc + half);
  uint4 xb = *(const uint4*)(xsrc + half + 8);
  uint4 wa = make_uint4(0,0,0,0), wb = wa;
  if (wsrc){
    wa = *(const uint4*)(wsrc + half);
    wb = *(const uint4*)(wsrc + half + 8);
  }
  *(uint4*)&As[0][r * 40 + half]     = xa;
  *(uint4*)&As[0][r * 40 + half + 8] = xb;
  *(uint4*)&Bs[0][r * 40 + half]     = wa;
  *(uint4*)&Bs[0][r * 40 + half + 8] = wb;
  __syncthreads();

  const int NK = Kd >> 5;
  for (int k = 0; k < NK; ++k){
    const int cur = k & 1;
    if (k + 1 < NK){                    // issue next-tile loads BEFORE compute
      int k0 = (k + 1) << 5;
      xa = *(const uint4*)(xsrc + k0 + half);
      xb = *(const uint4*)(xsrc + k0 + half + 8);
      if (wsrc){
        wa = *(const uint4*)(wsrc + k0 + half);
        wb = *(const uint4*)(wsrc + k0 + half + 8);
      }
    }
    short8 af[4], bfg[4];
    #pragma unroll
    for (int mi = 0; mi < 4; ++mi)
      af[mi] = *(const short8*)&As[cur][(wm*64 + mi*16 + l15) * 40 + quad*8];
    #pragma unroll
    for (int ni = 0; ni < 4; ++ni)
      bfg[ni] = *(const short8*)&Bs[cur][(wn*64 + ni*16 + l15) * 40 + quad*8];
    #pragma unroll
    for (int mi = 0; mi < 4; ++mi)
      #pragma unroll
      for (int ni = 0; ni < 4; ++ni)
        acc[mi][ni] = __builtin_amdgcn_mfma_f32_16x16x32_bf16(af[mi], bfg[ni], acc[mi][ni], 0, 0, 0);
    if (k + 1 < NK){
      const int nxt = cur ^ 1;
      *(uint4*)&As[nxt][r * 40 + half]     = xa;
      *(uint4*)&As[nxt][r * 40 + half + 8] = xb;
      *(uint4*)&Bs[nxt][r * 40 + half]     = wa;
      *(uint4*)&Bs[nxt][r * 40 + half + 8] = wb;
      __syncthreads();
    }
  }

  #pragma unroll
  for (int mi = 0; mi < 4; ++mi){
    #pragma unroll
    for (int ni = 0; ni < 4; ++ni){
      int col = bn0 + wn*64 + ni*16 + l15;
      if (col >= Nd) continue;
      #pragma unroll
      for (int rg = 0; rg < 4; ++rg){
        int row = bm0 + wm*64 + mi*16 + quad*4 + rg;
        float v = acc[mi][ni][rg];
        if (col < act_n) v = tanhf(v);
        if (OB) ((bf16u*)OUTv)[(size_t)row * Nd + col] = f2bf(v);
        else    ((float*)OUTv)[(size_t)row * Nd + col] = v;
      }
    }
  }
}

// ---------------------------------------------------------------------------
// MFMA NN GEMM, pre-transposed bf16 B (single-staging; K fits in LDS).
// ---------------------------------------------------------------------------
template<int KD, int EP>
__global__ __launch_bounds__(256) void k_gemm_nn_b(const bf16u* __restrict__ A, int lda,
                                                   const bf16u* __restrict__ BT, int koff,
                                                   bf16u* __restrict__ OUT,
                                                   const float* __restrict__ x,
                                                   const float* __restrict__ tma_g){
  __shared__ short As[128 * (KD + 8)];
  __shared__ short Bs[128 * (KD + 8)];
  const int tid  = threadIdx.x;
  const int lane = tid & 63;
  const int wv   = tid >> 6;
  const int wm   = wv >> 1, wn = wv & 1;
  const int bn0  = blockIdx.x * 128;
  const int bm0  = blockIdx.y * 128;
  const int l15  = lane & 15;
  const int quad = lane >> 4;

  for (int idx = tid; idx < 128 * (KD / 8); idx += 256){
    int r  = idx / (KD / 8);
    int kc = (idx % (KD / 8)) * 8;
    *(uint4*)&As[r * (KD + 8) + kc] =
        *(const uint4*)(A + (size_t)(bm0 + r) * lda + kc);
  }
  for (int idx = tid; idx < 128 * (KD / 8); idx += 256){
    int cc_ = idx / (KD / 8);
    int kc  = (idx % (KD / 8)) * 8;
    *(uint4*)&Bs[cc_ * (KD + 8) + kc] =
        *(const uint4*)(BT + (size_t)(bn0 + cc_) * W2TS + koff + kc);
  }
  __syncthreads();

  f32x4 acc[4][4];
  #pragma unroll
  for (int mi = 0; mi < 4; ++mi)
    #pragma unroll
    for (int ni = 0; ni < 4; ++ni)
      #pragma unroll
      for (int rg = 0; rg < 4; ++rg) acc[mi][ni][rg] = 0.f;

  #pragma unroll
  for (int kk = 0; kk < KD; kk += 32){
    short8 af[4], bfg[4];
    #pragma unroll
    for (int mi = 0; mi < 4; ++mi)
      af[mi] = *(const short8*)&As[(wm*64 + mi*16 + l15) * (KD + 8) + kk + quad*8];
    #pragma unroll
    for (int ni = 0; ni < 4; ++ni)
      bfg[ni] = *(const short8*)&Bs[(wn*64 + ni*16 + l15) * (KD + 8) + kk + quad*8];
    #pragma unroll
    for (int mi = 0; mi < 4; ++mi)
      #pragma unroll
      for (int ni = 0; ni < 4; ++ni)
        acc[mi][ni] = __builtin_amdgcn_mfma_f32_16x16x32_bf16(af[mi], bfg[ni], acc[mi][ni], 0, 0, 0);
  }

  #pragma unroll
  for (int mi = 0; mi < 4; ++mi){
    #pragma unroll
    for (int ni = 0; ni < 4; ++ni){
      int col = bn0 + wn*64 + ni*16 + l15;
      float tm = (EP == 1) ? tma_g[col] : 0.f;
      #pragma unroll
      for (int rg = 0; rg < 4; ++rg){
        int row = bm0 + wm*64 + mi*16 + quad*4 + rg;
        float v = acc[mi][ni][rg];
        if (EP == 1){
          float xv = x[(size_t)row * CC + col];
          float xp = ((row & (TT - 1)) == 0) ? 0.f : x[(size_t)row * CC + col - CC];
          v = xv + (xp - xv) * (v + tm);
        }
        OUT[(size_t)row * CC + col] = f2bf(v);
      }
    }
  }
}

// ---------------------------------------------------------------------------
// LEGACY f32-W GEMMs (fallback path only)
// ---------------------------------------------------------------------------
template<bool OB>
__global__ __launch_bounds__(256) void k_gemm_mfma(const bf16u* __restrict__ X,
                                                   const float* __restrict__ Wa,
                                                   const float* __restrict__ Wb,
                                                   const float* __restrict__ Wc,
                                                   int na, int nab,
                                                   void* __restrict__ OUTv,
                                                   int Nd, int Kd, int act_n){
  __shared__ short As[128 * 40];
  __shared__ short Bs[128 * 40];
  const int tid  = threadIdx.x;
  const int lane = tid & 63;
  const int wv   = tid >> 6;
  const int wm   = wv >> 1, wn = wv & 1;
  const int bn0  = blockIdx.x * 128;
  const int bm0  = blockIdx.y * 128;
  const int l15  = lane & 15;
  const int quad = lane >> 4;

  f32x4 acc[4][4];
  #pragma unroll
  for (int mi = 0; mi < 4; ++mi)
    #pragma unroll
    for (int ni = 0; ni < 4; ++ni)
      #pragma unroll
      for (int rg = 0; rg < 4; ++rg) acc[mi][ni][rg] = 0.f;

  const int r    = tid >> 1;
  const int half = (tid & 1) * 16;

  int rr = bn0 + r;
  const float* wsrc = nullptr;
  if (rr < na)        wsrc = Wa + (size_t)rr * Kd;
  else if (rr < nab)  wsrc = Wb + (size_t)(rr - na) * Kd;
  else if (rr < Nd)   wsrc = Wc + (size_t)(rr - nab) * Kd;
  const bf16u* xsrc = X + (size_t)(bm0 + r) * Kd;

  for (int k0 = 0; k0 < Kd; k0 += 32){
    uint4 xa = *(const uint4*)(xsrc + k0 + half);
    uint4 xb = *(const uint4*)(xsrc + k0 + half + 8);
    uint4 w0 = make_uint4(0,0,0,0), w1 = w0, w2 = w0, w3 = w0;
    if (wsrc){
      w0 = *(const uint4*)(wsrc + k0 + half);
      w1 = *(const uint4*)(wsrc + k0 + half + 4);
      w2 = *(const uint4*)(wsrc + k0 + half + 8);
      w3 = *(const uint4*)(wsrc + k0 + half + 12);
    }
    union { unsigned short s[8]; uint4 v; } p0, p1;
    p0.s[0]=f2bfbits(w0.x); p0.s[1]=f2bfbits(w0.y); p0.s[2]=f2bfbits(w0.z); p0.s[3]=f2bfbits(w0.w);
    p0.s[4]=f2bfbits(w1.x); p0.s[5]=f2bfbits(w1.y); p0.s[6]=f2bfbits(w1.z); p0.s[7]=f2bfbits(w1.w);
    p1.s[0]=f2bfbits(w2.x); p1.s[1]=f2bfbits(w2.y); p1.s[2]=f2bfbits(w2.z); p1.s[3]=f2bfbits(w2.w);
    p1.s[4]=f2bfbits(w3.x); p1.s[5]=f2bfbits(w3.y); p1.s[6]=f2bfbits(w3.z); p1.s[7]=f2bfbits(w3.w);

    *(uint4*)&As[r * 40 + half]     = xa;
    *(uint4*)&As[r * 40 + half + 8] = xb;
    *(uint4*)&Bs[r * 40 + half]     = p0.v;
    *(uint4*)&Bs[r * 40 + half + 8] = p1.v;
    __syncthreads();

    short8 af[4], bfg[4];
    #pragma unroll
    for (int mi = 0; mi < 4; ++mi)
      af[mi] = *(const short8*)&As[(wm*64 + mi*16 + l15) * 40 + quad*8];
    #pragma unroll
    for (int ni = 0; ni < 4; ++ni)
      bfg[ni] = *(const short8*)&Bs[(wn*64 + ni*16 + l15) * 40 + quad*8];
    #pragma unroll
    for (int mi = 0; mi < 4; ++mi)
      #pragma unroll
      for (int ni = 0; ni < 4; ++ni)
        acc[mi][ni] = __builtin_amdgcn_mfma_f32_16x16x32_bf16(af[mi], bfg[ni], acc[mi][ni], 0, 0, 0);
    __syncthreads();
  }

  #pragma unroll
  for (int mi = 0; mi < 4; ++mi){
    #pragma unroll
    for (int ni = 0; ni < 4; ++ni){
      int col = bn0 + wn*64 + ni*16 + l15;
      if (col >= Nd) continue;
      #pragma unroll
      for (int rg = 0; rg < 4; ++rg){
        int row = bm0 + wm*64 + mi*16 + quad*4 + rg;
        float v = acc[mi][ni][rg];
        if (col < act_n) v = tanhf(v);
        if (OB) ((bf16u*)OUTv)[(size_t)row * Nd + col] = f2bf(v);
        else    ((float*)OUTv)[(size_t)row * Nd + col] = v;
      }
    }
  }
}

template<int KD, int EP>
__global__ __launch_bounds__(256) void k_gemm_nn(const bf16u* __restrict__ A, int lda,
                                                 const float* __restrict__ B,
                                                 bf16u* __restrict__ OUT,
                                                 const float* __restrict__ x,
                                                 const float* __restrict__ tma_g){
  __shared__ short As[128 * (KD + 8)];
  __shared__ short Bs[128 * (KD + 8)];
  const int tid  = threadIdx.x;
  const int lane = tid & 63;
  const int wv   = tid >> 6;
  const int wm   = wv >> 1, wn = wv & 1;
  const int bn0  = blockIdx.x * 128;
  const int bm0  = blockIdx.y * 128;
  const int l15  = lane & 15;
  const int quad = lane >> 4;

  for (int idx = tid; idx < 128 * (KD / 8); idx += 256){
    int r  = idx / (KD / 8);
    int kc = (idx % (KD / 8)) * 8;
    *(uint4*)&As[r * (KD + 8) + kc] =
        *(const uint4*)(A + (size_t)(bm0 + r) * lda + kc);
  }
  for (int idx = tid; idx < KD * 128; idx += 256){
    int k = idx >> 7, c = idx & 127;
    Bs[c * (KD + 8) + k] = (short)f2bf(B[(size_t)k * CC + bn0 + c]);
  }
  __syncthreads();

  f32x4 acc[4][4];
  #pragma unroll
  for (int mi = 0; mi < 4; ++mi)
    #pragma unroll
    for (int ni = 0; ni < 4; ++ni)
      #pragma unroll
      for (int rg = 0; rg < 4; ++rg) acc[mi][ni][rg] = 0.f;

  #pragma unroll
  for (int kk = 0; kk < KD; kk += 32){
    short8 af[4], bfg[4];
    #pragma unroll
    for (int mi = 0; mi < 4; ++mi)
      af[mi] = *(const short8*)&As[(wm*64 + mi*16 + l15) * (KD + 8) + kk + quad*8];
    #pragma unroll
    for (int ni = 0; ni < 4; ++ni)
      bfg[ni] = *(const short8*)&Bs[(wn*64 + ni*16 + l15) * (KD + 8) + kk + quad*8];
    #pragma unroll
    for (int mi = 0; mi < 4; ++mi)
      #pragma unroll
      for (int ni = 0; ni < 4; ++ni)
        acc[mi][ni] = __builtin_amdgcn_mfma_f32_16x16x32_bf16(af[mi], bfg[ni], acc[mi][ni], 0, 0, 0);
  }

  #pragma unroll
  for (int mi = 0; mi < 4; ++mi){
    #pragma unroll
    for (int ni = 0; ni < 4; ++ni){
      int col = bn0 + wn*64 + ni*16 + l15;
      float tm = (EP == 1) ? tma_g[col] : 0.f;
      #pragma unroll
      for (int rg = 0; rg < 4; ++rg){
        int row = bm0 + wm*64 + mi*16 + quad*4 + rg;
        float v = acc[mi][ni][rg];
        if (EP == 1){
          float xv = x[(size_t)row * CC + col];
          float xp = ((row & (TT - 1)) == 0) ? 0.f : x[(size_t)row * CC + col - CC];
          v = xv + (xp - xv) * (v + tm);
        }
        OUT[(size_t)row * CC + col] = f2bf(v);
      }
    }
  }
}

// ---------------------------------------------------------------------------
// Fused elementwise + pair precompute, 4 tokens (2 pairs) per block.
// WMODE=1: w_t stored exact f32 in WF. WMODE=0: f16 -u fallback.
// ---------------------------------------------------------------------------
template<int WMODE>
__global__ __launch_bounds__(256) void k_elem(bf16u* __restrict__ K0,
    const bf16u* __restrict__ P1, const bf16u* __restrict__ P2,
    const bf16u* __restrict__ W2A,
    const float* __restrict__ kw2, const float* __restrict__ aw2,
    const float* __restrict__ maw2, const float* __restrict__ mkw2,
    const float* __restrict__ td,  const float* __restrict__ taa,
    const float* __restrict__ tma, const float* __restrict__ tmk,
    const float* __restrict__ faaaa,
    bf16u* __restrict__ KKN, bf16u* __restrict__ Bb, bf16u* __restrict__ UX,
    float* __restrict__ WF,
    bf16u* __restrict__ Rq, float* __restrict__ Dsc, float* __restrict__ RKsc){
  int n0 = blockIdx.x * 4, tid = threadIdx.x;
  __shared__ float at_l[4][16], mat_l[4][16], kt_l[4][16], mkt_l[4][16];
  {
    int grp = tid >> 6, q = tid & 63, tt = q >> 4, j = q & 15;
    if (grp == 0)      at_l[tt][j]  = bf2f(P1[(size_t)(n0+tt)*96 + 64 + j]);
    else if (grp == 1) mat_l[tt][j] = bf2f(P1[(size_t)(n0+tt)*96 + 80 + j]);
    else if (grp == 2) kt_l[tt][j]  = bf2f(P2[(size_t)(n0+tt)*32 + j]);
    else               mkt_l[tt][j] = bf2f(P2[(size_t)(n0+tt)*32 + 16 + j]);
  }
  __syncthreads();
  int c  = tid * 4;
  int h  = tid >> 4;       // head (16 lanes per head)
  int lg = tid & 15;

  float kkk[4][4], aa[4][4], mam[4][4], mkm[4][4];
  #pragma unroll
  for (int tt = 0; tt < 4; ++tt)
    #pragma unroll
    for (int i = 0; i < 4; ++i){ kkk[tt][i]=0; aa[tt][i]=0; mam[tt][i]=0; mkm[tt][i]=0; }

  #pragma unroll 4
  for (int j = 0; j < 16; ++j){
    float wk[4], wa[4], wm[4], wq[4];
    ld4f(kw2  + (size_t)j*CC + c, wk);
    ld4f(aw2  + (size_t)j*CC + c, wa);
    ld4f(maw2 + (size_t)j*CC + c, wm);
    ld4f(mkw2 + (size_t)j*CC + c, wq);
    #pragma unroll
    for (int tt = 0; tt < 4; ++tt){
      float s1 = kt_l[tt][j], s2 = at_l[tt][j], s3 = mat_l[tt][j], s4 = mkt_l[tt][j];
      #pragma unroll
      for (int i = 0; i < 4; ++i){
        kkk[tt][i] += s1 * wk[i];
        aa[tt][i]  += s2 * wa[i];
        mam[tt][i] += s3 * wm[i];
        mkm[tt][i] += s4 * wq[i];
      }
    }
  }

  float td4[4], taa4[4], tma4[4], tmk4[4], fa4[4];
  ld4f(td + c, td4); ld4f(taa + c, taa4); ld4f(tma + c, tma4); ld4f(tmk + c, tmk4);
  ld4f(faaaa + c, fa4);

#define ELEM_TOKEN(TT_, E_, A_, B_, KF_, WD_) do{ \
    float k0a[4]; ld4bf(K0 + (E_), k0a); \
    float w2a[4]; ld4bf(W2A + (E_), w2a); \
    float ssq = 0.f; \
    _Pragma("unroll") \
    for (int i = 0; i < 4; ++i){ A_[i] = k0a[i] + kkk[TT_][i]; ssq += A_[i]*A_[i]; } \
    ssq = red16(ssq); \
    float rinv = 1.f / fmaxf(sqrtf(ssq), 1e-12f); \
    float outw_[4]; \
    _Pragma("unroll") \
    for (int i = 0; i < 4; ++i){ \
      float z  = td4[i] + w2a[i]; \
      float nz = -z; \
      float sp = (nz > 15.f) ? nz : log1pf(expf(nz)); \
      float w  = -sp - 0.5f; \
      float av  = sigm(taa4[i] + aa[TT_][i]); \
      float mav = sigm(tma4[i] + mam[TT_][i]); \
      float mkv = sigm(tmk4[i] + mkm[TT_][i]); \
      A_[i] *= rinv; \
      B_[i]  = -A_[i] * av; \
      KF_[i] = k0a[i] * (mav + av * (1.f - mav)) * expf(w * mkv); \
      float ou = -expf(w); \
      outw_[i] = ou; \
      if (WMODE == 1) WD_[i] = __expf(ou);              /* exact f32 w_t */ \
      else            WD_[i] = __expf(hval(f2h(ou)));   /* f16-consistent */ \
    } \
    st4bf(Bb + (E_), B_); \
    st4bf(K0 + (E_), KF_); \
    if (WMODE == 1) *(float4*)(WF + (E_)) = make_float4(WD_[0], WD_[1], WD_[2], WD_[3]); \
    else            st4h(UX + (E_), outw_); \
  }while(0)

  #pragma unroll
  for (int p = 0; p < 2; ++p){
    const int ttE = 2*p, ttO = ttE + 1;
    size_t eE = (size_t)(n0 + ttE) * CC + c;
    size_t eO = eE + CC;
    float aE[4], bE[4], kfE[4], wdE[4];
    float aO[4], bO[4], kfO[4], wdO[4];
    ELEM_TOKEN(ttE, eE, aE, bE, kfE, wdE);
    ELEM_TOKEN(ttO, eO, aO, bO, kfO, wdO);
    st4bf(KKN + eE, aE);

    float rE[4], rO[4];
    ld4bf(Rq + eE, rE); ld4bf(Rq + eO, rO);

    // rk for k_post (before R is overwritten)
    float rkE = red16(rE[0]*kfE[0]*fa4[0] + rE[1]*kfE[1]*fa4[1]
                    + rE[2]*kfE[2]*fa4[2] + rE[3]*kfE[3]*fa4[3]);
    float rkO = red16(rO[0]*kfO[0]*fa4[0] + rO[1]*kfO[1]*fa4[1]
                    + rO[2]*kfO[2]*fa4[2] + rO[3]*kfO[3]*fa4[3]);

    // u1 over KKN odd row
    float c1 = red16(dot4(bE, aO));
    float d  = red16(dot4(kfE, aO));
    float u1[4];
    #pragma unroll
    for (int i = 0; i < 4; ++i) u1[i] = wdE[i]*aO[i] + c1*aE[i];
    st4bf(KKN + eO, u1);

    // q' even
    float cq = red16(dot4(bE, rE));
    float e1 = red16(dot4(kfE, rE));
    float qe[4];
    #pragma unroll
    for (int i = 0; i < 4; ++i) qe[i] = wdE[i]*rE[i] + cq*aE[i];
    st4bf(Rq + eE, qe);

    // z = M_{t+1} q_{t+1}; q' odd = M_t z
    float cz  = red16(dot4(bO, rO));
    float e21 = red16(dot4(kfO, rO));
    float z[4];
    #pragma unroll
    for (int i = 0; i < 4; ++i) z[i] = wdO[i]*rO[i] + cz*aO[i];
    float cy  = red16(dot4(bE, z));
    float e20 = red16(dot4(kfE, z));
    float qo[4];
    #pragma unroll
    for (int i = 0; i < 4; ++i) qo[i] = wdE[i]*z[i] + cy*aE[i];
    st4bf(Rq + eO, qo);

    if (lg == 0){
      size_t pr = (size_t)((n0 + ttE) >> 1);
      float4 dv; dv.x = d; dv.y = e1; dv.z = e20; dv.w = e21;
      *(float4*)(Dsc + (pr * HH + h) * 4) = dv;
      RKsc[(size_t)(n0 + ttE) * HH + h] = rkE;
      RKsc[(size_t)(n0 + ttO) * HH + h] = rkO;
    }
  }
#undef ELEM_TOKEN
}

// ---------------------------------------------------------------------------
// Recurrence v13 (r8-validated): 32-lane rows, 2 waves/SIMD, pair-fused,
// all 4 reductions vs base S, f32 decay (WMODE=1).
// ---------------------------------------------------------------------------
template<int WMODE>
__global__ __launch_bounds__(256) void k_rec(const bf16u* __restrict__ Qp,
                                             const bf16u* __restrict__ WT,
                                             const float* __restrict__ WF,
                                             const bf16u* __restrict__ KFt,
                                             const bf16u* __restrict__ Vt,
                                             const bf16u* __restrict__ Aa,
                                             const bf16u* __restrict__ Bv,
                                             const float* __restrict__ Dsc,
                                             bf16u* __restrict__ Y){
  const int p   = blockIdx.x;                 // 0..511
  const int g   = (p & 7) | ((p >> 6) << 3);  // (b,h) group 0..63, XCD-clustered
  const int oct = (p >> 3) & 7;               // row octet within the head
  const int b   = g >> 4;
  const int h   = g & 15;
  const int tid = threadIdx.x;
  const int l31 = tid & 31;                   // 32 lanes per row
  const int i   = oct * 8 + (tid >> 5);       // state row 0..63
  const size_t base0 = (size_t)(b * TT) * CC + h * HSS;
  const size_t colb  = base0 + l31 * 2;       // 2 cols per lane
  const size_t rowb  = base0 + i;
  const size_t dscb  = ((size_t)(b * (TT/2)) * HH + h) * 4;

  float S0 = 0.f, S1 = 0.f;                   // state cols (2*l31, 2*l31+1)

  unsigned int qEA,qOA,aEA,uOA,kEA,kOA,bEA,bOA,wEA,wOA; float2 fEA,fOA; unsigned short vEA,vOA; float4 dA;
  unsigned int qEB,qOB,aEB,uOB,kEB,kOB,bEB,bOB,wEB,wOB; float2 fEB,fOB; unsigned short vEB,vOB; float4 dB;
  unsigned int qEC,qOC,aEC,uOC,kEC,kOC,bEC,bOC,wEC,wOC; float2 fEC,fOC; unsigned short vEC,vOC; float4 dC;
  unsigned int qED,qOD,aED,uOD,kED,kOD,bED,bOD,wED,wOD; float2 fED,fOD; unsigned short vED,vOD; float4 dD;

#define PL(S, T_) do{ \
    size_t cE_ = colb + (size_t)(T_) * CC, cO_ = cE_ + CC; \
    qE##S = *(const unsigned int*)(Qp  + cE_); qO##S = *(const unsigned int*)(Qp  + cO_); \
    aE##S = *(const unsigned int*)(Aa  + cE_); uO##S = *(const unsigned int*)(Aa  + cO_); \
    kE##S = *(const unsigned int*)(KFt + cE_); kO##S = *(const unsigned int*)(KFt + cO_); \
    bE##S = *(const unsigned int*)(Bv  + cE_); bO##S = *(const unsigned int*)(Bv  + cO_); \
    if (WMODE == 1){ \
      fE##S = *(const float2*)(WF + cE_); fO##S = *(const float2*)(WF + cO_); \
    } else { \
      wE##S = *(const unsigned int*)(WT + cE_); wO##S = *(const unsigned int*)(WT + cO_); \
    } \
    vE##S = Vt[rowb + (size_t)(T_) * CC]; \
    vO##S = Vt[rowb + (size_t)(T_ + 1) * CC]; \
    d##S  = *(const float4*)(Dsc + dscb + (size_t)((T_) >> 1) * (HH*4)); \
  }while(0)

#define PSTEP(S, T_) do{ \
    float a0=bflo(aE##S), a1=bfhi(aE##S); \
    float u0=bflo(uO##S), u1=bfhi(uO##S); \
    float g0=bflo(qE##S), g1=bfhi(qE##S); \
    float o0=bflo(qO##S), o1=bfhi(qO##S); \
    float pE_ = fmaf(S1, a1, S0 * a0); \
    float pO_ = fmaf(S1, u1, S0 * u0); \
    float yE_ = fmaf(S1, g1, S0 * g0); \
    float yO_ = fmaf(S1, o1, S0 * o0); \
    pE_ = red32(pE_); \
    pO_ = red32(pO_); \
    yE_ = red32(yE_); \
    yO_ = red32(yO_); \
    float vEf = bf2f(vE##S), vOf = bf2f(vO##S); \
    float saE = pE_; \
    float saO = fmaf(d##S.x, vEf, pO_); \
    float ypE = fmaf(d##S.y, vEf, yE_); \
    float ypO = fmaf(d##S.z, vEf, fmaf(d##S.w, vOf, yO_)); \
    float k0=bflo(kE##S), k1=bfhi(kE##S); \
    float b0=bflo(bE##S), b1=bfhi(bE##S); \
    float w0, w1; \
    if (WMODE == 1){ w0=fE##S.x; w1=fE##S.y; } \
    else { w0=__expf(hlo(wE##S)); w1=__expf(hhi(wE##S)); } \
    S0 = fmaf(S0, w0, fmaf(saE, b0, vEf * k0)); \
    S1 = fmaf(S1, w1, fmaf(saE, b1, vEf * k1)); \
    float ko0=bflo(kO##S), ko1=bfhi(kO##S); \
    float bo0=bflo(bO##S), bo1=bfhi(bO##S); \
    float wo0, wo1; \
    if (WMODE == 1){ wo0=fO##S.x; wo1=fO##S.y; } \
    else { wo0=__expf(hlo(wO##S)); wo1=__expf(hhi(wO##S)); } \
    S0 = fmaf(S0, wo0, fmaf(saO, bo0, vOf * ko0)); \
    S1 = fmaf(S1, wo1, fmaf(saO, bo1, vOf * ko1)); \
    if (l31 == 0){ \
      Y[rowb + (size_t)(T_) * CC]     = f2bf(ypE); \
      Y[rowb + (size_t)(T_ + 1) * CC] = f2bf(ypO); \
    } \
  }while(0)

  PL(A, 0); PL(B, 2); PL(C, 4); PL(D, 6);
  for (int t = 0; t < TT; t += 8){
    PSTEP(A, t);
    if (t + 8  < TT) PL(A, t + 8);
    PSTEP(B, t + 2);
    if (t + 10 < TT) PL(B, t + 10);
    PSTEP(C, t + 4);
    if (t + 12 < TT) PL(C, t + 12);
    PSTEP(D, t + 6);
    if (t + 14 < TT) PL(D, t + 14);
  }
#undef PL
#undef PSTEP
}

// ---------------------------------------------------------------------------
// Post: GroupNorm + precomputed bonus rk*v + precomputed gate GV -> YG (bf16)
// ---------------------------------------------------------------------------
__global__ __launch_bounds__(256) void k_post(const bf16u* __restrict__ Y,
                                              const bf16u* __restrict__ Vt,
                                              const bf16u* __restrict__ GV,
                                              const float* __restrict__ lnw,
                                              const float* __restrict__ lnb,
                                              const float* __restrict__ RKsc,
                                              bf16u* __restrict__ YG){
  int n = blockIdx.x, tid = threadIdx.x;
  int c = tid * 4;
  size_t e = (size_t)n * CC + c;

  float ya[4]; ld4bf(Y + e, ya);
  float s = ya[0] + ya[1] + ya[2] + ya[3];
  s = red16(s);
  float mu = s * (1.f / 64.f);
  float d[4], vs = 0.f;
  #pragma unroll
  for (int i = 0; i < 4; ++i){ d[i] = ya[i] - mu; vs += d[i] * d[i]; }
  vs = red16(vs);
  float rstd = rsqrtf(vs * (1.f / 64.f) + EPSGN);

  float rk = RKsc[(size_t)n * HH + (tid >> 4)];

  float va[4]; ld4bf(Vt + e, va);
  float lw4[4], lb4[4];
  ld4f(lnw + c, lw4); ld4f(lnb + c, lb4);
  float g[4]; ld4bf(GV + e, g);
  float o[4];
  #pragma unroll
  for (int i = 0; i < 4; ++i){
    float yn = d[i] * rstd * lw4[i] + lb4[i] + rk * va[i];
    o[i] = yn * g[i];
  }
  st4bf(YG + e, o);
}

// ---------------------------------------------------------------------------
extern "C" void kernel_launch(void* const* d_in, const int* in_sizes, int n_in,
                              void* d_out, int out_size, void* d_ws, size_t ws_size,
                              hipStream_t stream){
  (void)in_sizes; (void)n_in; (void)out_size;
  const float* x        = (const float*)d_in[0];
  const float* tmx      = (const float*)d_in[1];
  const float* tmaa     = (const float*)d_in[2];
  const float* maa_w1   = (const float*)d_in[3];
  const float* maa_w2   = (const float*)d_in[4];
  const float* decay_w1 = (const float*)d_in[5];
  const float* decay_w2 = (const float*)d_in[6];
  const float* aaa_w1   = (const float*)d_in[7];
  const float* aaa_w2   = (const float*)d_in[8];
  const float* kkk_w1   = (const float*)d_in[9];
  const float* kkk_w2   = (const float*)d_in[10];
  const float* gate_w1  = (const float*)d_in[11];
  const float* gate_w2  = (const float*)d_in[12];
  const float* ma_w1    = (const float*)d_in[13];
  const float* ma_w2    = (const float*)d_in[14];
  const float* mk_w1    = (const float*)d_in[15];
  const float* mk_w2    = (const float*)d_in[16];
  const float* t_decay  = (const float*)d_in[17];
  const float* t_faaaa  = (const float*)d_in[18];
  const float* t_aaaaa  = (const float*)d_in[19];
  const float* t_misc_a = (const float*)d_in[20];
  const float* t_misc_k = (const float*)d_in[21];
  const float* Wr       = (const float*)d_in[22];
  const float* Wk       = (const float*)d_in[23];
  const float* Wv       = (const float*)d_in[24];
  const float* Wo       = (const float*)d_in[25];
  const float* ln_w     = (const float*)d_in[26];
  const float* ln_b     = (const float*)d_in[27];

  // Slot map (8MiB bf16 each), 56 MiB slots + smalls at 56..60 MiB.
  // 60..76 MiB region is time-shared:
  //   phase A (steps 0-6):  WrB@60 WkB@62 WvB@64 W1B@66 W2TB@67  (bf16 weights)
  //   phase B (steps 7-8):  WF (f32 w_t, 16 MiB) — k_elem overwrites phase A
  //   phase C (steps 9-11): WoB@60 (2MiB) + GW2T@62 (256KiB), after k_rec
  bf16u* bw  = (bf16u*)d_ws;
  bf16u* MIX = bw + 0*SLOT;
  bf16u* X0  = bw + 0*SLOT;
  bf16u* KKN = bw + 0*SLOT;
  bf16u* YG  = bw + 0*SLOT;
  bf16u* X1  = bw + 1*SLOT;
  bf16u* Bb  = bw + 1*SLOT;
  bf16u* GV  = bw + 1*SLOT;
  bf16u* X2  = bw + 2*SLOT;
  bf16u* UX  = bw + 2*SLOT;
  bf16u* X3  = bw + 3*SLOT;
  bf16u* W2A = bw + 3*SLOT;
  bf16u* Yb  = bw + 3*SLOT;
  bf16u* R   = bw + 4*SLOT;   // becomes q'
  bf16u* K0  = bw + 5*SLOT;   // becomes KF
  bf16u* V   = bw + 6*SLOT;
  char*  wsb = (char*)d_ws;
  bf16u* LO  = (bf16u*)(wsb + (56ull<<20));   // [N,128] bf16, 1 MiB
  bf16u* GT  = (bf16u*)(wsb + (57ull<<20));   // [N,128] bf16, 1 MiB
  bf16u* P1  = (bf16u*)(wsb + (58ull<<20));   // [N,96]  bf16 (dt|at|ma)
  bf16u* P2  = (bf16u*)(wsb + (58ull<<20) + (768ull<<10)); // [N,32] bf16
  float* Dsc = (float*)(wsb + (59ull<<20));   // [N/2,16] float4, 512 KiB
  float* RKsc= (float*)(wsb + (59ull<<20) + (512ull<<10)); // [N,16] f32, 256 KiB
  float* WF  = (float*)(wsb + (60ull<<20));   // [N,CC] f32 w_t, 16 MiB
  bf16u* WrB = (bf16u*)(wsb + (60ull<<20));
  bf16u* WkB = (bf16u*)(wsb + (62ull<<20));
  bf16u* WvB = (bf16u*)(wsb + (64ull<<20));
  bf16u* W1B = (bf16u*)(wsb + (66ull<<20));   // 384 rows x 1024, 0.75 MiB
  bf16u* W2TB= (bf16u*)(wsb + (67ull<<20));   // [1024][192], 0.375 MiB
  bf16u* WoB = (bf16u*)(wsb + (60ull<<20));   // phase C, aliases WrB/WF
  bf16u* GW2T= (bf16u*)(wsb + (62ull<<20));   // phase C: gate_w2^T bf16 [1024][128]
  const bool fast = ws_size >= (77ull<<20);

  if (fast){
    // 0. weight pre-conversion (bf16; identical RNE rounding to old in-GEMM)
    k_wconv1<<<3648, 256, 0, stream>>>(Wr, Wk, Wv, maa_w1, gate_w1, decay_w1,
                                       aaa_w1, ma_w1, kkk_w1, mk_w1,
                                       maa_w2, decay_w2,
                                       WrB, WkB, WvB, W1B, W2TB);
    // 1. mix
    k_prep<<<4096, 256, 0, stream>>>(x, tmx, MIX);
    // 2. lo = tanh(mix @ maa_w1^T)
    k_gemm_mfma_b<true><<<dim3(1,32),256,0,stream>>>(MIX, W1B, LO, 128, CC, 128);
    // 3. xm[g] = x + xx*(lo_g @ maa_w2_g + tmaa_g)
    bf16u* XMs[4] = {X0, X1, X2, X3};
    for (int g = 0; g < 4; ++g)
      k_gemm_nn_b<32,1><<<dim3(8,32),256,0,stream>>>(LO + g*32, 128, W2TB, g*32,
                                                     XMs[g], x, tmaa + (size_t)g*CC);
    // 4. big projections (pipelined mfma_b)
    k_gemm_mfma_b<true><<<dim3(8,32),256,0,stream>>>(X0, WrB, R,  CC, CC, 0);
    k_gemm_mfma_b<true><<<dim3(8,32),256,0,stream>>>(X2, WkB, K0, CC, CC, 0);
    k_gemm_mfma_b<true><<<dim3(8,32),256,0,stream>>>(X3, WvB, V,  CC, CC, 0);
    // 5. first-stage LoRA projections
    k_gemm_mfma_b<true><<<dim3(1,32),256,0,stream>>>(X0, W1B + 128*1024, GT, 128, CC, 128);
    k_gemm_mfma_b<true><<<dim3(1,32),256,0,stream>>>(X1, W1B + 256*1024, P1, 96,  CC, 64);
    k_gemm_mfma_b<true><<<dim3(1,32),256,0,stream>>>(X2, W1B + 352*1024, P2, 32,  CC, 16);
    // 6. W2A = P1[:, :64] @ decay_w2 (last read of W2TB before WF overwrites)
    k_gemm_nn_b<64,0><<<dim3(8,32),256,0,stream>>>(P1, 96, W2TB, 128, W2A, nullptr, nullptr);
    // 7. fused elementwise + pair precompute (writes WF over phase-A weights)
    k_elem<1><<<1024, 256, 0, stream>>>(K0, P1, P2, W2A,
                                        kkk_w2, aaa_w2, ma_w2, mk_w2,
                                        t_decay, t_aaaaa, t_misc_a, t_misc_k, t_faaaa,
                                        KKN, Bb, UX, WF, R, Dsc, RKsc);
    // 8. delta-rule recurrence (r8-validated v13)
    k_rec<1><<<512, 256, 0, stream>>>(R, UX, WF, K0, V, KKN, Bb, Dsc, Yb);
    // 8b. Wo -> bf16 + gate_w2 -> transposed bf16, into now-dead WF region
    k_wconv2<<<1536, 256, 0, stream>>>(Wo, gate_w2, WoB, GW2T);
    // 9. GV = GT @ gate_w2 via fast NT path (bitwise-identical to legacy)
    k_gemm_mfma_b<true><<<dim3(8,32),256,0,stream>>>(GT, GW2T, GV, CC, 128, 0);
    // 10. groupnorm + bonus + gate
    k_post<<<4096, 256, 0, stream>>>(Yb, V, GV, ln_w, ln_b, RKsc, YG);
    // 11. out = yg @ Wo^T -> f32
    k_gemm_mfma_b<false><<<dim3(8,32),256,0,stream>>>(YG, WoB, d_out, CC, CC, 0);
  } else {
    // Fallback: exact r8 sequence (f32 weights in-GEMM, f16 -u decay).
    k_prep<<<4096, 256, 0, stream>>>(x, tmx, MIX);
    k_gemm_mfma<true><<<dim3(1,32),256,0,stream>>>(MIX, maa_w1, maa_w1, maa_w1,
                                                   128, 128, LO, 128, CC, 128);
    bf16u* XMs[4] = {X0, X1, X2, X3};
    for (int g = 0; g < 4; ++g)
      k_gemm_nn<32,1><<<dim3(8,32),256,0,stream>>>(LO + g*32, 128,
                                                   maa_w2 + (size_t)g*32*CC,
                                                   XMs[g], x, tmaa + (size_t)g*CC);
    k_gemm_mfma<true><<<dim3(8,32),256,0,stream>>>(X0, Wr, Wr, Wr, CC, CC, R,  CC, CC, 0);
    k_gemm_mfma<true><<<dim3(8,32),256,0,stream>>>(X2, Wk, Wk, Wk, CC, CC, K0, CC, CC, 0);
    k_gemm_mfma<true><<<dim3(8,32),256,0,stream>>>(X3, Wv, Wv, Wv, CC, CC, V,  CC, CC, 0);
    k_gemm_mfma<true><<<dim3(1,32),256,0,stream>>>(X0, gate_w1, gate_w1, gate_w1,
                                                   128, 128, GT, 128, CC, 128);
    k_gemm_mfma<true><<<dim3(1,32),256,0,stream>>>(X1, decay_w1, aaa_w1, ma_w1,
                                                   64, 80, P1, 96, CC, 64);
    k_gemm_mfma<true><<<dim3(1,32),256,0,stream>>>(X2, kkk_w1, mk_w1, mk_w1,
                                                   16, 32, P2, 32, CC, 16);
    k_gemm_nn<64,0><<<dim3(8,32),256,0,stream>>>(P1, 96, decay_w2, W2A, nullptr, nullptr);
    k_elem<0><<<1024, 256, 0, stream>>>(K0, P1, P2, W2A,
                                        kkk_w2, aaa_w2, ma_w2, mk_w2,
                                        t_decay, t_aaaaa, t_misc_a, t_misc_k, t_faaaa,
                                        KKN, Bb, UX, WF, R, Dsc, RKsc);
    k_rec<0><<<512, 256, 0, stream>>>(R, UX, WF, K0, V, KKN, Bb, Dsc, Yb);
    k_gemm_nn<128,0><<<dim3(8,32),256,0,stream>>>(GT, 128, gate_w2, GV, nullptr, nullptr);
    k_post<<<4096, 256, 0, stream>>>(Yb, V, GV, ln_w, ln_b, RKsc, YG);
    k_gemm_mfma<false><<<dim3(8,32),256,0,stream>>>(YG, Wo, Wo, Wo, CC, CC, d_out, CC, CC, 0);
  }
}

// Round 11
// 589.008 us; speedup vs baseline: 1.6658x; 1.1497x over previous
//
#include <hip/hip_runtime.h>
#include <cstdint>
#include <cstddef>

// Problem constants
#define BB   4
#define TT   1024
#define CC   1024
#define HH   16
#define HSS  64
#define NNtok 4096            // B*T
#define EPSGN 0.00064f
#define W2TS 192              // W2TB col count (maa_w2 128 | decay_w2 64)

typedef unsigned short bf16u;
typedef __attribute__((ext_vector_type(8))) short short8;
typedef __attribute__((ext_vector_type(4))) float f32x4;
#define SLOT 4194304ull       // elements per 8MiB bf16 slot (= NNtok*CC)

__device__ __forceinline__ float bf2f(bf16u u){
  union { unsigned int i; float f; } cv; cv.i = ((unsigned int)u) << 16; return cv.f;
}
__device__ __forceinline__ unsigned short f2bfbits(unsigned int x){
  return (unsigned short)((x + 0x7fffu + ((x >> 16) & 1u)) >> 16);   // RNE
}
__device__ __forceinline__ bf16u f2bf(float f){
  union { float f; unsigned int i; } cv; cv.f = f;
  return f2bfbits(cv.i);
}
__device__ __forceinline__ void ld4bf(const bf16u* p, float* o){
  ushort4 u = *reinterpret_cast<const ushort4*>(p);
  o[0]=bf2f(u.x); o[1]=bf2f(u.y); o[2]=bf2f(u.z); o[3]=bf2f(u.w);
}
__device__ __forceinline__ void st4bf(bf16u* p, const float* v){
  ushort4 u; u.x=f2bf(v[0]); u.y=f2bf(v[1]); u.z=f2bf(v[2]); u.w=f2bf(v[3]);
  *reinterpret_cast<ushort4*>(p) = u;
}
__device__ __forceinline__ unsigned short f2h(float f){
  union { _Float16 h; unsigned short s; } c; c.h = (_Float16)f; return c.s;
}
__device__ __forceinline__ void st4h(bf16u* p, const float* v){
  ushort4 u; u.x=f2h(v[0]); u.y=f2h(v[1]); u.z=f2h(v[2]); u.w=f2h(v[3]);
  *reinterpret_cast<ushort4*>(p) = u;
}
__device__ __forceinline__ void ld4f(const float* p, float* o){
  float4 v = *reinterpret_cast<const float4*>(p);
  o[0]=v.x; o[1]=v.y; o[2]=v.z; o[3]=v.w;
}
__device__ __forceinline__ float sigm(float x){ return 1.f / (1.f + expf(-x)); }

// unpack helpers
__device__ __forceinline__ float bflo(unsigned int u){
  union { unsigned int i; float f; } c; c.i = u << 16; return c.f;
}
__device__ __forceinline__ float bfhi(unsigned int u){
  union { unsigned int i; float f; } c; c.i = u & 0xffff0000u; return c.f;
}
__device__ __forceinline__ float hlo(unsigned int u){
  union { unsigned short s; _Float16 h; } c; c.s = (unsigned short)(u & 0xffffu); return (float)c.h;
}
__device__ __forceinline__ float hhi(unsigned int u){
  union { unsigned short s; _Float16 h; } c; c.s = (unsigned short)(u >> 16); return (float)c.h;
}
__device__ __forceinline__ float hval(unsigned short s){
  union { unsigned short s; _Float16 h; } c; c.s = s; return (float)c.h;
}
__device__ __forceinline__ float dot4(const float* x, const float* y){
  return (x[0]*y[0] + x[1]*y[1]) + (x[2]*y[2] + x[3]*y[3]);
}

// 16-lane sum via DPP. old=0 + bound_ctrl=1 folds to single v_add_f32_dpp.
template<int CTRL>
__device__ __forceinline__ float dpp_add(float v){
  union { float f; int i; } a, b;
  a.f = v;
  b.i = __builtin_amdgcn_update_dpp(0, a.i, CTRL, 0xF, 0xF, true);
  return v + b.f;
}
__device__ __forceinline__ float red16(float v){
  v = dpp_add<0xB1>(v);    // quad_perm [1,0,3,2]  (xor 1)
  v = dpp_add<0x4E>(v);    // quad_perm [2,3,0,1]  (xor 2)
  v = dpp_add<0x124>(v);   // row_ror:4
  v = dpp_add<0x128>(v);   // row_ror:8
  return v;
}
// 32-lane sum in all lanes: red16 then exchange complementary 16-rows
// between two DISTINCT-register copies (laundered; rounds 1/3 failed when
// regalloc coalesced both operands into one phys reg -> self-swap).
__device__ __forceinline__ float red32(float v){
  v = red16(v);
  union { float f; int i; } x, y;
  x.f = v; y.f = v;
  asm volatile("" : "+v"(y.i));   // distinct-vreg launder
  asm volatile("v_permlane16_swap_b32 %0, %1" : "+v"(x.i), "+v"(y.i));
  return x.f + y.f;
}

// ---------------------------------------------------------------------------
// mix = x + (x[t-1]-x[t])*time_maa_x  (x[-1]=0), stored bf16
// ---------------------------------------------------------------------------
__global__ __launch_bounds__(256) void k_prep(const float* __restrict__ x,
                                              const float* __restrict__ tmx,
                                              bf16u* __restrict__ MIX){
  int e = (blockIdx.x * 256 + threadIdx.x) * 4;
  int n = e >> 10;
  int c = e & (CC - 1);
  int t = n & (TT - 1);
  float xf[4]; ld4f(x + e, xf);
  float pf[4] = {0.f, 0.f, 0.f, 0.f};
  if (t > 0) ld4f(x + e - CC, pf);
  float tm[4]; ld4f(tmx + c, tm);
  float mv[4];
  #pragma unroll
  for (int i = 0; i < 4; ++i) mv[i] = xf[i] + (pf[i] - xf[i]) * tm[i];
  st4bf(MIX + e, mv);
}

// ---------------------------------------------------------------------------
// Weight pre-conversion (once per call, ~5us). Outputs live in WF region
// (60..67.4 MiB), dead before k_elem overwrites it at step 7.
// ---------------------------------------------------------------------------
__global__ __launch_bounds__(256) void k_wconv1(
    const float* __restrict__ Wr, const float* __restrict__ Wk,
    const float* __restrict__ Wv,
    const float* __restrict__ maa_w1, const float* __restrict__ gate_w1,
    const float* __restrict__ decay_w1, const float* __restrict__ aaa_w1,
    const float* __restrict__ ma_w1, const float* __restrict__ kkk_w1,
    const float* __restrict__ mk_w1,
    const float* __restrict__ maa_w2, const float* __restrict__ decay_w2,
    bf16u* __restrict__ WrB, bf16u* __restrict__ WkB, bf16u* __restrict__ WvB,
    bf16u* __restrict__ W1B, bf16u* __restrict__ W2TB){
  int blk = blockIdx.x, tid = threadIdx.x;
  if (blk < 3072){
    const float* src = (blk < 1024) ? Wr : (blk < 2048) ? Wk : Wv;
    bf16u* dst = (blk < 1024) ? WrB : (blk < 2048) ? WkB : WvB;
    size_t e = (size_t)(blk & 1023) * 1024 + (size_t)tid * 4;
    float v[4]; ld4f(src + e, v);
    st4bf(dst + e, v);
  } else if (blk < 3456){
    int row = blk - 3072;
    const float* src;
    if      (row < 128) src = maa_w1   + (size_t)row * 1024;
    else if (row < 256) src = gate_w1  + (size_t)(row - 128) * 1024;
    else if (row < 320) src = decay_w1 + (size_t)(row - 256) * 1024;
    else if (row < 336) src = aaa_w1   + (size_t)(row - 320) * 1024;
    else if (row < 352) src = ma_w1    + (size_t)(row - 336) * 1024;
    else if (row < 368) src = kkk_w1   + (size_t)(row - 352) * 1024;
    else                src = mk_w1    + (size_t)(row - 368) * 1024;
    float v[4]; ld4f(src + tid * 4, v);
    st4bf(W1B + (size_t)row * 1024 + tid * 4, v);
  } else {
    int j = blk - 3456;   // 0..191
    const float* src = (j < 128) ? (maa_w2 + (size_t)j * 1024)
                                 : (decay_w2 + (size_t)(j - 128) * 1024);
    for (int c = tid; c < 1024; c += 256)
      W2TB[(size_t)c * W2TS + j] = f2bf(src[c]);
  }
}

// Wo -> bf16 and gate_w2 -> transposed bf16 GW2T [1024][128]; after k_rec.
__global__ __launch_bounds__(256) void k_wconv2(const float* __restrict__ Wo,
                                                const float* __restrict__ gate_w2,
                                                bf16u* __restrict__ WoB,
                                                bf16u* __restrict__ GW2T){
  int blk = blockIdx.x, tid = threadIdx.x;
  if (blk < 1024){
    size_t e = ((size_t)blk * 256 + tid) * 4;
    float v[4]; ld4f(Wo + e, v);
    st4bf(WoB + e, v);
  } else {
    int c = (blk - 1024) * 2 + (tid >> 7);
    int j = tid & 127;
    GW2T[(size_t)c * 128 + j] = f2bf(gate_w2[(size_t)j * CC + c]);
  }
}

// ---------------------------------------------------------------------------
// MFMA NT GEMM body, bf16-W, M64xN128 tile, software-pipelined (r11).
// M-tile 64 doubles grid -> 2 blocks/CU -> 2 waves/SIMD (TLP fills stalls;
// r8 lesson). Per-output MFMA accumulation sequence identical to the M128
// kernel -> bitwise-identical results. LDS ~30KB (2 blocks/CU fits easily).
// ---------------------------------------------------------------------------
#define B64_ASZ (64*40)
#define B64_BSZ (128*40)
template<bool OB>
__device__ __forceinline__ void gemm_b64_body(const bf16u* __restrict__ X,
                                              const bf16u* __restrict__ WB,
                                              void* __restrict__ OUTv,
                                              int Nd, int Kd, int act_n,
                                              short* __restrict__ As,
                                              short* __restrict__ Bs,
                                              int bn0, int bm0){
  const int tid  = threadIdx.x;
  const int lane = tid & 63;
  const int wv   = tid >> 6;
  const int wm   = wv >> 1, wn = wv & 1;   // wave -> 32-row x 64-col subtile
  const int l15  = lane & 15;
  const int quad = lane >> 4;

  f32x4 acc[2][4];
  #pragma unroll
  for (int mi = 0; mi < 2; ++mi)
    #pragma unroll
    for (int ni = 0; ni < 4; ++ni)
      #pragma unroll
      for (int rg = 0; rg < 4; ++rg) acc[mi][ni][rg] = 0.f;

  const int ra = tid >> 2, ka = (tid & 3) * 8;      // A: 64 rows x 32k, 1 uint4/thr
  const int rb = tid >> 1, kb = (tid & 1) * 16;     // B: 128 rows x 32k, 2 uint4/thr
  const bf16u* xsrc = X + (size_t)(bm0 + ra) * Kd;
  const bf16u* wsrc = (bn0 + rb < Nd) ? WB + (size_t)(bn0 + rb) * Kd : nullptr;

  uint4 xa = *(const uint4*)(xsrc + ka);
  uint4 wa = make_uint4(0,0,0,0), wb = wa;
  if (wsrc){
    wa = *(const uint4*)(wsrc + kb);
    wb = *(const uint4*)(wsrc + kb + 8);
  }
  *(uint4*)&As[ra * 40 + ka]      = xa;
  *(uint4*)&Bs[rb * 40 + kb]      = wa;
  *(uint4*)&Bs[rb * 40 + kb + 8]  = wb;
  __syncthreads();

  const int NK = Kd >> 5;
  for (int k = 0; k < NK; ++k){
    const int cur = k & 1;
    if (k + 1 < NK){                    // issue next-tile loads BEFORE compute
      int k0 = (k + 1) << 5;
      xa = *(const uint4*)(xsrc + k0 + ka);
      if (wsrc){
        wa = *(const uint4*)(wsrc + k0 + kb);
        wb = *(const uint4*)(wsrc + k0 + kb + 8);
      }
    }
    short8 af[2], bfg[4];
    #pragma unroll
    for (int mi = 0; mi < 2; ++mi)
      af[mi] = *(const short8*)&As[cur*B64_ASZ + (wm*32 + mi*16 + l15) * 40 + quad*8];
    #pragma unroll
    for (int ni = 0; ni < 4; ++ni)
      bfg[ni] = *(const short8*)&Bs[cur*B64_BSZ + (wn*64 + ni*16 + l15) * 40 + quad*8];
    #pragma unroll
    for (int mi = 0; mi < 2; ++mi)
      #pragma unroll
      for (int ni = 0; ni < 4; ++ni)
        acc[mi][ni] = __builtin_amdgcn_mfma_f32_16x16x32_bf16(af[mi], bfg[ni], acc[mi][ni], 0, 0, 0);
    if (k + 1 < NK){
      const int nxt = cur ^ 1;
      *(uint4*)&As[nxt*B64_ASZ + ra * 40 + ka]     = xa;
      *(uint4*)&Bs[nxt*B64_BSZ + rb * 40 + kb]     = wa;
      *(uint4*)&Bs[nxt*B64_BSZ + rb * 40 + kb + 8] = wb;
      __syncthreads();
    }
  }

  #pragma unroll
  for (int mi = 0; mi < 2; ++mi){
    #pragma unroll
    for (int ni = 0; ni < 4; ++ni){
      int col = bn0 + wn*64 + ni*16 + l15;
      if (col >= Nd) continue;
      #pragma unroll
      for (int rg = 0; rg < 4; ++rg){
        int row = bm0 + wm*32 + mi*16 + quad*4 + rg;
        float v = acc[mi][ni][rg];
        if (col < act_n) v = tanhf(v);
        if (OB) ((bf16u*)OUTv)[(size_t)row * Nd + col] = f2bf(v);
        else    ((float*)OUTv)[(size_t)row * Nd + col] = v;
      }
    }
  }
}

template<bool OB>
__global__ __launch_bounds__(256) void k_gemm_b64(const bf16u* __restrict__ X,
                                                  const bf16u* __restrict__ WB,
                                                  void* __restrict__ OUTv,
                                                  int Nd, int Kd, int act_n){
  __shared__ short As[2*B64_ASZ];
  __shared__ short Bs[2*B64_BSZ];
  gemm_b64_body<OB>(X, WB, OUTv, Nd, Kd, act_n, As, Bs,
                    blockIdx.x * 128, blockIdx.y * 64);
}

// 3 LoRA projections merged into one launch (z decodes): 3x concurrency
// vs serialized 32-block launches that each used 12% of CUs.
__global__ __launch_bounds__(256) void k_gemm_b64_lora(const bf16u* __restrict__ X0,
                                                       const bf16u* __restrict__ X1,
                                                       const bf16u* __restrict__ X2,
                                                       const bf16u* __restrict__ W1B,
                                                       bf16u* __restrict__ GT,
                                                       bf16u* __restrict__ P1,
                                                       bf16u* __restrict__ P2){
  __shared__ short As[2*B64_ASZ];
  __shared__ short Bs[2*B64_BSZ];
  const int z = blockIdx.z;
  const int bm0 = blockIdx.y * 64;
  if (z == 0)
    gemm_b64_body<true>(X0, W1B + 128*1024, GT, 128, CC, 128, As, Bs, 0, bm0);
  else if (z == 1)
    gemm_b64_body<true>(X1, W1B + 256*1024, P1, 96, CC, 64, As, Bs, 0, bm0);
  else
    gemm_b64_body<true>(X2, W1B + 352*1024, P2, 32, CC, 16, As, Bs, 0, bm0);
}

// ---------------------------------------------------------------------------
// MFMA NN GEMM body, pre-transposed bf16 B (single-staging; K fits in LDS).
// ---------------------------------------------------------------------------
template<int KD, int EP>
__device__ __forceinline__ void gemm_nn_body(const bf16u* __restrict__ A, int lda,
                                             const bf16u* __restrict__ BT, int koff,
                                             bf16u* __restrict__ OUT,
                                             const float* __restrict__ x,
                                             const float* __restrict__ tma_g,
                                             short* __restrict__ As,
                                             short* __restrict__ Bs,
                                             int bn0, int bm0){
  const int tid  = threadIdx.x;
  const int lane = tid & 63;
  const int wv   = tid >> 6;
  const int wm   = wv >> 1, wn = wv & 1;
  const int l15  = lane & 15;
  const int quad = lane >> 4;

  for (int idx = tid; idx < 128 * (KD / 8); idx += 256){
    int r  = idx / (KD / 8);
    int kc = (idx % (KD / 8)) * 8;
    *(uint4*)&As[r * (KD + 8) + kc] =
        *(const uint4*)(A + (size_t)(bm0 + r) * lda + kc);
  }
  for (int idx = tid; idx < 128 * (KD / 8); idx += 256){
    int cc_ = idx / (KD / 8);
    int kc  = (idx % (KD / 8)) * 8;
    *(uint4*)&Bs[cc_ * (KD + 8) + kc] =
        *(const uint4*)(BT + (size_t)(bn0 + cc_) * W2TS + koff + kc);
  }
  __syncthreads();

  f32x4 acc[4][4];
  #pragma unroll
  for (int mi = 0; mi < 4; ++mi)
    #pragma unroll
    for (int ni = 0; ni < 4; ++ni)
      #pragma unroll
      for (int rg = 0; rg < 4; ++rg) acc[mi][ni][rg] = 0.f;

  #pragma unroll
  for (int kk = 0; kk < KD; kk += 32){
    short8 af[4], bfg[4];
    #pragma unroll
    for (int mi = 0; mi < 4; ++mi)
      af[mi] = *(const short8*)&As[(wm*64 + mi*16 + l15) * (KD + 8) + kk + quad*8];
    #pragma unroll
    for (int ni = 0; ni < 4; ++ni)
      bfg[ni] = *(const short8*)&Bs[(wn*64 + ni*16 + l15) * (KD + 8) + kk + quad*8];
    #pragma unroll
    for (int mi = 0; mi < 4; ++mi)
      #pragma unroll
      for (int ni = 0; ni < 4; ++ni)
        acc[mi][ni] = __builtin_amdgcn_mfma_f32_16x16x32_bf16(af[mi], bfg[ni], acc[mi][ni], 0, 0, 0);
  }

  #pragma unroll
  for (int mi = 0; mi < 4; ++mi){
    #pragma unroll
    for (int ni = 0; ni < 4; ++ni){
      int col = bn0 + wn*64 + ni*16 + l15;
      float tm = (EP == 1) ? tma_g[col] : 0.f;
      #pragma unroll
      for (int rg = 0; rg < 4; ++rg){
        int row = bm0 + wm*64 + mi*16 + quad*4 + rg;
        float v = acc[mi][ni][rg];
        if (EP == 1){
          float xv = x[(size_t)row * CC + col];
          float xp = ((row & (TT - 1)) == 0) ? 0.f : x[(size_t)row * CC + col - CC];
          v = xv + (xp - xv) * (v + tm);
        }
        OUT[(size_t)row * CC + col] = f2bf(v);
      }
    }
  }
}

template<int KD, int EP>
__global__ __launch_bounds__(256) void k_gemm_nn_b(const bf16u* __restrict__ A, int lda,
                                                   const bf16u* __restrict__ BT, int koff,
                                                   bf16u* __restrict__ OUT,
                                                   const float* __restrict__ x,
                                                   const float* __restrict__ tma_g){
  __shared__ short As[128 * (KD + 8)];
  __shared__ short Bs[128 * (KD + 8)];
  gemm_nn_body<KD, EP>(A, lda, BT, koff, OUT, x, tma_g, As, Bs,
                       blockIdx.x * 128, blockIdx.y * 128);
}

// 4 xm NN-GEMMs merged into one launch (z = group): 4x concurrency + 3 fewer
// launch gaps. OUT = X0 + z*SLOT (slots are contiguous); koff = z*32.
__global__ __launch_bounds__(256) void k_gemm_nn_b4(const bf16u* __restrict__ LO,
                                                    const bf16u* __restrict__ BT,
                                                    bf16u* __restrict__ X0base,
                                                    const float* __restrict__ x,
                                                    const float* __restrict__ tmaa){
  __shared__ short As[128 * 40];
  __shared__ short Bs[128 * 40];
  const int z = blockIdx.z;
  gemm_nn_body<32, 1>(LO + z*32, 128, BT, z*32, X0base + (size_t)z*SLOT,
                      x, tmaa + (size_t)z*CC, As, Bs,
                      blockIdx.x * 128, blockIdx.y * 128);
}

// ---------------------------------------------------------------------------
// LEGACY f32-W GEMMs (fallback path only)
// ---------------------------------------------------------------------------
template<bool OB>
__global__ __launch_bounds__(256) void k_gemm_mfma(const bf16u* __restrict__ X,
                                                   const float* __restrict__ Wa,
                                                   const float* __restrict__ Wb,
                                                   const float* __restrict__ Wc,
                                                   int na, int nab,
                                                   void* __restrict__ OUTv,
                                                   int Nd, int Kd, int act_n){
  __shared__ short As[128 * 40];
  __shared__ short Bs[128 * 40];
  const int tid  = threadIdx.x;
  const int lane = tid & 63;
  const int wv   = tid >> 6;
  const int wm   = wv >> 1, wn = wv & 1;
  const int bn0  = blockIdx.x * 128;
  const int bm0  = blockIdx.y * 128;
  const int l15  = lane & 15;
  const int quad = lane >> 4;

  f32x4 acc[4][4];
  #pragma unroll
  for (int mi = 0; mi < 4; ++mi)
    #pragma unroll
    for (int ni = 0; ni < 4; ++ni)
      #pragma unroll
      for (int rg = 0; rg < 4; ++rg) acc[mi][ni][rg] = 0.f;

  const int r    = tid >> 1;
  const int half = (tid & 1) * 16;

  int rr = bn0 + r;
  const float* wsrc = nullptr;
  if (rr < na)        wsrc = Wa + (size_t)rr * Kd;
  else if (rr < nab)  wsrc = Wb + (size_t)(rr - na) * Kd;
  else if (rr < Nd)   wsrc = Wc + (size_t)(rr - nab) * Kd;
  const bf16u* xsrc = X + (size_t)(bm0 + r) * Kd;

  for (int k0 = 0; k0 < Kd; k0 += 32){
    uint4 xa = *(const uint4*)(xsrc + k0 + half);
    uint4 xb = *(const uint4*)(xsrc + k0 + half + 8);
    uint4 w0 = make_uint4(0,0,0,0), w1 = w0, w2 = w0, w3 = w0;
    if (wsrc){
      w0 = *(const uint4*)(wsrc + k0 + half);
      w1 = *(const uint4*)(wsrc + k0 + half + 4);
      w2 = *(const uint4*)(wsrc + k0 + half + 8);
      w3 = *(const uint4*)(wsrc + k0 + half + 12);
    }
    union { unsigned short s[8]; uint4 v; } p0, p1;
    p0.s[0]=f2bfbits(w0.x); p0.s[1]=f2bfbits(w0.y); p0.s[2]=f2bfbits(w0.z); p0.s[3]=f2bfbits(w0.w);
    p0.s[4]=f2bfbits(w1.x); p0.s[5]=f2bfbits(w1.y); p0.s[6]=f2bfbits(w1.z); p0.s[7]=f2bfbits(w1.w);
    p1.s[0]=f2bfbits(w2.x); p1.s[1]=f2bfbits(w2.y); p1.s[2]=f2bfbits(w2.z); p1.s[3]=f2bfbits(w2.w);
    p1.s[4]=f2bfbits(w3.x); p1.s[5]=f2bfbits(w3.y); p1.s[6]=f2bfbits(w3.z); p1.s[7]=f2bfbits(w3.w);

    *(uint4*)&As[r * 40 + half]     = xa;
    *(uint4*)&As[r * 40 + half + 8] = xb;
    *(uint4*)&Bs[r * 40 + half]     = p0.v;
    *(uint4*)&Bs[r * 40 + half + 8] = p1.v;
    __syncthreads();

    short8 af[4], bfg[4];
    #pragma unroll
    for (int mi = 0; mi < 4; ++mi)
      af[mi] = *(const short8*)&As[(wm*64 + mi*16 + l15) * 40 + quad*8];
    #pragma unroll
    for (int ni = 0; ni < 4; ++ni)
      bfg[ni] = *(const short8*)&Bs[(wn*64 + ni*16 + l15) * 40 + quad*8];
    #pragma unroll
    for (int mi = 0; mi < 4; ++mi)
      #pragma unroll
      for (int ni = 0; ni < 4; ++ni)
        acc[mi][ni] = __builtin_amdgcn_mfma_f32_16x16x32_bf16(af[mi], bfg[ni], acc[mi][ni], 0, 0, 0);
    __syncthreads();
  }

  #pragma unroll
  for (int mi = 0; mi < 4; ++mi){
    #pragma unroll
    for (int ni = 0; ni < 4; ++ni){
      int col = bn0 + wn*64 + ni*16 + l15;
      if (col >= Nd) continue;
      #pragma unroll
      for (int rg = 0; rg < 4; ++rg){
        int row = bm0 + wm*64 + mi*16 + quad*4 + rg;
        float v = acc[mi][ni][rg];
        if (col < act_n) v = tanhf(v);
        if (OB) ((bf16u*)OUTv)[(size_t)row * Nd + col] = f2bf(v);
        else    ((float*)OUTv)[(size_t)row * Nd + col] = v;
      }
    }
  }
}

template<int KD, int EP>
__global__ __launch_bounds__(256) void k_gemm_nn(const bf16u* __restrict__ A, int lda,
                                                 const float* __restrict__ B,
                                                 bf16u* __restrict__ OUT,
                                                 const float* __restrict__ x,
                                                 const float* __restrict__ tma_g){
  __shared__ short As[128 * (KD + 8)];
  __shared__ short Bs[128 * (KD + 8)];
  const int tid  = threadIdx.x;
  const int lane = tid & 63;
  const int wv   = tid >> 6;
  const int wm   = wv >> 1, wn = wv & 1;
  const int bn0  = blockIdx.x * 128;
  const int bm0  = blockIdx.y * 128;
  const int l15  = lane & 15;
  const int quad = lane >> 4;

  for (int idx = tid; idx < 128 * (KD / 8); idx += 256){
    int r  = idx / (KD / 8);
    int kc = (idx % (KD / 8)) * 8;
    *(uint4*)&As[r * (KD + 8) + kc] =
        *(const uint4*)(A + (size_t)(bm0 + r) * lda + kc);
  }
  for (int idx = tid; idx < KD * 128; idx += 256){
    int k = idx >> 7, c = idx & 127;
    Bs[c * (KD + 8) + k] = (short)f2bf(B[(size_t)k * CC + bn0 + c]);
  }
  __syncthreads();

  f32x4 acc[4][4];
  #pragma unroll
  for (int mi = 0; mi < 4; ++mi)
    #pragma unroll
    for (int ni = 0; ni < 4; ++ni)
      #pragma unroll
      for (int rg = 0; rg < 4; ++rg) acc[mi][ni][rg] = 0.f;

  #pragma unroll
  for (int kk = 0; kk < KD; kk += 32){
    short8 af[4], bfg[4];
    #pragma unroll
    for (int mi = 0; mi < 4; ++mi)
      af[mi] = *(const short8*)&As[(wm*64 + mi*16 + l15) * (KD + 8) + kk + quad*8];
    #pragma unroll
    for (int ni = 0; ni < 4; ++ni)
      bfg[ni] = *(const short8*)&Bs[(wn*64 + ni*16 + l15) * (KD + 8) + kk + quad*8];
    #pragma unroll
    for (int mi = 0; mi < 4; ++mi)
      #pragma unroll
      for (int ni = 0; ni < 4; ++ni)
        acc[mi][ni] = __builtin_amdgcn_mfma_f32_16x16x32_bf16(af[mi], bfg[ni], acc[mi][ni], 0, 0, 0);
  }

  #pragma unroll
  for (int mi = 0; mi < 4; ++mi){
    #pragma unroll
    for (int ni = 0; ni < 4; ++ni){
      int col = bn0 + wn*64 + ni*16 + l15;
      float tm = (EP == 1) ? tma_g[col] : 0.f;
      #pragma unroll
      for (int rg = 0; rg < 4; ++rg){
        int row = bm0 + wm*64 + mi*16 + quad*4 + rg;
        float v = acc[mi][ni][rg];
        if (EP == 1){
          float xv = x[(size_t)row * CC + col];
          float xp = ((row & (TT - 1)) == 0) ? 0.f : x[(size_t)row * CC + col - CC];
          v = xv + (xp - xv) * (v + tm);
        }
        OUT[(size_t)row * CC + col] = f2bf(v);
      }
    }
  }
}

// ---------------------------------------------------------------------------
// Fused elementwise + pair precompute, 4 tokens (2 pairs) per block.
// WMODE=1: w_t stored exact f32 in WF. WMODE=0: f16 -u fallback.
// ---------------------------------------------------------------------------
template<int WMODE>
__global__ __launch_bounds__(256) void k_elem(bf16u* __restrict__ K0,
    const bf16u* __restrict__ P1, const bf16u* __restrict__ P2,
    const bf16u* __restrict__ W2A,
    const float* __restrict__ kw2, const float* __restrict__ aw2,
    const float* __restrict__ maw2, const float* __restrict__ mkw2,
    const float* __restrict__ td,  const float* __restrict__ taa,
    const float* __restrict__ tma, const float* __restrict__ tmk,
    const float* __restrict__ faaaa,
    bf16u* __restrict__ KKN, bf16u* __restrict__ Bb, bf16u* __restrict__ UX,
    float* __restrict__ WF,
    bf16u* __restrict__ Rq, float* __restrict__ Dsc, float* __restrict__ RKsc){
  int n0 = blockIdx.x * 4, tid = threadIdx.x;
  __shared__ float at_l[4][16], mat_l[4][16], kt_l[4][16], mkt_l[4][16];
  {
    int grp = tid >> 6, q = tid & 63, tt = q >> 4, j = q & 15;
    if (grp == 0)      at_l[tt][j]  = bf2f(P1[(size_t)(n0+tt)*96 + 64 + j]);
    else if (grp == 1) mat_l[tt][j] = bf2f(P1[(size_t)(n0+tt)*96 + 80 + j]);
    else if (grp == 2) kt_l[tt][j]  = bf2f(P2[(size_t)(n0+tt)*32 + j]);
    else               mkt_l[tt][j] = bf2f(P2[(size_t)(n0+tt)*32 + 16 + j]);
  }
  __syncthreads();
  int c  = tid * 4;
  int h  = tid >> 4;       // head (16 lanes per head)
  int lg = tid & 15;

  float kkk[4][4], aa[4][4], mam[4][4], mkm[4][4];
  #pragma unroll
  for (int tt = 0; tt < 4; ++tt)
    #pragma unroll
    for (int i = 0; i < 4; ++i){ kkk[tt][i]=0; aa[tt][i]=0; mam[tt][i]=0; mkm[tt][i]=0; }

  #pragma unroll 4
  for (int j = 0; j < 16; ++j){
    float wk[4], wa[4], wm[4], wq[4];
    ld4f(kw2  + (size_t)j*CC + c, wk);
    ld4f(aw2  + (size_t)j*CC + c, wa);
    ld4f(maw2 + (size_t)j*CC + c, wm);
    ld4f(mkw2 + (size_t)j*CC + c, wq);
    #pragma unroll
    for (int tt = 0; tt < 4; ++tt){
      float s1 = kt_l[tt][j], s2 = at_l[tt][j], s3 = mat_l[tt][j], s4 = mkt_l[tt][j];
      #pragma unroll
      for (int i = 0; i < 4; ++i){
        kkk[tt][i] += s1 * wk[i];
        aa[tt][i]  += s2 * wa[i];
        mam[tt][i] += s3 * wm[i];
        mkm[tt][i] += s4 * wq[i];
      }
    }
  }

  float td4[4], taa4[4], tma4[4], tmk4[4], fa4[4];
  ld4f(td + c, td4); ld4f(taa + c, taa4); ld4f(tma + c, tma4); ld4f(tmk + c, tmk4);
  ld4f(faaaa + c, fa4);

#define ELEM_TOKEN(TT_, E_, A_, B_, KF_, WD_) do{ \
    float k0a[4]; ld4bf(K0 + (E_), k0a); \
    float w2a[4]; ld4bf(W2A + (E_), w2a); \
    float ssq = 0.f; \
    _Pragma("unroll") \
    for (int i = 0; i < 4; ++i){ A_[i] = k0a[i] + kkk[TT_][i]; ssq += A_[i]*A_[i]; } \
    ssq = red16(ssq); \
    float rinv = 1.f / fmaxf(sqrtf(ssq), 1e-12f); \
    float outw_[4]; \
    _Pragma("unroll") \
    for (int i = 0; i < 4; ++i){ \
      float z  = td4[i] + w2a[i]; \
      float nz = -z; \
      float sp = (nz > 15.f) ? nz : log1pf(expf(nz)); \
      float w  = -sp - 0.5f; \
      float av  = sigm(taa4[i] + aa[TT_][i]); \
      float mav = sigm(tma4[i] + mam[TT_][i]); \
      float mkv = sigm(tmk4[i] + mkm[TT_][i]); \
      A_[i] *= rinv; \
      B_[i]  = -A_[i] * av; \
      KF_[i] = k0a[i] * (mav + av * (1.f - mav)) * expf(w * mkv); \
      float ou = -expf(w); \
      outw_[i] = ou; \
      if (WMODE == 1) WD_[i] = __expf(ou);              /* exact f32 w_t */ \
      else            WD_[i] = __expf(hval(f2h(ou)));   /* f16-consistent */ \
    } \
    st4bf(Bb + (E_), B_); \
    st4bf(K0 + (E_), KF_); \
    if (WMODE == 1) *(float4*)(WF + (E_)) = make_float4(WD_[0], WD_[1], WD_[2], WD_[3]); \
    else            st4h(UX + (E_), outw_); \
  }while(0)

  #pragma unroll
  for (int p = 0; p < 2; ++p){
    const int ttE = 2*p, ttO = ttE + 1;
    size_t eE = (size_t)(n0 + ttE) * CC + c;
    size_t eO = eE + CC;
    float aE[4], bE[4], kfE[4], wdE[4];
    float aO[4], bO[4], kfO[4], wdO[4];
    ELEM_TOKEN(ttE, eE, aE, bE, kfE, wdE);
    ELEM_TOKEN(ttO, eO, aO, bO, kfO, wdO);
    st4bf(KKN + eE, aE);

    float rE[4], rO[4];
    ld4bf(Rq + eE, rE); ld4bf(Rq + eO, rO);

    // rk for k_post (before R is overwritten)
    float rkE = red16(rE[0]*kfE[0]*fa4[0] + rE[1]*kfE[1]*fa4[1]
                    + rE[2]*kfE[2]*fa4[2] + rE[3]*kfE[3]*fa4[3]);
    float rkO = red16(rO[0]*kfO[0]*fa4[0] + rO[1]*kfO[1]*fa4[1]
                    + rO[2]*kfO[2]*fa4[2] + rO[3]*kfO[3]*fa4[3]);

    // u1 over KKN odd row
    float c1 = red16(dot4(bE, aO));
    float d  = red16(dot4(kfE, aO));
    float u1[4];
    #pragma unroll
    for (int i = 0; i < 4; ++i) u1[i] = wdE[i]*aO[i] + c1*aE[i];
    st4bf(KKN + eO, u1);

    // q' even
    float cq = red16(dot4(bE, rE));
    float e1 = red16(dot4(kfE, rE));
    float qe[4];
    #pragma unroll
    for (int i = 0; i < 4; ++i) qe[i] = wdE[i]*rE[i] + cq*aE[i];
    st4bf(Rq + eE, qe);

    // z = M_{t+1} q_{t+1}; q' odd = M_t z
    float cz  = red16(dot4(bO, rO));
    float e21 = red16(dot4(kfO, rO));
    float z[4];
    #pragma unroll
    for (int i = 0; i < 4; ++i) z[i] = wdO[i]*rO[i] + cz*aO[i];
    float cy  = red16(dot4(bE, z));
    float e20 = red16(dot4(kfE, z));
    float qo[4];
    #pragma unroll
    for (int i = 0; i < 4; ++i) qo[i] = wdE[i]*z[i] + cy*aE[i];
    st4bf(Rq + eO, qo);

    if (lg == 0){
      size_t pr = (size_t)((n0 + ttE) >> 1);
      float4 dv; dv.x = d; dv.y = e1; dv.z = e20; dv.w = e21;
      *(float4*)(Dsc + (pr * HH + h) * 4) = dv;
      RKsc[(size_t)(n0 + ttE) * HH + h] = rkE;
      RKsc[(size_t)(n0 + ttO) * HH + h] = rkO;
    }
  }
#undef ELEM_TOKEN
}

// ---------------------------------------------------------------------------
// Recurrence v13 (r8-validated): 32-lane rows, 2 waves/SIMD, pair-fused,
// all 4 reductions vs base S, f32 decay (WMODE=1).
// ---------------------------------------------------------------------------
template<int WMODE>
__global__ __launch_bounds__(256) void k_rec(const bf16u* __restrict__ Qp,
                                             const bf16u* __restrict__ WT,
                                             const float* __restrict__ WF,
                                             const bf16u* __restrict__ KFt,
                                             const bf16u* __restrict__ Vt,
                                             const bf16u* __restrict__ Aa,
                                             const bf16u* __restrict__ Bv,
                                             const float* __restrict__ Dsc,
                                             bf16u* __restrict__ Y){
  const int p   = blockIdx.x;                 // 0..511
  const int g   = (p & 7) | ((p >> 6) << 3);  // (b,h) group 0..63, XCD-clustered
  const int oct = (p >> 3) & 7;               // row octet within the head
  const int b   = g >> 4;
  const int h   = g & 15;
  const int tid = threadIdx.x;
  const int l31 = tid & 31;                   // 32 lanes per row
  const int i   = oct * 8 + (tid >> 5);       // state row 0..63
  const size_t base0 = (size_t)(b * TT) * CC + h * HSS;
  const size_t colb  = base0 + l31 * 2;       // 2 cols per lane
  const size_t rowb  = base0 + i;
  const size_t dscb  = ((size_t)(b * (TT/2)) * HH + h) * 4;

  float S0 = 0.f, S1 = 0.f;                   // state cols (2*l31, 2*l31+1)

  unsigned int qEA,qOA,aEA,uOA,kEA,kOA,bEA,bOA,wEA,wOA; float2 fEA,fOA; unsigned short vEA,vOA; float4 dA;
  unsigned int qEB,qOB,aEB,uOB,kEB,kOB,bEB,bOB,wEB,wOB; float2 fEB,fOB; unsigned short vEB,vOB; float4 dB;
  unsigned int qEC,qOC,aEC,uOC,kEC,kOC,bEC,bOC,wEC,wOC; float2 fEC,fOC; unsigned short vEC,vOC; float4 dC;
  unsigned int qED,qOD,aED,uOD,kED,kOD,bED,bOD,wED,wOD; float2 fED,fOD; unsigned short vED,vOD; float4 dD;

#define PL(S, T_) do{ \
    size_t cE_ = colb + (size_t)(T_) * CC, cO_ = cE_ + CC; \
    qE##S = *(const unsigned int*)(Qp  + cE_); qO##S = *(const unsigned int*)(Qp  + cO_); \
    aE##S = *(const unsigned int*)(Aa  + cE_); uO##S = *(const unsigned int*)(Aa  + cO_); \
    kE##S = *(const unsigned int*)(KFt + cE_); kO##S = *(const unsigned int*)(KFt + cO_); \
    bE##S = *(const unsigned int*)(Bv  + cE_); bO##S = *(const unsigned int*)(Bv  + cO_); \
    if (WMODE == 1){ \
      fE##S = *(const float2*)(WF + cE_); fO##S = *(const float2*)(WF + cO_); \
    } else { \
      wE##S = *(const unsigned int*)(WT + cE_); wO##S = *(const unsigned int*)(WT + cO_); \
    } \
    vE##S = Vt[rowb + (size_t)(T_) * CC]; \
    vO##S = Vt[rowb + (size_t)(T_ + 1) * CC]; \
    d##S  = *(const float4*)(Dsc + dscb + (size_t)((T_) >> 1) * (HH*4)); \
  }while(0)

#define PSTEP(S, T_) do{ \
    float a0=bflo(aE##S), a1=bfhi(aE##S); \
    float u0=bflo(uO##S), u1=bfhi(uO##S); \
    float g0=bflo(qE##S), g1=bfhi(qE##S); \
    float o0=bflo(qO##S), o1=bfhi(qO##S); \
    float pE_ = fmaf(S1, a1, S0 * a0); \
    float pO_ = fmaf(S1, u1, S0 * u0); \
    float yE_ = fmaf(S1, g1, S0 * g0); \
    float yO_ = fmaf(S1, o1, S0 * o0); \
    pE_ = red32(pE_); \
    pO_ = red32(pO_); \
    yE_ = red32(yE_); \
    yO_ = red32(yO_); \
    float vEf = bf2f(vE##S), vOf = bf2f(vO##S); \
    float saE = pE_; \
    float saO = fmaf(d##S.x, vEf, pO_); \
    float ypE = fmaf(d##S.y, vEf, yE_); \
    float ypO = fmaf(d##S.z, vEf, fmaf(d##S.w, vOf, yO_)); \
    float k0=bflo(kE##S), k1=bfhi(kE##S); \
    float b0=bflo(bE##S), b1=bfhi(bE##S); \
    float w0, w1; \
    if (WMODE == 1){ w0=fE##S.x; w1=fE##S.y; } \
    else { w0=__expf(hlo(wE##S)); w1=__expf(hhi(wE##S)); } \
    S0 = fmaf(S0, w0, fmaf(saE, b0, vEf * k0)); \
    S1 = fmaf(S1, w1, fmaf(saE, b1, vEf * k1)); \
    float ko0=bflo(kO##S), ko1=bfhi(kO##S); \
    float bo0=bflo(bO##S), bo1=bfhi(bO##S); \
    float wo0, wo1; \
    if (WMODE == 1){ wo0=fO##S.x; wo1=fO##S.y; } \
    else { wo0=__expf(hlo(wO##S)); wo1=__expf(hhi(wO##S)); } \
    S0 = fmaf(S0, wo0, fmaf(saO, bo0, vOf * ko0)); \
    S1 = fmaf(S1, wo1, fmaf(saO, bo1, vOf * ko1)); \
    if (l31 == 0){ \
      Y[rowb + (size_t)(T_) * CC]     = f2bf(ypE); \
      Y[rowb + (size_t)(T_ + 1) * CC] = f2bf(ypO); \
    } \
  }while(0)

  PL(A, 0); PL(B, 2); PL(C, 4); PL(D, 6);
  for (int t = 0; t < TT; t += 8){
    PSTEP(A, t);
    if (t + 8  < TT) PL(A, t + 8);
    PSTEP(B, t + 2);
    if (t + 10 < TT) PL(B, t + 10);
    PSTEP(C, t + 4);
    if (t + 12 < TT) PL(C, t + 12);
    PSTEP(D, t + 6);
    if (t + 14 < TT) PL(D, t + 14);
  }
#undef PL
#undef PSTEP
}

// ---------------------------------------------------------------------------
// Post: GroupNorm + precomputed bonus rk*v + precomputed gate GV -> YG (bf16)
// ---------------------------------------------------------------------------
__global__ __launch_bounds__(256) void k_post(const bf16u* __restrict__ Y,
                                              const bf16u* __restrict__ Vt,
                                              const bf16u* __restrict__ GV,
                                              const float* __restrict__ lnw,
                                              const float* __restrict__ lnb,
                                              const float* __restrict__ RKsc,
                                              bf16u* __restrict__ YG){
  int n = blockIdx.x, tid = threadIdx.x;
  int c = tid * 4;
  size_t e = (size_t)n * CC + c;

  float ya[4]; ld4bf(Y + e, ya);
  float s = ya[0] + ya[1] + ya[2] + ya[3];
  s = red16(s);
  float mu = s * (1.f / 64.f);
  float d[4], vs = 0.f;
  #pragma unroll
  for (int i = 0; i < 4; ++i){ d[i] = ya[i] - mu; vs += d[i] * d[i]; }
  vs = red16(vs);
  float rstd = rsqrtf(vs * (1.f / 64.f) + EPSGN);

  float rk = RKsc[(size_t)n * HH + (tid >> 4)];

  float va[4]; ld4bf(Vt + e, va);
  float lw4[4], lb4[4];
  ld4f(lnw + c, lw4); ld4f(lnb + c, lb4);
  float g[4]; ld4bf(GV + e, g);
  float o[4];
  #pragma unroll
  for (int i = 0; i < 4; ++i){
    float yn = d[i] * rstd * lw4[i] + lb4[i] + rk * va[i];
    o[i] = yn * g[i];
  }
  st4bf(YG + e, o);
}

// ---------------------------------------------------------------------------
extern "C" void kernel_launch(void* const* d_in, const int* in_sizes, int n_in,
                              void* d_out, int out_size, void* d_ws, size_t ws_size,
                              hipStream_t stream){
  (void)in_sizes; (void)n_in; (void)out_size;
  const float* x        = (const float*)d_in[0];
  const float* tmx      = (const float*)d_in[1];
  const float* tmaa     = (const float*)d_in[2];
  const float* maa_w1   = (const float*)d_in[3];
  const float* maa_w2   = (const float*)d_in[4];
  const float* decay_w1 = (const float*)d_in[5];
  const float* decay_w2 = (const float*)d_in[6];
  const float* aaa_w1   = (const float*)d_in[7];
  const float* aaa_w2   = (const float*)d_in[8];
  const float* kkk_w1   = (const float*)d_in[9];
  const float* kkk_w2   = (const float*)d_in[10];
  const float* gate_w1  = (const float*)d_in[11];
  const float* gate_w2  = (const float*)d_in[12];
  const float* ma_w1    = (const float*)d_in[13];
  const float* ma_w2    = (const float*)d_in[14];
  const float* mk_w1    = (const float*)d_in[15];
  const float* mk_w2    = (const float*)d_in[16];
  const float* t_decay  = (const float*)d_in[17];
  const float* t_faaaa  = (const float*)d_in[18];
  const float* t_aaaaa  = (const float*)d_in[19];
  const float* t_misc_a = (const float*)d_in[20];
  const float* t_misc_k = (const float*)d_in[21];
  const float* Wr       = (const float*)d_in[22];
  const float* Wk       = (const float*)d_in[23];
  const float* Wv       = (const float*)d_in[24];
  const float* Wo       = (const float*)d_in[25];
  const float* ln_w     = (const float*)d_in[26];
  const float* ln_b     = (const float*)d_in[27];

  // Slot map (8MiB bf16 each), 56 MiB slots + smalls at 56..60 MiB.
  // 60..76 MiB region is time-shared:
  //   phase A (steps 0-6):  WrB@60 WkB@62 WvB@64 W1B@66 W2TB@67  (bf16 weights)
  //   phase B (steps 7-8):  WF (f32 w_t, 16 MiB) — k_elem overwrites phase A
  //   phase C (steps 9-11): WoB@60 (2MiB) + GW2T@62 (256KiB), after k_rec
  bf16u* bw  = (bf16u*)d_ws;
  bf16u* MIX = bw + 0*SLOT;
  bf16u* X0  = bw + 0*SLOT;
  bf16u* KKN = bw + 0*SLOT;
  bf16u* YG  = bw + 0*SLOT;
  bf16u* X1  = bw + 1*SLOT;
  bf16u* Bb  = bw + 1*SLOT;
  bf16u* GV  = bw + 1*SLOT;
  bf16u* X2  = bw + 2*SLOT;
  bf16u* UX  = bw + 2*SLOT;
  bf16u* X3  = bw + 3*SLOT;
  bf16u* W2A = bw + 3*SLOT;
  bf16u* Yb  = bw + 3*SLOT;
  bf16u* R   = bw + 4*SLOT;   // becomes q'
  bf16u* K0  = bw + 5*SLOT;   // becomes KF
  bf16u* V   = bw + 6*SLOT;
  char*  wsb = (char*)d_ws;
  bf16u* LO  = (bf16u*)(wsb + (56ull<<20));   // [N,128] bf16, 1 MiB
  bf16u* GT  = (bf16u*)(wsb + (57ull<<20));   // [N,128] bf16, 1 MiB
  bf16u* P1  = (bf16u*)(wsb + (58ull<<20));   // [N,96]  bf16 (dt|at|ma)
  bf16u* P2  = (bf16u*)(wsb + (58ull<<20) + (768ull<<10)); // [N,32] bf16
  float* Dsc = (float*)(wsb + (59ull<<20));   // [N/2,16] float4, 512 KiB
  float* RKsc= (float*)(wsb + (59ull<<20) + (512ull<<10)); // [N,16] f32, 256 KiB
  float* WF  = (float*)(wsb + (60ull<<20));   // [N,CC] f32 w_t, 16 MiB
  bf16u* WrB = (bf16u*)(wsb + (60ull<<20));
  bf16u* WkB = (bf16u*)(wsb + (62ull<<20));
  bf16u* WvB = (bf16u*)(wsb + (64ull<<20));
  bf16u* W1B = (bf16u*)(wsb + (66ull<<20));   // 384 rows x 1024, 0.75 MiB
  bf16u* W2TB= (bf16u*)(wsb + (67ull<<20));   // [1024][192], 0.375 MiB
  bf16u* WoB = (bf16u*)(wsb + (60ull<<20));   // phase C, aliases WrB/WF
  bf16u* GW2T= (bf16u*)(wsb + (62ull<<20));   // phase C: gate_w2^T bf16 [1024][128]
  const bool fast = ws_size >= (77ull<<20);

  if (fast){
    // 0. weight pre-conversion (bf16; identical RNE rounding)
    k_wconv1<<<3648, 256, 0, stream>>>(Wr, Wk, Wv, maa_w1, gate_w1, decay_w1,
                                       aaa_w1, ma_w1, kkk_w1, mk_w1,
                                       maa_w2, decay_w2,
                                       WrB, WkB, WvB, W1B, W2TB);
    // 1. mix
    k_prep<<<4096, 256, 0, stream>>>(x, tmx, MIX);
    // 2. lo = tanh(mix @ maa_w1^T)  (M64: 64 blocks)
    k_gemm_b64<true><<<dim3(1,64),256,0,stream>>>(MIX, W1B, LO, 128, CC, 128);
    // 3. xm[g]: 4 NN-GEMMs merged into one launch (grid.z = group)
    k_gemm_nn_b4<<<dim3(8,32,4),256,0,stream>>>(LO, W2TB, X0, x, tmaa);
    // 4. big projections (M64: 512 blocks = 2 waves/SIMD)
    k_gemm_b64<true><<<dim3(8,64),256,0,stream>>>(X0, WrB, R,  CC, CC, 0);
    k_gemm_b64<true><<<dim3(8,64),256,0,stream>>>(X2, WkB, K0, CC, CC, 0);
    k_gemm_b64<true><<<dim3(8,64),256,0,stream>>>(X3, WvB, V,  CC, CC, 0);
    // 5. LoRA projections merged into one launch (grid.z = which)
    k_gemm_b64_lora<<<dim3(1,64,3),256,0,stream>>>(X0, X1, X2, W1B, GT, P1, P2);
    // 6. W2A = P1[:, :64] @ decay_w2 (last read of W2TB before WF overwrites)
    k_gemm_nn_b<64,0><<<dim3(8,32),256,0,stream>>>(P1, 96, W2TB, 128, W2A, nullptr, nullptr);
    // 7. fused elementwise + pair precompute (writes WF over phase-A weights)
    k_elem<1><<<1024, 256, 0, stream>>>(K0, P1, P2, W2A,
                                        kkk_w2, aaa_w2, ma_w2, mk_w2,
                                        t_decay, t_aaaaa, t_misc_a, t_misc_k, t_faaaa,
                                        KKN, Bb, UX, WF, R, Dsc, RKsc);
    // 8. delta-rule recurrence (r8-validated v13)
    k_rec<1><<<512, 256, 0, stream>>>(R, UX, WF, K0, V, KKN, Bb, Dsc, Yb);
    // 8b. Wo -> bf16 + gate_w2 -> transposed bf16, into now-dead WF region
    k_wconv2<<<1536, 256, 0, stream>>>(Wo, gate_w2, WoB, GW2T);
    // 9. GV = GT @ gate_w2 (M64 fast NT path)
    k_gemm_b64<true><<<dim3(8,64),256,0,stream>>>(GT, GW2T, GV, CC, 128, 0);
    // 10. groupnorm + bonus + gate
    k_post<<<4096, 256, 0, stream>>>(Yb, V, GV, ln_w, ln_b, RKsc, YG);
    // 11. out = yg @ Wo^T -> f32
    k_gemm_b64<false><<<dim3(8,64),256,0,stream>>>(YG, WoB, d_out, CC, CC, 0);
  } else {
    // Fallback: exact r8 sequence (f32 weights in-GEMM, f16 -u decay).
    k_prep<<<4096, 256, 0, stream>>>(x, tmx, MIX);
    k_gemm_mfma<true><<<dim3(1,32),256,0,stream>>>(MIX, maa_w1, maa_w1, maa_w1,
                                                   128, 128, LO, 128, CC, 128);
    bf16u* XMs[4] = {X0, X1, X2, X3};
    for (int g = 0; g < 4; ++g)
      k_gemm_nn<32,1><<<dim3(8,32),256,0,stream>>>(LO + g*32, 128,
                                                   maa_w2 + (size_t)g*32*CC,
                                                   XMs[g], x, tmaa + (size_t)g*CC);
    k_gemm_mfma<true><<<dim3(8,32),256,0,stream>>>(X0, Wr, Wr, Wr, CC, CC, R,  CC, CC, 0);
    k_gemm_mfma<true><<<dim3(8,32),256,0,stream>>>(X2, Wk, Wk, Wk, CC, CC, K0, CC, CC, 0);
    k_gemm_mfma<true><<<dim3(8,32),256,0,stream>>>(X3, Wv, Wv, Wv, CC, CC, V,  CC, CC, 0);
    k_gemm_mfma<true><<<dim3(1,32),256,0,stream>>>(X0, gate_w1, gate_w1, gate_w1,
                                                   128, 128, GT, 128, CC, 128);
    k_gemm_mfma<true><<<dim3(1,32),256,0,stream>>>(X1, decay_w1, aaa_w1, ma_w1,
                                                   64, 80, P1, 96, CC, 64);
    k_gemm_mfma<true><<<dim3(1,32),256,0,stream>>>(X2, kkk_w1, mk_w1, mk_w1,
                                                   16, 32, P2, 32, CC, 16);
    k_gemm_nn<64,0><<<dim3(8,32),256,0,stream>>>(P1, 96, decay_w2, W2A, nullptr, nullptr);
    k_elem<0><<<1024, 256, 0, stream>>>(K0, P1, P2, W2A,
                                        kkk_w2, aaa_w2, ma_w2, mk_w2,
                                        t_decay, t_aaaaa, t_misc_a, t_misc_k, t_faaaa,
                                        KKN, Bb, UX, WF, R, Dsc, RKsc);
    k_rec<0><<<512, 256, 0, stream>>>(R, UX, WF, K0, V, KKN, Bb, Dsc, Yb);
    k_gemm_nn<128,0><<<dim3(8,32),256,0,stream>>>(GT, 128, gate_w2, GV, nullptr, nullptr);
    k_post<<<4096, 256, 0, stream>>>(Yb, V, GV, ln_w, ln_b, RKsc, YG);
    k_gemm_mfma<false><<<dim3(8,32),256,0,stream>>>(YG, Wo, Wo, Wo, CC, CC, d_out, CC, CC, 0);
  }
}

// Round 12
// 563.543 us; speedup vs baseline: 1.7411x; 1.0452x over previous
//
#include <hip/hip_runtime.h>
#include <cstdint>
#include <cstddef>

// Problem constants
#define BB   4
#define TT   1024
#define CC   1024
#define HH   16
#define HSS  64
#define NNtok 4096            // B*T
#define EPSGN 0.00064f
#define W2TS 192              // W2TB col count (maa_w2 128 | decay_w2 64)

typedef unsigned short bf16u;
typedef __attribute__((ext_vector_type(8))) short short8;
typedef __attribute__((ext_vector_type(4))) float f32x4;
#define SLOT 4194304ull       // elements per 8MiB bf16 slot (= NNtok*CC)

__device__ __forceinline__ float bf2f(bf16u u){
  union { unsigned int i; float f; } cv; cv.i = ((unsigned int)u) << 16; return cv.f;
}
__device__ __forceinline__ unsigned short f2bfbits(unsigned int x){
  return (unsigned short)((x + 0x7fffu + ((x >> 16) & 1u)) >> 16);   // RNE
}
__device__ __forceinline__ bf16u f2bf(float f){
  union { float f; unsigned int i; } cv; cv.f = f;
  return f2bfbits(cv.i);
}
__device__ __forceinline__ void ld4bf(const bf16u* p, float* o){
  ushort4 u = *reinterpret_cast<const ushort4*>(p);
  o[0]=bf2f(u.x); o[1]=bf2f(u.y); o[2]=bf2f(u.z); o[3]=bf2f(u.w);
}
__device__ __forceinline__ void st4bf(bf16u* p, const float* v){
  ushort4 u; u.x=f2bf(v[0]); u.y=f2bf(v[1]); u.z=f2bf(v[2]); u.w=f2bf(v[3]);
  *reinterpret_cast<ushort4*>(p) = u;
}
__device__ __forceinline__ unsigned short f2h(float f){
  union { _Float16 h; unsigned short s; } c; c.h = (_Float16)f; return c.s;
}
__device__ __forceinline__ void st4h(bf16u* p, const float* v){
  ushort4 u; u.x=f2h(v[0]); u.y=f2h(v[1]); u.z=f2h(v[2]); u.w=f2h(v[3]);
  *reinterpret_cast<ushort4*>(p) = u;
}
__device__ __forceinline__ void ld4f(const float* p, float* o){
  float4 v = *reinterpret_cast<const float4*>(p);
  o[0]=v.x; o[1]=v.y; o[2]=v.z; o[3]=v.w;
}
__device__ __forceinline__ float sigm(float x){ return 1.f / (1.f + expf(-x)); }

// unpack helpers
__device__ __forceinline__ float bflo(unsigned int u){
  union { unsigned int i; float f; } c; c.i = u << 16; return c.f;
}
__device__ __forceinline__ float bfhi(unsigned int u){
  union { unsigned int i; float f; } c; c.i = u & 0xffff0000u; return c.f;
}
__device__ __forceinline__ float hlo(unsigned int u){
  union { unsigned short s; _Float16 h; } c; c.s = (unsigned short)(u & 0xffffu); return (float)c.h;
}
__device__ __forceinline__ float hhi(unsigned int u){
  union { unsigned short s; _Float16 h; } c; c.s = (unsigned short)(u >> 16); return (float)c.h;
}
__device__ __forceinline__ float hval(unsigned short s){
  union { unsigned short s; _Float16 h; } c; c.s = s; return (float)c.h;
}
__device__ __forceinline__ float dot4(const float* x, const float* y){
  return (x[0]*y[0] + x[1]*y[1]) + (x[2]*y[2] + x[3]*y[3]);
}

// 16-lane sum via DPP. old=0 + bound_ctrl=1 folds to single v_add_f32_dpp.
template<int CTRL>
__device__ __forceinline__ float dpp_add(float v){
  union { float f; int i; } a, b;
  a.f = v;
  b.i = __builtin_amdgcn_update_dpp(0, a.i, CTRL, 0xF, 0xF, true);
  return v + b.f;
}
__device__ __forceinline__ float red16(float v){
  v = dpp_add<0xB1>(v);    // quad_perm [1,0,3,2]  (xor 1)
  v = dpp_add<0x4E>(v);    // quad_perm [2,3,0,1]  (xor 2)
  v = dpp_add<0x124>(v);   // row_ror:4
  v = dpp_add<0x128>(v);   // row_ror:8
  return v;
}
// 32-lane sum in all lanes: red16 then exchange complementary 16-rows
// between two DISTINCT-register copies (laundered; rounds 1/3 failed when
// regalloc coalesced both operands into one phys reg -> self-swap).
__device__ __forceinline__ float red32(float v){
  v = red16(v);
  union { float f; int i; } x, y;
  x.f = v; y.f = v;
  asm volatile("" : "+v"(y.i));   // distinct-vreg launder
  asm volatile("v_permlane16_swap_b32 %0, %1" : "+v"(x.i), "+v"(y.i));
  return x.f + y.f;
}

// ---------------------------------------------------------------------------
// mix = x + (x[t-1]-x[t])*time_maa_x  (x[-1]=0), stored bf16 (fallback path)
// ---------------------------------------------------------------------------
__global__ __launch_bounds__(256) void k_prep(const float* __restrict__ x,
                                              const float* __restrict__ tmx,
                                              bf16u* __restrict__ MIX){
  int e = (blockIdx.x * 256 + threadIdx.x) * 4;
  int n = e >> 10;
  int c = e & (CC - 1);
  int t = n & (TT - 1);
  float xf[4]; ld4f(x + e, xf);
  float pf[4] = {0.f, 0.f, 0.f, 0.f};
  if (t > 0) ld4f(x + e - CC, pf);
  float tm[4]; ld4f(tmx + c, tm);
  float mv[4];
  #pragma unroll
  for (int i = 0; i < 4; ++i) mv[i] = xf[i] + (pf[i] - xf[i]) * tm[i];
  st4bf(MIX + e, mv);
}

// ---------------------------------------------------------------------------
// MERGED prep + weight pre-conversion (r12): both independent elementwise
// passes -> one launch (blk<4096: mix; else: weight convert). Outputs live
// in WF region (60..67.4 MiB), dead before k_elem overwrites it at step 7.
// ---------------------------------------------------------------------------
__global__ __launch_bounds__(256) void k_prep_wconv(
    const float* __restrict__ x, const float* __restrict__ tmx,
    bf16u* __restrict__ MIX,
    const float* __restrict__ Wr, const float* __restrict__ Wk,
    const float* __restrict__ Wv,
    const float* __restrict__ maa_w1, const float* __restrict__ gate_w1,
    const float* __restrict__ decay_w1, const float* __restrict__ aaa_w1,
    const float* __restrict__ ma_w1, const float* __restrict__ kkk_w1,
    const float* __restrict__ mk_w1,
    const float* __restrict__ maa_w2, const float* __restrict__ decay_w2,
    bf16u* __restrict__ WrB, bf16u* __restrict__ WkB, bf16u* __restrict__ WvB,
    bf16u* __restrict__ W1B, bf16u* __restrict__ W2TB){
  int tid = threadIdx.x;
  if (blockIdx.x < 4096){
    int e = (blockIdx.x * 256 + tid) * 4;
    int n = e >> 10;
    int c = e & (CC - 1);
    int t = n & (TT - 1);
    float xf[4]; ld4f(x + e, xf);
    float pf[4] = {0.f, 0.f, 0.f, 0.f};
    if (t > 0) ld4f(x + e - CC, pf);
    float tm[4]; ld4f(tmx + c, tm);
    float mv[4];
    #pragma unroll
    for (int i = 0; i < 4; ++i) mv[i] = xf[i] + (pf[i] - xf[i]) * tm[i];
    st4bf(MIX + e, mv);
    return;
  }
  int blk = blockIdx.x - 4096;
  if (blk < 3072){
    const float* src = (blk < 1024) ? Wr : (blk < 2048) ? Wk : Wv;
    bf16u* dst = (blk < 1024) ? WrB : (blk < 2048) ? WkB : WvB;
    size_t e = (size_t)(blk & 1023) * 1024 + (size_t)tid * 4;
    float v[4]; ld4f(src + e, v);
    st4bf(dst + e, v);
  } else if (blk < 3456){
    int row = blk - 3072;
    const float* src;
    if      (row < 128) src = maa_w1   + (size_t)row * 1024;
    else if (row < 256) src = gate_w1  + (size_t)(row - 128) * 1024;
    else if (row < 320) src = decay_w1 + (size_t)(row - 256) * 1024;
    else if (row < 336) src = aaa_w1   + (size_t)(row - 320) * 1024;
    else if (row < 352) src = ma_w1    + (size_t)(row - 336) * 1024;
    else if (row < 368) src = kkk_w1   + (size_t)(row - 352) * 1024;
    else                src = mk_w1    + (size_t)(row - 368) * 1024;
    float v[4]; ld4f(src + tid * 4, v);
    st4bf(W1B + (size_t)row * 1024 + tid * 4, v);
  } else {
    int j = blk - 3456;   // 0..191
    const float* src = (j < 128) ? (maa_w2 + (size_t)j * 1024)
                                 : (decay_w2 + (size_t)(j - 128) * 1024);
    for (int c = tid; c < 1024; c += 256)
      W2TB[(size_t)c * W2TS + j] = f2bf(src[c]);
  }
}

// Wo -> bf16 and gate_w2 -> transposed bf16 GW2T [1024][128]; after k_rec.
__global__ __launch_bounds__(256) void k_wconv2(const float* __restrict__ Wo,
                                                const float* __restrict__ gate_w2,
                                                bf16u* __restrict__ WoB,
                                                bf16u* __restrict__ GW2T){
  int blk = blockIdx.x, tid = threadIdx.x;
  if (blk < 1024){
    size_t e = ((size_t)blk * 256 + tid) * 4;
    float v[4]; ld4f(Wo + e, v);
    st4bf(WoB + e, v);
  } else {
    int c = (blk - 1024) * 2 + (tid >> 7);
    int j = tid & 127;
    GW2T[(size_t)c * 128 + j] = f2bf(gate_w2[(size_t)j * CC + c]);
  }
}

// ---------------------------------------------------------------------------
// MFMA NT GEMM body, bf16-W, M64xN128, BK=64 double-K staging (r12):
// halves barrier count (16 vs 32 for K=1024) and doubles prefetch distance.
// MFMA k-order preserved (kk=0 then 32 within a stage) -> bitwise identical.
// LDS 55.3KB/block -> still exactly 2 blocks/CU. 2 waves/SIMD (r8 lesson).
// ---------------------------------------------------------------------------
#define B64_AROW 72
#define B64_ASZ (64*72)
#define B64_BSZ (128*72)
template<bool OB>
__device__ __forceinline__ void gemm_b64_body(const bf16u* __restrict__ X,
                                              const bf16u* __restrict__ WB,
                                              void* __restrict__ OUTv,
                                              int Nd, int Kd, int act_n,
                                              short* __restrict__ As,
                                              short* __restrict__ Bs,
                                              int bn0, int bm0){
  const int tid  = threadIdx.x;
  const int lane = tid & 63;
  const int wv   = tid >> 6;
  const int wm   = wv >> 1, wn = wv & 1;   // wave -> 32-row x 64-col subtile
  const int l15  = lane & 15;
  const int quad = lane >> 4;

  f32x4 acc[2][4];
  #pragma unroll
  for (int mi = 0; mi < 2; ++mi)
    #pragma unroll
    for (int ni = 0; ni < 4; ++ni)
      #pragma unroll
      for (int rg = 0; rg < 4; ++rg) acc[mi][ni][rg] = 0.f;

  const int ra = tid >> 2, k0a = (tid & 3) * 16;   // A: 64 rows x 64k, 2 uint4/thr
  const int rb = tid >> 1, k0b = (tid & 1) * 32;   // B: 128 rows x 64k, 4 uint4/thr
  const bf16u* xsrc = X + (size_t)(bm0 + ra) * Kd;
  const bf16u* wsrc = (bn0 + rb < Nd) ? WB + (size_t)(bn0 + rb) * Kd : nullptr;

  uint4 xa0 = *(const uint4*)(xsrc + k0a);
  uint4 xa1 = *(const uint4*)(xsrc + k0a + 8);
  uint4 wa0 = make_uint4(0,0,0,0), wa1 = wa0, wa2 = wa0, wa3 = wa0;
  if (wsrc){
    wa0 = *(const uint4*)(wsrc + k0b);
    wa1 = *(const uint4*)(wsrc + k0b + 8);
    wa2 = *(const uint4*)(wsrc + k0b + 16);
    wa3 = *(const uint4*)(wsrc + k0b + 24);
  }
  *(uint4*)&As[ra * B64_AROW + k0a]      = xa0;
  *(uint4*)&As[ra * B64_AROW + k0a + 8]  = xa1;
  *(uint4*)&Bs[rb * B64_AROW + k0b]      = wa0;
  *(uint4*)&Bs[rb * B64_AROW + k0b + 8]  = wa1;
  *(uint4*)&Bs[rb * B64_AROW + k0b + 16] = wa2;
  *(uint4*)&Bs[rb * B64_AROW + k0b + 24] = wa3;
  __syncthreads();

  const int NS = Kd >> 6;
  for (int s = 0; s < NS; ++s){
    const int cur = s & 1;
    if (s + 1 < NS){                    // issue next-stage loads BEFORE compute
      int kb = (s + 1) << 6;
      xa0 = *(const uint4*)(xsrc + kb + k0a);
      xa1 = *(const uint4*)(xsrc + kb + k0a + 8);
      if (wsrc){
        wa0 = *(const uint4*)(wsrc + kb + k0b);
        wa1 = *(const uint4*)(wsrc + kb + k0b + 8);
        wa2 = *(const uint4*)(wsrc + kb + k0b + 16);
        wa3 = *(const uint4*)(wsrc + kb + k0b + 24);
      }
    }
    #pragma unroll
    for (int kk = 0; kk < 64; kk += 32){
      short8 af[2], bfg[4];
      #pragma unroll
      for (int mi = 0; mi < 2; ++mi)
        af[mi] = *(const short8*)&As[cur*B64_ASZ + (wm*32 + mi*16 + l15) * B64_AROW + kk + quad*8];
      #pragma unroll
      for (int ni = 0; ni < 4; ++ni)
        bfg[ni] = *(const short8*)&Bs[cur*B64_BSZ + (wn*64 + ni*16 + l15) * B64_AROW + kk + quad*8];
      #pragma unroll
      for (int mi = 0; mi < 2; ++mi)
        #pragma unroll
        for (int ni = 0; ni < 4; ++ni)
          acc[mi][ni] = __builtin_amdgcn_mfma_f32_16x16x32_bf16(af[mi], bfg[ni], acc[mi][ni], 0, 0, 0);
    }
    if (s + 1 < NS){
      const int nxt = cur ^ 1;
      *(uint4*)&As[nxt*B64_ASZ + ra * B64_AROW + k0a]      = xa0;
      *(uint4*)&As[nxt*B64_ASZ + ra * B64_AROW + k0a + 8]  = xa1;
      *(uint4*)&Bs[nxt*B64_BSZ + rb * B64_AROW + k0b]      = wa0;
      *(uint4*)&Bs[nxt*B64_BSZ + rb * B64_AROW + k0b + 8]  = wa1;
      *(uint4*)&Bs[nxt*B64_BSZ + rb * B64_AROW + k0b + 16] = wa2;
      *(uint4*)&Bs[nxt*B64_BSZ + rb * B64_AROW + k0b + 24] = wa3;
      __syncthreads();
    }
  }

  #pragma unroll
  for (int mi = 0; mi < 2; ++mi){
    #pragma unroll
    for (int ni = 0; ni < 4; ++ni){
      int col = bn0 + wn*64 + ni*16 + l15;
      if (col >= Nd) continue;
      #pragma unroll
      for (int rg = 0; rg < 4; ++rg){
        int row = bm0 + wm*32 + mi*16 + quad*4 + rg;
        float v = acc[mi][ni][rg];
        if (col < act_n) v = tanhf(v);
        if (OB) ((bf16u*)OUTv)[(size_t)row * Nd + col] = f2bf(v);
        else    ((float*)OUTv)[(size_t)row * Nd + col] = v;
      }
    }
  }
}

template<bool OB>
__global__ __launch_bounds__(256) void k_gemm_b64(const bf16u* __restrict__ X,
                                                  const bf16u* __restrict__ WB,
                                                  void* __restrict__ OUTv,
                                                  int Nd, int Kd, int act_n){
  __shared__ short As[2*B64_ASZ];
  __shared__ short Bs[2*B64_BSZ];
  gemm_b64_body<OB>(X, WB, OUTv, Nd, Kd, act_n, As, Bs,
                    blockIdx.x * 128, blockIdx.y * 64);
}

// R/K/V big projections merged into one z=3 launch (r12): 1536 blocks,
// rounds pipeline across z -> drain/fill bubbles once instead of 3x.
__global__ __launch_bounds__(256) void k_gemm_b64_rkv(const bf16u* __restrict__ X0,
                                                      const bf16u* __restrict__ X2,
                                                      const bf16u* __restrict__ X3,
                                                      const bf16u* __restrict__ WrB,
                                                      const bf16u* __restrict__ WkB,
                                                      const bf16u* __restrict__ WvB,
                                                      bf16u* __restrict__ R,
                                                      bf16u* __restrict__ K0,
                                                      bf16u* __restrict__ V){
  __shared__ short As[2*B64_ASZ];
  __shared__ short Bs[2*B64_BSZ];
  const int z = blockIdx.z;
  const int bn0 = blockIdx.x * 128, bm0 = blockIdx.y * 64;
  if (z == 0)      gemm_b64_body<true>(X0, WrB, R,  CC, CC, 0, As, Bs, bn0, bm0);
  else if (z == 1) gemm_b64_body<true>(X2, WkB, K0, CC, CC, 0, As, Bs, bn0, bm0);
  else             gemm_b64_body<true>(X3, WvB, V,  CC, CC, 0, As, Bs, bn0, bm0);
}

// 3 LoRA projections merged into one launch (z decodes).
__global__ __launch_bounds__(256) void k_gemm_b64_lora(const bf16u* __restrict__ X0,
                                                       const bf16u* __restrict__ X1,
                                                       const bf16u* __restrict__ X2,
                                                       const bf16u* __restrict__ W1B,
                                                       bf16u* __restrict__ GT,
                                                       bf16u* __restrict__ P1,
                                                       bf16u* __restrict__ P2){
  __shared__ short As[2*B64_ASZ];
  __shared__ short Bs[2*B64_BSZ];
  const int z = blockIdx.z;
  const int bm0 = blockIdx.y * 64;
  if (z == 0)
    gemm_b64_body<true>(X0, W1B + 128*1024, GT, 128, CC, 128, As, Bs, 0, bm0);
  else if (z == 1)
    gemm_b64_body<true>(X1, W1B + 256*1024, P1, 96, CC, 64, As, Bs, 0, bm0);
  else
    gemm_b64_body<true>(X2, W1B + 352*1024, P2, 32, CC, 16, As, Bs, 0, bm0);
}

// ---------------------------------------------------------------------------
// MFMA NN GEMM body, pre-transposed bf16 B (single-staging; K fits in LDS).
// ---------------------------------------------------------------------------
template<int KD, int EP>
__device__ __forceinline__ void gemm_nn_body(const bf16u* __restrict__ A, int lda,
                                             const bf16u* __restrict__ BT, int koff,
                                             bf16u* __restrict__ OUT,
                                             const float* __restrict__ x,
                                             const float* __restrict__ tma_g,
                                             short* __restrict__ As,
                                             short* __restrict__ Bs,
                                             int bn0, int bm0){
  const int tid  = threadIdx.x;
  const int lane = tid & 63;
  const int wv   = tid >> 6;
  const int wm   = wv >> 1, wn = wv & 1;
  const int l15  = lane & 15;
  const int quad = lane >> 4;

  for (int idx = tid; idx < 128 * (KD / 8); idx += 256){
    int r  = idx / (KD / 8);
    int kc = (idx % (KD / 8)) * 8;
    *(uint4*)&As[r * (KD + 8) + kc] =
        *(const uint4*)(A + (size_t)(bm0 + r) * lda + kc);
  }
  for (int idx = tid; idx < 128 * (KD / 8); idx += 256){
    int cc_ = idx / (KD / 8);
    int kc  = (idx % (KD / 8)) * 8;
    *(uint4*)&Bs[cc_ * (KD + 8) + kc] =
        *(const uint4*)(BT + (size_t)(bn0 + cc_) * W2TS + koff + kc);
  }
  __syncthreads();

  f32x4 acc[4][4];
  #pragma unroll
  for (int mi = 0; mi < 4; ++mi)
    #pragma unroll
    for (int ni = 0; ni < 4; ++ni)
      #pragma unroll
      for (int rg = 0; rg < 4; ++rg) acc[mi][ni][rg] = 0.f;

  #pragma unroll
  for (int kk = 0; kk < KD; kk += 32){
    short8 af[4], bfg[4];
    #pragma unroll
    for (int mi = 0; mi < 4; ++mi)
      af[mi] = *(const short8*)&As[(wm*64 + mi*16 + l15) * (KD + 8) + kk + quad*8];
    #pragma unroll
    for (int ni = 0; ni < 4; ++ni)
      bfg[ni] = *(const short8*)&Bs[(wn*64 + ni*16 + l15) * (KD + 8) + kk + quad*8];
    #pragma unroll
    for (int mi = 0; mi < 4; ++mi)
      #pragma unroll
      for (int ni = 0; ni < 4; ++ni)
        acc[mi][ni] = __builtin_amdgcn_mfma_f32_16x16x32_bf16(af[mi], bfg[ni], acc[mi][ni], 0, 0, 0);
  }

  #pragma unroll
  for (int mi = 0; mi < 4; ++mi){
    #pragma unroll
    for (int ni = 0; ni < 4; ++ni){
      int col = bn0 + wn*64 + ni*16 + l15;
      float tm = (EP == 1) ? tma_g[col] : 0.f;
      #pragma unroll
      for (int rg = 0; rg < 4; ++rg){
        int row = bm0 + wm*64 + mi*16 + quad*4 + rg;
        float v = acc[mi][ni][rg];
        if (EP == 1){
          float xv = x[(size_t)row * CC + col];
          float xp = ((row & (TT - 1)) == 0) ? 0.f : x[(size_t)row * CC + col - CC];
          v = xv + (xp - xv) * (v + tm);
        }
        OUT[(size_t)row * CC + col] = f2bf(v);
      }
    }
  }
}

template<int KD, int EP>
__global__ __launch_bounds__(256) void k_gemm_nn_b(const bf16u* __restrict__ A, int lda,
                                                   const bf16u* __restrict__ BT, int koff,
                                                   bf16u* __restrict__ OUT,
                                                   const float* __restrict__ x,
                                                   const float* __restrict__ tma_g){
  __shared__ short As[128 * (KD + 8)];
  __shared__ short Bs[128 * (KD + 8)];
  gemm_nn_body<KD, EP>(A, lda, BT, koff, OUT, x, tma_g, As, Bs,
                       blockIdx.x * 128, blockIdx.y * 128);
}

// 4 xm NN-GEMMs merged into one launch (z = group).
__global__ __launch_bounds__(256) void k_gemm_nn_b4(const bf16u* __restrict__ LO,
                                                    const bf16u* __restrict__ BT,
                                                    bf16u* __restrict__ X0base,
                                                    const float* __restrict__ x,
                                                    const float* __restrict__ tmaa){
  __shared__ short As[128 * 40];
  __shared__ short Bs[128 * 40];
  const int z = blockIdx.z;
  gemm_nn_body<32, 1>(LO + z*32, 128, BT, z*32, X0base + (size_t)z*SLOT,
                      x, tmaa + (size_t)z*CC, As, Bs,
                      blockIdx.x * 128, blockIdx.y * 128);
}

// ---------------------------------------------------------------------------
// LEGACY f32-W GEMMs (fallback path only)
// ---------------------------------------------------------------------------
template<bool OB>
__global__ __launch_bounds__(256) void k_gemm_mfma(const bf16u* __restrict__ X,
                                                   const float* __restrict__ Wa,
                                                   const float* __restrict__ Wb,
                                                   const float* __restrict__ Wc,
                                                   int na, int nab,
                                                   void* __restrict__ OUTv,
                                                   int Nd, int Kd, int act_n){
  __shared__ short As[128 * 40];
  __shared__ short Bs[128 * 40];
  const int tid  = threadIdx.x;
  const int lane = tid & 63;
  const int wv   = tid >> 6;
  const int wm   = wv >> 1, wn = wv & 1;
  const int bn0  = blockIdx.x * 128;
  const int bm0  = blockIdx.y * 128;
  const int l15  = lane & 15;
  const int quad = lane >> 4;

  f32x4 acc[4][4];
  #pragma unroll
  for (int mi = 0; mi < 4; ++mi)
    #pragma unroll
    for (int ni = 0; ni < 4; ++ni)
      #pragma unroll
      for (int rg = 0; rg < 4; ++rg) acc[mi][ni][rg] = 0.f;

  const int r    = tid >> 1;
  const int half = (tid & 1) * 16;

  int rr = bn0 + r;
  const float* wsrc = nullptr;
  if (rr < na)        wsrc = Wa + (size_t)rr * Kd;
  else if (rr < nab)  wsrc = Wb + (size_t)(rr - na) * Kd;
  else if (rr < Nd)   wsrc = Wc + (size_t)(rr - nab) * Kd;
  const bf16u* xsrc = X + (size_t)(bm0 + r) * Kd;

  for (int k0 = 0; k0 < Kd; k0 += 32){
    uint4 xa = *(const uint4*)(xsrc + k0 + half);
    uint4 xb = *(const uint4*)(xsrc + k0 + half + 8);
    uint4 w0 = make_uint4(0,0,0,0), w1 = w0, w2 = w0, w3 = w0;
    if (wsrc){
      w0 = *(const uint4*)(wsrc + k0 + half);
      w1 = *(const uint4*)(wsrc + k0 + half + 4);
      w2 = *(const uint4*)(wsrc + k0 + half + 8);
      w3 = *(const uint4*)(wsrc + k0 + half + 12);
    }
    union { unsigned short s[8]; uint4 v; } p0, p1;
    p0.s[0]=f2bfbits(w0.x); p0.s[1]=f2bfbits(w0.y); p0.s[2]=f2bfbits(w0.z); p0.s[3]=f2bfbits(w0.w);
    p0.s[4]=f2bfbits(w1.x); p0.s[5]=f2bfbits(w1.y); p0.s[6]=f2bfbits(w1.z); p0.s[7]=f2bfbits(w1.w);
    p1.s[0]=f2bfbits(w2.x); p1.s[1]=f2bfbits(w2.y); p1.s[2]=f2bfbits(w2.z); p1.s[3]=f2bfbits(w2.w);
    p1.s[4]=f2bfbits(w3.x); p1.s[5]=f2bfbits(w3.y); p1.s[6]=f2bfbits(w3.z); p1.s[7]=f2bfbits(w3.w);

    *(uint4*)&As[r * 40 + half]     = xa;
    *(uint4*)&As[r * 40 + half + 8] = xb;
    *(uint4*)&Bs[r * 40 + half]     = p0.v;
    *(uint4*)&Bs[r * 40 + half + 8] = p1.v;
    __syncthreads();

    short8 af[4], bfg[4];
    #pragma unroll
    for (int mi = 0; mi < 4; ++mi)
      af[mi] = *(const short8*)&As[(wm*64 + mi*16 + l15) * 40 + quad*8];
    #pragma unroll
    for (int ni = 0; ni < 4; ++ni)
      bfg[ni] = *(const short8*)&Bs[(wn*64 + ni*16 + l15) * 40 + quad*8];
    #pragma unroll
    for (int mi = 0; mi < 4; ++mi)
      #pragma unroll
      for (int ni = 0; ni < 4; ++ni)
        acc[mi][ni] = __builtin_amdgcn_mfma_f32_16x16x32_bf16(af[mi], bfg[ni], acc[mi][ni], 0, 0, 0);
    __syncthreads();
  }

  #pragma unroll
  for (int mi = 0; mi < 4; ++mi){
    #pragma unroll
    for (int ni = 0; ni < 4; ++ni){
      int col = bn0 + wn*64 + ni*16 + l15;
      if (col >= Nd) continue;
      #pragma unroll
      for (int rg = 0; rg < 4; ++rg){
        int row = bm0 + wm*64 + mi*16 + quad*4 + rg;
        float v = acc[mi][ni][rg];
        if (col < act_n) v = tanhf(v);
        if (OB) ((bf16u*)OUTv)[(size_t)row * Nd + col] = f2bf(v);
        else    ((float*)OUTv)[(size_t)row * Nd + col] = v;
      }
    }
  }
}

template<int KD, int EP>
__global__ __launch_bounds__(256) void k_gemm_nn(const bf16u* __restrict__ A, int lda,
                                                 const float* __restrict__ B,
                                                 bf16u* __restrict__ OUT,
                                                 const float* __restrict__ x,
                                                 const float* __restrict__ tma_g){
  __shared__ short As[128 * (KD + 8)];
  __shared__ short Bs[128 * (KD + 8)];
  const int tid  = threadIdx.x;
  const int lane = tid & 63;
  const int wv   = tid >> 6;
  const int wm   = wv >> 1, wn = wv & 1;
  const int bn0  = blockIdx.x * 128;
  const int bm0  = blockIdx.y * 128;
  const int l15  = lane & 15;
  const int quad = lane >> 4;

  for (int idx = tid; idx < 128 * (KD / 8); idx += 256){
    int r  = idx / (KD / 8);
    int kc = (idx % (KD / 8)) * 8;
    *(uint4*)&As[r * (KD + 8) + kc] =
        *(const uint4*)(A + (size_t)(bm0 + r) * lda + kc);
  }
  for (int idx = tid; idx < KD * 128; idx += 256){
    int k = idx >> 7, c = idx & 127;
    Bs[c * (KD + 8) + k] = (short)f2bf(B[(size_t)k * CC + bn0 + c]);
  }
  __syncthreads();

  f32x4 acc[4][4];
  #pragma unroll
  for (int mi = 0; mi < 4; ++mi)
    #pragma unroll
    for (int ni = 0; ni < 4; ++ni)
      #pragma unroll
      for (int rg = 0; rg < 4; ++rg) acc[mi][ni][rg] = 0.f;

  #pragma unroll
  for (int kk = 0; kk < KD; kk += 32){
    short8 af[4], bfg[4];
    #pragma unroll
    for (int mi = 0; mi < 4; ++mi)
      af[mi] = *(const short8*)&As[(wm*64 + mi*16 + l15) * (KD + 8) + kk + quad*8];
    #pragma unroll
    for (int ni = 0; ni < 4; ++ni)
      bfg[ni] = *(const short8*)&Bs[(wn*64 + ni*16 + l15) * (KD + 8) + kk + quad*8];
    #pragma unroll
    for (int mi = 0; mi < 4; ++mi)
      #pragma unroll
      for (int ni = 0; ni < 4; ++ni)
        acc[mi][ni] = __builtin_amdgcn_mfma_f32_16x16x32_bf16(af[mi], bfg[ni], acc[mi][ni], 0, 0, 0);
  }

  #pragma unroll
  for (int mi = 0; mi < 4; ++mi){
    #pragma unroll
    for (int ni = 0; ni < 4; ++ni){
      int col = bn0 + wn*64 + ni*16 + l15;
      float tm = (EP == 1) ? tma_g[col] : 0.f;
      #pragma unroll
      for (int rg = 0; rg < 4; ++rg){
        int row = bm0 + wm*64 + mi*16 + quad*4 + rg;
        float v = acc[mi][ni][rg];
        if (EP == 1){
          float xv = x[(size_t)row * CC + col];
          float xp = ((row & (TT - 1)) == 0) ? 0.f : x[(size_t)row * CC + col - CC];
          v = xv + (xp - xv) * (v + tm);
        }
        OUT[(size_t)row * CC + col] = f2bf(v);
      }
    }
  }
}

// ---------------------------------------------------------------------------
// Fused elementwise + pair precompute, 4 tokens (2 pairs) per block.
// WMODE=1: w_t stored exact f32 in WF. WMODE=0: f16 -u fallback.
// ---------------------------------------------------------------------------
template<int WMODE>
__global__ __launch_bounds__(256) void k_elem(bf16u* __restrict__ K0,
    const bf16u* __restrict__ P1, const bf16u* __restrict__ P2,
    const bf16u* __restrict__ W2A,
    const float* __restrict__ kw2, const float* __restrict__ aw2,
    const float* __restrict__ maw2, const float* __restrict__ mkw2,
    const float* __restrict__ td,  const float* __restrict__ taa,
    const float* __restrict__ tma, const float* __restrict__ tmk,
    const float* __restrict__ faaaa,
    bf16u* __restrict__ KKN, bf16u* __restrict__ Bb, bf16u* __restrict__ UX,
    float* __restrict__ WF,
    bf16u* __restrict__ Rq, float* __restrict__ Dsc, float* __restrict__ RKsc){
  int n0 = blockIdx.x * 4, tid = threadIdx.x;
  __shared__ float at_l[4][16], mat_l[4][16], kt_l[4][16], mkt_l[4][16];
  {
    int grp = tid >> 6, q = tid & 63, tt = q >> 4, j = q & 15;
    if (grp == 0)      at_l[tt][j]  = bf2f(P1[(size_t)(n0+tt)*96 + 64 + j]);
    else if (grp == 1) mat_l[tt][j] = bf2f(P1[(size_t)(n0+tt)*96 + 80 + j]);
    else if (grp == 2) kt_l[tt][j]  = bf2f(P2[(size_t)(n0+tt)*32 + j]);
    else               mkt_l[tt][j] = bf2f(P2[(size_t)(n0+tt)*32 + 16 + j]);
  }
  __syncthreads();
  int c  = tid * 4;
  int h  = tid >> 4;       // head (16 lanes per head)
  int lg = tid & 15;

  float kkk[4][4], aa[4][4], mam[4][4], mkm[4][4];
  #pragma unroll
  for (int tt = 0; tt < 4; ++tt)
    #pragma unroll
    for (int i = 0; i < 4; ++i){ kkk[tt][i]=0; aa[tt][i]=0; mam[tt][i]=0; mkm[tt][i]=0; }

  #pragma unroll 4
  for (int j = 0; j < 16; ++j){
    float wk[4], wa[4], wm[4], wq[4];
    ld4f(kw2  + (size_t)j*CC + c, wk);
    ld4f(aw2  + (size_t)j*CC + c, wa);
    ld4f(maw2 + (size_t)j*CC + c, wm);
    ld4f(mkw2 + (size_t)j*CC + c, wq);
    #pragma unroll
    for (int tt = 0; tt < 4; ++tt){
      float s1 = kt_l[tt][j], s2 = at_l[tt][j], s3 = mat_l[tt][j], s4 = mkt_l[tt][j];
      #pragma unroll
      for (int i = 0; i < 4; ++i){
        kkk[tt][i] += s1 * wk[i];
        aa[tt][i]  += s2 * wa[i];
        mam[tt][i] += s3 * wm[i];
        mkm[tt][i] += s4 * wq[i];
      }
    }
  }

  float td4[4], taa4[4], tma4[4], tmk4[4], fa4[4];
  ld4f(td + c, td4); ld4f(taa + c, taa4); ld4f(tma + c, tma4); ld4f(tmk + c, tmk4);
  ld4f(faaaa + c, fa4);

#define ELEM_TOKEN(TT_, E_, A_, B_, KF_, WD_) do{ \
    float k0a[4]; ld4bf(K0 + (E_), k0a); \
    float w2a[4]; ld4bf(W2A + (E_), w2a); \
    float ssq = 0.f; \
    _Pragma("unroll") \
    for (int i = 0; i < 4; ++i){ A_[i] = k0a[i] + kkk[TT_][i]; ssq += A_[i]*A_[i]; } \
    ssq = red16(ssq); \
    float rinv = 1.f / fmaxf(sqrtf(ssq), 1e-12f); \
    float outw_[4]; \
    _Pragma("unroll") \
    for (int i = 0; i < 4; ++i){ \
      float z  = td4[i] + w2a[i]; \
      float nz = -z; \
      float sp = (nz > 15.f) ? nz : log1pf(expf(nz)); \
      float w  = -sp - 0.5f; \
      float av  = sigm(taa4[i] + aa[TT_][i]); \
      float mav = sigm(tma4[i] + mam[TT_][i]); \
      float mkv = sigm(tmk4[i] + mkm[TT_][i]); \
      A_[i] *= rinv; \
      B_[i]  = -A_[i] * av; \
      KF_[i] = k0a[i] * (mav + av * (1.f - mav)) * expf(w * mkv); \
      float ou = -expf(w); \
      outw_[i] = ou; \
      if (WMODE == 1) WD_[i] = __expf(ou);              /* exact f32 w_t */ \
      else            WD_[i] = __expf(hval(f2h(ou)));   /* f16-consistent */ \
    } \
    st4bf(Bb + (E_), B_); \
    st4bf(K0 + (E_), KF_); \
    if (WMODE == 1) *(float4*)(WF + (E_)) = make_float4(WD_[0], WD_[1], WD_[2], WD_[3]); \
    else            st4h(UX + (E_), outw_); \
  }while(0)

  #pragma unroll
  for (int p = 0; p < 2; ++p){
    const int ttE = 2*p, ttO = ttE + 1;
    size_t eE = (size_t)(n0 + ttE) * CC + c;
    size_t eO = eE + CC;
    float aE[4], bE[4], kfE[4], wdE[4];
    float aO[4], bO[4], kfO[4], wdO[4];
    ELEM_TOKEN(ttE, eE, aE, bE, kfE, wdE);
    ELEM_TOKEN(ttO, eO, aO, bO, kfO, wdO);
    st4bf(KKN + eE, aE);

    float rE[4], rO[4];
    ld4bf(Rq + eE, rE); ld4bf(Rq + eO, rO);

    // rk for k_post (before R is overwritten)
    float rkE = red16(rE[0]*kfE[0]*fa4[0] + rE[1]*kfE[1]*fa4[1]
                    + rE[2]*kfE[2]*fa4[2] + rE[3]*kfE[3]*fa4[3]);
    float rkO = red16(rO[0]*kfO[0]*fa4[0] + rO[1]*kfO[1]*fa4[1]
                    + rO[2]*kfO[2]*fa4[2] + rO[3]*kfO[3]*fa4[3]);

    // u1 over KKN odd row
    float c1 = red16(dot4(bE, aO));
    float d  = red16(dot4(kfE, aO));
    float u1[4];
    #pragma unroll
    for (int i = 0; i < 4; ++i) u1[i] = wdE[i]*aO[i] + c1*aE[i];
    st4bf(KKN + eO, u1);

    // q' even
    float cq = red16(dot4(bE, rE));
    float e1 = red16(dot4(kfE, rE));
    float qe[4];
    #pragma unroll
    for (int i = 0; i < 4; ++i) qe[i] = wdE[i]*rE[i] + cq*aE[i];
    st4bf(Rq + eE, qe);

    // z = M_{t+1} q_{t+1}; q' odd = M_t z
    float cz  = red16(dot4(bO, rO));
    float e21 = red16(dot4(kfO, rO));
    float z[4];
    #pragma unroll
    for (int i = 0; i < 4; ++i) z[i] = wdO[i]*rO[i] + cz*aO[i];
    float cy  = red16(dot4(bE, z));
    float e20 = red16(dot4(kfE, z));
    float qo[4];
    #pragma unroll
    for (int i = 0; i < 4; ++i) qo[i] = wdE[i]*z[i] + cy*aE[i];
    st4bf(Rq + eO, qo);

    if (lg == 0){
      size_t pr = (size_t)((n0 + ttE) >> 1);
      float4 dv; dv.x = d; dv.y = e1; dv.z = e20; dv.w = e21;
      *(float4*)(Dsc + (pr * HH + h) * 4) = dv;
      RKsc[(size_t)(n0 + ttE) * HH + h] = rkE;
      RKsc[(size_t)(n0 + ttO) * HH + h] = rkO;
    }
  }
#undef ELEM_TOKEN
}

// ---------------------------------------------------------------------------
// Recurrence v13 (r8-validated): 32-lane rows, 2 waves/SIMD, pair-fused,
// all 4 reductions vs base S, f32 decay (WMODE=1).
// ---------------------------------------------------------------------------
template<int WMODE>
__global__ __launch_bounds__(256) void k_rec(const bf16u* __restrict__ Qp,
                                             const bf16u* __restrict__ WT,
                                             const float* __restrict__ WF,
                                             const bf16u* __restrict__ KFt,
                                             const bf16u* __restrict__ Vt,
                                             const bf16u* __restrict__ Aa,
                                             const bf16u* __restrict__ Bv,
                                             const float* __restrict__ Dsc,
                                             bf16u* __restrict__ Y){
  const int p   = blockIdx.x;                 // 0..511
  const int g   = (p & 7) | ((p >> 6) << 3);  // (b,h) group 0..63, XCD-clustered
  const int oct = (p >> 3) & 7;               // row octet within the head
  const int b   = g >> 4;
  const int h   = g & 15;
  const int tid = threadIdx.x;
  const int l31 = tid & 31;                   // 32 lanes per row
  const int i   = oct * 8 + (tid >> 5);       // state row 0..63
  const size_t base0 = (size_t)(b * TT) * CC + h * HSS;
  const size_t colb  = base0 + l31 * 2;       // 2 cols per lane
  const size_t rowb  = base0 + i;
  const size_t dscb  = ((size_t)(b * (TT/2)) * HH + h) * 4;

  float S0 = 0.f, S1 = 0.f;                   // state cols (2*l31, 2*l31+1)

  unsigned int qEA,qOA,aEA,uOA,kEA,kOA,bEA,bOA,wEA,wOA; float2 fEA,fOA; unsigned short vEA,vOA; float4 dA;
  unsigned int qEB,qOB,aEB,uOB,kEB,kOB,bEB,bOB,wEB,wOB; float2 fEB,fOB; unsigned short vEB,vOB; float4 dB;
  unsigned int qEC,qOC,aEC,uOC,kEC,kOC,bEC,bOC,wEC,wOC; float2 fEC,fOC; unsigned short vEC,vOC; float4 dC;
  unsigned int qED,qOD,aED,uOD,kED,kOD,bED,bOD,wED,wOD; float2 fED,fOD; unsigned short vED,vOD; float4 dD;

#define PL(S, T_) do{ \
    size_t cE_ = colb + (size_t)(T_) * CC, cO_ = cE_ + CC; \
    qE##S = *(const unsigned int*)(Qp  + cE_); qO##S = *(const unsigned int*)(Qp  + cO_); \
    aE##S = *(const unsigned int*)(Aa  + cE_); uO##S = *(const unsigned int*)(Aa  + cO_); \
    kE##S = *(const unsigned int*)(KFt + cE_); kO##S = *(const unsigned int*)(KFt + cO_); \
    bE##S = *(const unsigned int*)(Bv  + cE_); bO##S = *(const unsigned int*)(Bv  + cO_); \
    if (WMODE == 1){ \
      fE##S = *(const float2*)(WF + cE_); fO##S = *(const float2*)(WF + cO_); \
    } else { \
      wE##S = *(const unsigned int*)(WT + cE_); wO##S = *(const unsigned int*)(WT + cO_); \
    } \
    vE##S = Vt[rowb + (size_t)(T_) * CC]; \
    vO##S = Vt[rowb + (size_t)(T_ + 1) * CC]; \
    d##S  = *(const float4*)(Dsc + dscb + (size_t)((T_) >> 1) * (HH*4)); \
  }while(0)

#define PSTEP(S, T_) do{ \
    float a0=bflo(aE##S), a1=bfhi(aE##S); \
    float u0=bflo(uO##S), u1=bfhi(uO##S); \
    float g0=bflo(qE##S), g1=bfhi(qE##S); \
    float o0=bflo(qO##S), o1=bfhi(qO##S); \
    float pE_ = fmaf(S1, a1, S0 * a0); \
    float pO_ = fmaf(S1, u1, S0 * u0); \
    float yE_ = fmaf(S1, g1, S0 * g0); \
    float yO_ = fmaf(S1, o1, S0 * o0); \
    pE_ = red32(pE_); \
    pO_ = red32(pO_); \
    yE_ = red32(yE_); \
    yO_ = red32(yO_); \
    float vEf = bf2f(vE##S), vOf = bf2f(vO##S); \
    float saE = pE_; \
    float saO = fmaf(d##S.x, vEf, pO_); \
    float ypE = fmaf(d##S.y, vEf, yE_); \
    float ypO = fmaf(d##S.z, vEf, fmaf(d##S.w, vOf, yO_)); \
    float k0=bflo(kE##S), k1=bfhi(kE##S); \
    float b0=bflo(bE##S), b1=bfhi(bE##S); \
    float w0, w1; \
    if (WMODE == 1){ w0=fE##S.x; w1=fE##S.y; } \
    else { w0=__expf(hlo(wE##S)); w1=__expf(hhi(wE##S)); } \
    S0 = fmaf(S0, w0, fmaf(saE, b0, vEf * k0)); \
    S1 = fmaf(S1, w1, fmaf(saE, b1, vEf * k1)); \
    float ko0=bflo(kO##S), ko1=bfhi(kO##S); \
    float bo0=bflo(bO##S), bo1=bfhi(bO##S); \
    float wo0, wo1; \
    if (WMODE == 1){ wo0=fO##S.x; wo1=fO##S.y; } \
    else { wo0=__expf(hlo(wO##S)); wo1=__expf(hhi(wO##S)); } \
    S0 = fmaf(S0, wo0, fmaf(saO, bo0, vOf * ko0)); \
    S1 = fmaf(S1, wo1, fmaf(saO, bo1, vOf * ko1)); \
    if (l31 == 0){ \
      Y[rowb + (size_t)(T_) * CC]     = f2bf(ypE); \
      Y[rowb + (size_t)(T_ + 1) * CC] = f2bf(ypO); \
    } \
  }while(0)

  PL(A, 0); PL(B, 2); PL(C, 4); PL(D, 6);
  for (int t = 0; t < TT; t += 8){
    PSTEP(A, t);
    if (t + 8  < TT) PL(A, t + 8);
    PSTEP(B, t + 2);
    if (t + 10 < TT) PL(B, t + 10);
    PSTEP(C, t + 4);
    if (t + 12 < TT) PL(C, t + 12);
    PSTEP(D, t + 6);
    if (t + 14 < TT) PL(D, t + 14);
  }
#undef PL
#undef PSTEP
}

// ---------------------------------------------------------------------------
// Post: GroupNorm + precomputed bonus rk*v + precomputed gate GV -> YG (bf16)
// ---------------------------------------------------------------------------
__global__ __launch_bounds__(256) void k_post(const bf16u* __restrict__ Y,
                                              const bf16u* __restrict__ Vt,
                                              const bf16u* __restrict__ GV,
                                              const float* __restrict__ lnw,
                                              const float* __restrict__ lnb,
                                              const float* __restrict__ RKsc,
                                              bf16u* __restrict__ YG){
  int n = blockIdx.x, tid = threadIdx.x;
  int c = tid * 4;
  size_t e = (size_t)n * CC + c;

  float ya[4]; ld4bf(Y + e, ya);
  float s = ya[0] + ya[1] + ya[2] + ya[3];
  s = red16(s);
  float mu = s * (1.f / 64.f);
  float d[4], vs = 0.f;
  #pragma unroll
  for (int i = 0; i < 4; ++i){ d[i] = ya[i] - mu; vs += d[i] * d[i]; }
  vs = red16(vs);
  float rstd = rsqrtf(vs * (1.f / 64.f) + EPSGN);

  float rk = RKsc[(size_t)n * HH + (tid >> 4)];

  float va[4]; ld4bf(Vt + e, va);
  float lw4[4], lb4[4];
  ld4f(lnw + c, lw4); ld4f(lnb + c, lb4);
  float g[4]; ld4bf(GV + e, g);
  float o[4];
  #pragma unroll
  for (int i = 0; i < 4; ++i){
    float yn = d[i] * rstd * lw4[i] + lb4[i] + rk * va[i];
    o[i] = yn * g[i];
  }
  st4bf(YG + e, o);
}

// ---------------------------------------------------------------------------
extern "C" void kernel_launch(void* const* d_in, const int* in_sizes, int n_in,
                              void* d_out, int out_size, void* d_ws, size_t ws_size,
                              hipStream_t stream){
  (void)in_sizes; (void)n_in; (void)out_size;
  const float* x        = (const float*)d_in[0];
  const float* tmx      = (const float*)d_in[1];
  const float* tmaa     = (const float*)d_in[2];
  const float* maa_w1   = (const float*)d_in[3];
  const float* maa_w2   = (const float*)d_in[4];
  const float* decay_w1 = (const float*)d_in[5];
  const float* decay_w2 = (const float*)d_in[6];
  const float* aaa_w1   = (const float*)d_in[7];
  const float* aaa_w2   = (const float*)d_in[8];
  const float* kkk_w1   = (const float*)d_in[9];
  const float* kkk_w2   = (const float*)d_in[10];
  const float* gate_w1  = (const float*)d_in[11];
  const float* gate_w2  = (const float*)d_in[12];
  const float* ma_w1    = (const float*)d_in[13];
  const float* ma_w2    = (const float*)d_in[14];
  const float* mk_w1    = (const float*)d_in[15];
  const float* mk_w2    = (const float*)d_in[16];
  const float* t_decay  = (const float*)d_in[17];
  const float* t_faaaa  = (const float*)d_in[18];
  const float* t_aaaaa  = (const float*)d_in[19];
  const float* t_misc_a = (const float*)d_in[20];
  const float* t_misc_k = (const float*)d_in[21];
  const float* Wr       = (const float*)d_in[22];
  const float* Wk       = (const float*)d_in[23];
  const float* Wv       = (const float*)d_in[24];
  const float* Wo       = (const float*)d_in[25];
  const float* ln_w     = (const float*)d_in[26];
  const float* ln_b     = (const float*)d_in[27];

  // Slot map (8MiB bf16 each), 56 MiB slots + smalls at 56..60 MiB.
  // 60..76 MiB region is time-shared:
  //   phase A (steps 0-6):  WrB@60 WkB@62 WvB@64 W1B@66 W2TB@67  (bf16 weights)
  //   phase B (steps 7-8):  WF (f32 w_t, 16 MiB) — k_elem overwrites phase A
  //   phase C (steps 9-11): WoB@60 (2MiB) + GW2T@62 (256KiB), after k_rec
  bf16u* bw  = (bf16u*)d_ws;
  bf16u* MIX = bw + 0*SLOT;
  bf16u* X0  = bw + 0*SLOT;
  bf16u* KKN = bw + 0*SLOT;
  bf16u* YG  = bw + 0*SLOT;
  bf16u* X1  = bw + 1*SLOT;
  bf16u* Bb  = bw + 1*SLOT;
  bf16u* GV  = bw + 1*SLOT;
  bf16u* X2  = bw + 2*SLOT;
  bf16u* UX  = bw + 2*SLOT;
  bf16u* X3  = bw + 3*SLOT;
  bf16u* W2A = bw + 3*SLOT;
  bf16u* Yb  = bw + 3*SLOT;
  bf16u* R   = bw + 4*SLOT;   // becomes q'
  bf16u* K0  = bw + 5*SLOT;   // becomes KF
  bf16u* V   = bw + 6*SLOT;
  char*  wsb = (char*)d_ws;
  bf16u* LO  = (bf16u*)(wsb + (56ull<<20));   // [N,128] bf16, 1 MiB
  bf16u* GT  = (bf16u*)(wsb + (57ull<<20));   // [N,128] bf16, 1 MiB
  bf16u* P1  = (bf16u*)(wsb + (58ull<<20));   // [N,96]  bf16 (dt|at|ma)
  bf16u* P2  = (bf16u*)(wsb + (58ull<<20) + (768ull<<10)); // [N,32] bf16
  float* Dsc = (float*)(wsb + (59ull<<20));   // [N/2,16] float4, 512 KiB
  float* RKsc= (float*)(wsb + (59ull<<20) + (512ull<<10)); // [N,16] f32, 256 KiB
  float* WF  = (float*)(wsb + (60ull<<20));   // [N,CC] f32 w_t, 16 MiB
  bf16u* WrB = (bf16u*)(wsb + (60ull<<20));
  bf16u* WkB = (bf16u*)(wsb + (62ull<<20));
  bf16u* WvB = (bf16u*)(wsb + (64ull<<20));
  bf16u* W1B = (bf16u*)(wsb + (66ull<<20));   // 384 rows x 1024, 0.75 MiB
  bf16u* W2TB= (bf16u*)(wsb + (67ull<<20));   // [1024][192], 0.375 MiB
  bf16u* WoB = (bf16u*)(wsb + (60ull<<20));   // phase C, aliases WrB/WF
  bf16u* GW2T= (bf16u*)(wsb + (62ull<<20));   // phase C: gate_w2^T bf16 [1024][128]
  const bool fast = ws_size >= (77ull<<20);

  if (fast){
    // 0+1. merged mix + weight pre-conversion (bf16; identical RNE rounding)
    k_prep_wconv<<<7744, 256, 0, stream>>>(x, tmx, MIX,
                                           Wr, Wk, Wv, maa_w1, gate_w1, decay_w1,
                                           aaa_w1, ma_w1, kkk_w1, mk_w1,
                                           maa_w2, decay_w2,
                                           WrB, WkB, WvB, W1B, W2TB);
    // 2. lo = tanh(mix @ maa_w1^T)
    k_gemm_b64<true><<<dim3(1,64),256,0,stream>>>(MIX, W1B, LO, 128, CC, 128);
    // 3. xm[g]: 4 NN-GEMMs merged into one launch (grid.z = group)
    k_gemm_nn_b4<<<dim3(8,32,4),256,0,stream>>>(LO, W2TB, X0, x, tmaa);
    // 4. big projections merged (z=3, 1536 blocks, BK=64 pipelined)
    k_gemm_b64_rkv<<<dim3(8,64,3),256,0,stream>>>(X0, X2, X3, WrB, WkB, WvB,
                                                  R, K0, V);
    // 5. LoRA projections merged into one launch (grid.z = which)
    k_gemm_b64_lora<<<dim3(1,64,3),256,0,stream>>>(X0, X1, X2, W1B, GT, P1, P2);
    // 6. W2A = P1[:, :64] @ decay_w2 (last read of W2TB before WF overwrites)
    k_gemm_nn_b<64,0><<<dim3(8,32),256,0,stream>>>(P1, 96, W2TB, 128, W2A, nullptr, nullptr);
    // 7. fused elementwise + pair precompute (writes WF over phase-A weights)
    k_elem<1><<<1024, 256, 0, stream>>>(K0, P1, P2, W2A,
                                        kkk_w2, aaa_w2, ma_w2, mk_w2,
                                        t_decay, t_aaaaa, t_misc_a, t_misc_k, t_faaaa,
                                        KKN, Bb, UX, WF, R, Dsc, RKsc);
    // 8. delta-rule recurrence (r8-validated v13)
    k_rec<1><<<512, 256, 0, stream>>>(R, UX, WF, K0, V, KKN, Bb, Dsc, Yb);
    // 8b. Wo -> bf16 + gate_w2 -> transposed bf16, into now-dead WF region
    k_wconv2<<<1536, 256, 0, stream>>>(Wo, gate_w2, WoB, GW2T);
    // 9. GV = GT @ gate_w2 (BK=64 fast NT path)
    k_gemm_b64<true><<<dim3(8,64),256,0,stream>>>(GT, GW2T, GV, CC, 128, 0);
    // 10. groupnorm + bonus + gate
    k_post<<<4096, 256, 0, stream>>>(Yb, V, GV, ln_w, ln_b, RKsc, YG);
    // 11. out = yg @ Wo^T -> f32
    k_gemm_b64<false><<<dim3(8,64),256,0,stream>>>(YG, WoB, d_out, CC, CC, 0);
  } else {
    // Fallback: exact r8 sequence (f32 weights in-GEMM, f16 -u decay).
    k_prep<<<4096, 256, 0, stream>>>(x, tmx, MIX);
    k_gemm_mfma<true><<<dim3(1,32),256,0,stream>>>(MIX, maa_w1, maa_w1, maa_w1,
                                                   128, 128, LO, 128, CC, 128);
    bf16u* XMs[4] = {X0, X1, X2, X3};
    for (int g = 0; g < 4; ++g)
      k_gemm_nn<32,1><<<dim3(8,32),256,0,stream>>>(LO + g*32, 128,
                                                   maa_w2 + (size_t)g*32*CC,
                                                   XMs[g], x, tmaa + (size_t)g*CC);
    k_gemm_mfma<true><<<dim3(8,32),256,0,stream>>>(X0, Wr, Wr, Wr, CC, CC, R,  CC, CC, 0);
    k_gemm_mfma<true><<<dim3(8,32),256,0,stream>>>(X2, Wk, Wk, Wk, CC, CC, K0, CC, CC, 0);
    k_gemm_mfma<true><<<dim3(8,32),256,0,stream>>>(X3, Wv, Wv, Wv, CC, CC, V,  CC, CC, 0);
    k_gemm_mfma<true><<<dim3(1,32),256,0,stream>>>(X0, gate_w1, gate_w1, gate_w1,
                                                   128, 128, GT, 128, CC, 128);
    k_gemm_mfma<true><<<dim3(1,32),256,0,stream>>>(X1, decay_w1, aaa_w1, ma_w1,
                                                   64, 80, P1, 96, CC, 64);
    k_gemm_mfma<true><<<dim3(1,32),256,0,stream>>>(X2, kkk_w1, mk_w1, mk_w1,
                                                   16, 32, P2, 32, CC, 16);
    k_gemm_nn<64,0><<<dim3(8,32),256,0,stream>>>(P1, 96, decay_w2, W2A, nullptr, nullptr);
    k_elem<0><<<1024, 256, 0, stream>>>(K0, P1, P2, W2A,
                                        kkk_w2, aaa_w2, ma_w2, mk_w2,
                                        t_decay, t_aaaaa, t_misc_a, t_misc_k, t_faaaa,
                                        KKN, Bb, UX, WF, R, Dsc, RKsc);
    k_rec<0><<<512, 256, 0, stream>>>(R, UX, WF, K0, V, KKN, Bb, Dsc, Yb);
    k_gemm_nn<128,0><<<dim3(8,32),256,0,stream>>>(GT, 128, gate_w2, GV, nullptr, nullptr);
    k_post<<<4096, 256, 0, stream>>>(Yb, V, GV, ln_w, ln_b, RKsc, YG);
    k_gemm_mfma<false><<<dim3(8,32),256,0,stream>>>(YG, Wo, Wo, Wo, CC, CC, d_out, CC, CC, 0);
  }
}